// Round 2
// baseline (8189.059 us; speedup 1.0000x reference)
//
#include <hip/hip_runtime.h>
#include <stdint.h>

#define TT 128
#define BB 128
#define DD 300
#define EE 1024
#define GG 900
#define NMU 1000
#define ASP 500

#define OUT_SLOG 131072
#define OUT_ACT  163840
#define OUT_LOGP 196608

// ---------------- threefry2x32 (JAX, 20 rounds) ----------------
__host__ __device__ static inline uint32_t rotl32(uint32_t x, int r){
  return (x << r) | (x >> (32 - r));
}

__host__ __device__ static inline void tf2x32(uint32_t k0, uint32_t k1,
                                              uint32_t x0, uint32_t x1,
                                              uint32_t* o0, uint32_t* o1){
  uint32_t ks2 = k0 ^ k1 ^ 0x1BD11BDAu;
#define TFR(r) { x0 += x1; x1 = rotl32(x1, r); x1 ^= x0; }
  x0 += k0; x1 += k1;
  TFR(13) TFR(15) TFR(26) TFR(6)
  x0 += k1; x1 += ks2 + 1u;
  TFR(17) TFR(29) TFR(16) TFR(24)
  x0 += ks2; x1 += k0 + 2u;
  TFR(13) TFR(15) TFR(26) TFR(6)
  x0 += k0; x1 += k1 + 3u;
  TFR(17) TFR(29) TFR(16) TFR(24)
  x0 += k1; x1 += ks2 + 4u;
  TFR(13) TFR(15) TFR(26) TFR(6)
  x0 += ks2; x1 += k0 + 5u;
#undef TFR
  *o0 = x0; *o1 = x1;
}

__device__ static inline uint32_t rng32(uint32_t k0, uint32_t k1, uint32_t idx){
  uint32_t a, b;
  tf2x32(k0, k1, 0u, idx, &a, &b);
  return a ^ b;
}

__device__ static inline float u01(uint32_t bits){
  return __uint_as_float((bits >> 9) | 0x3f800000u) - 1.0f;
}

__device__ static inline float jgumbel(uint32_t k0, uint32_t k1, uint32_t idx){
  float u = u01(rng32(k0, k1, idx));
  float l1 = logf(u + 1e-20f);
  return -logf(-l1 + 1e-20f);
}

__device__ static inline float erfinv32(float x){   // XLA ErfInv32 (Giles)
  float w = -log1pf(-x * x);
  float p;
  if (w < 5.0f){
    w = w - 2.5f;
    p = 2.81022636e-08f;
    p = 3.43273939e-07f  + p * w;
    p = -3.5233877e-06f  + p * w;
    p = -4.39150654e-06f + p * w;
    p = 0.00021858087f   + p * w;
    p = -0.00125372503f  + p * w;
    p = -0.00417768164f  + p * w;
    p = 0.246640727f     + p * w;
    p = 1.50140941f      + p * w;
  } else {
    w = sqrtf(w) - 3.0f;
    p = -0.000200214257f;
    p = 0.000100950558f  + p * w;
    p = 0.00134934322f   + p * w;
    p = -0.00367342844f  + p * w;
    p = 0.00573950773f   + p * w;
    p = -0.0076224613f   + p * w;
    p = 0.00943887047f   + p * w;
    p = 1.00167406f      + p * w;
    p = 2.83297682f      + p * w;
  }
  return p * x;
}

__device__ static inline float jnormal(uint32_t k0, uint32_t k1, uint32_t idx){
  float u = u01(rng32(k0, k1, idx));
  const float lo = -0.99999994f;
  float v = u * 2.0f + lo;
  v = fmaxf(lo, v);
  return 1.41421356237f * erfinv32(v);
}

__device__ static inline float jsigmoid(float x){
  return 1.0f / (1.0f + expf(-x));
}

__device__ static inline unsigned short f2bf(float f){   // RNE f32->bf16
  uint32_t u = __float_as_uint(f);
  uint32_t r = (u + 0x7fffu + ((u >> 16) & 1u)) >> 16;
  return (unsigned short)r;
}

// ---------------- GEMM1: gi_all[r=(t*BB+b)][900] = x@Wih_c^T + bih ----------------
__global__ __launch_bounds__(256) void k_gemm_gi(
    const float* __restrict__ X, const float* __restrict__ W,
    const float* __restrict__ bias, float* __restrict__ C)
{
  __shared__ float As[16][64];
  __shared__ float Bs[16][68];
  const int tid = threadIdx.x;
  const int rbase = blockIdx.y * 64;
  const int cbase = blockIdx.x * 64;
  const int tx = tid & 15, ty = tid >> 4;
  const int lrow = tid >> 2, lq = tid & 3;

  const int rg = rbase + lrow;
  const float* xrow = X + ((long)(rg & 127) * TT + (rg >> 7)) * DD;
  const int wj = cbase + lrow;

  float4 c0 = {0,0,0,0}, c1 = {0,0,0,0}, c2 = {0,0,0,0}, c3 = {0,0,0,0};

  for (int k0 = 0; k0 < DD; k0 += 16){
    int k = k0 + lq * 4;
    float4 va = {0,0,0,0};
    if (k < DD) va = *(const float4*)(xrow + k);
    As[lq*4+0][lrow] = va.x; As[lq*4+1][lrow] = va.y;
    As[lq*4+2][lrow] = va.z; As[lq*4+3][lrow] = va.w;
    float4 vb = {0,0,0,0};
    if (k < DD && wj < GG) vb = *(const float4*)(W + (long)wj * DD + k);
    Bs[lq*4+0][lrow] = vb.x; Bs[lq*4+1][lrow] = vb.y;
    Bs[lq*4+2][lrow] = vb.z; Bs[lq*4+3][lrow] = vb.w;
    __syncthreads();
#pragma unroll
    for (int kk = 0; kk < 16; ++kk){
      const float4 a = *(const float4*)&As[kk][ty * 4];
      const float4 b = *(const float4*)&Bs[kk][tx * 4];
      c0.x += a.x*b.x; c0.y += a.x*b.y; c0.z += a.x*b.z; c0.w += a.x*b.w;
      c1.x += a.y*b.x; c1.y += a.y*b.y; c1.z += a.y*b.z; c1.w += a.y*b.w;
      c2.x += a.z*b.x; c2.y += a.z*b.y; c2.z += a.z*b.z; c2.w += a.z*b.w;
      c3.x += a.w*b.x; c3.y += a.w*b.y; c3.z += a.w*b.z; c3.w += a.w*b.w;
    }
    __syncthreads();
  }
  const int ci = cbase + tx * 4;
  const int r0 = rbase + ty * 4;
  float bv[4];
#pragma unroll
  for (int j = 0; j < 4; ++j) bv[j] = (ci + j < GG) ? bias[ci + j] : 0.0f;
  float4 rows[4] = {c0, c1, c2, c3};
#pragma unroll
  for (int i = 0; i < 4; ++i){
    float vals[4] = {rows[i].x + bv[0], rows[i].y + bv[1],
                     rows[i].z + bv[2], rows[i].w + bv[3]};
    float* crow = C + (long)(r0 + i) * GG;
    if (ci + 3 < GG){
      float4 st = {vals[0], vals[1], vals[2], vals[3]};
      *(float4*)(crow + ci) = st;
    } else {
#pragma unroll
      for (int j = 0; j < 4; ++j) if (ci + j < GG) crow[ci + j] = vals[j];
    }
  }
}

// ---------------- GEMM-mu: mu_all[r][1000] = relu([img|hx])@Wmu^T + bmu ----------------
__global__ __launch_bounds__(256) void k_gemm_mu(
    const float* __restrict__ X, const float* __restrict__ HX,
    const float* __restrict__ W, const float* __restrict__ bias,
    float* __restrict__ C)
{
  __shared__ float As[16][64];
  __shared__ float Bs[16][68];
  const int tid = threadIdx.x;
  const int rbase = blockIdx.y * 64;
  const int cbase = blockIdx.x * 64;
  const int tx = tid & 15, ty = tid >> 4;
  const int lrow = tid >> 2, lq = tid & 3;

  const int rg = rbase + lrow;
  const float* xrow = X + ((long)(rg & 127) * TT + (rg >> 7)) * DD;
  const float* hrow = HX + (long)rg * DD;
  const int wj = cbase + lrow;

  float4 c0 = {0,0,0,0}, c1 = {0,0,0,0}, c2 = {0,0,0,0}, c3 = {0,0,0,0};

  for (int k0 = 0; k0 < 600; k0 += 16){
    int k = k0 + lq * 4;
    float4 va = {0,0,0,0};
    if (k < 300)      va = *(const float4*)(xrow + k);
    else if (k < 600) va = *(const float4*)(hrow + (k - 300));
    va.x = fmaxf(va.x, 0.0f); va.y = fmaxf(va.y, 0.0f);
    va.z = fmaxf(va.z, 0.0f); va.w = fmaxf(va.w, 0.0f);
    As[lq*4+0][lrow] = va.x; As[lq*4+1][lrow] = va.y;
    As[lq*4+2][lrow] = va.z; As[lq*4+3][lrow] = va.w;
    float4 vb = {0,0,0,0};
    if (k < 600 && wj < NMU) vb = *(const float4*)(W + (long)wj * 600 + k);
    Bs[lq*4+0][lrow] = vb.x; Bs[lq*4+1][lrow] = vb.y;
    Bs[lq*4+2][lrow] = vb.z; Bs[lq*4+3][lrow] = vb.w;
    __syncthreads();
#pragma unroll
    for (int kk = 0; kk < 16; ++kk){
      const float4 a = *(const float4*)&As[kk][ty * 4];
      const float4 b = *(const float4*)&Bs[kk][tx * 4];
      c0.x += a.x*b.x; c0.y += a.x*b.y; c0.z += a.x*b.z; c0.w += a.x*b.w;
      c1.x += a.y*b.x; c1.y += a.y*b.y; c1.z += a.y*b.z; c1.w += a.y*b.w;
      c2.x += a.z*b.x; c2.y += a.z*b.y; c2.z += a.z*b.z; c2.w += a.z*b.w;
      c3.x += a.w*b.x; c3.y += a.w*b.y; c3.z += a.w*b.z; c3.w += a.w*b.w;
    }
    __syncthreads();
  }
  const int ci = cbase + tx * 4;
  const int r0 = rbase + ty * 4;
  float bv[4];
#pragma unroll
  for (int j = 0; j < 4; ++j) bv[j] = (ci + j < NMU) ? bias[ci + j] : 0.0f;
  float4 rows[4] = {c0, c1, c2, c3};
#pragma unroll
  for (int i = 0; i < 4; ++i){
    float vals[4] = {rows[i].x + bv[0], rows[i].y + bv[1],
                     rows[i].z + bv[2], rows[i].w + bv[3]};
    float* crow = C + (long)(r0 + i) * NMU;
    if (ci + 3 < NMU){
      float4 st = {vals[0], vals[1], vals[2], vals[3]};
      *(float4*)(crow + ci) = st;
    } else {
#pragma unroll
      for (int j = 0; j < 4; ++j) if (ci + j < NMU) crow[ci + j] = vals[j];
    }
  }
}

// ---------------- lv (pre-softplus), wave-per-row ----------------
__global__ __launch_bounds__(256) void k_lv(
    const float* __restrict__ X, const float* __restrict__ HX,
    const float* __restrict__ Wlv, const float* __restrict__ blv,
    float* __restrict__ LV)
{
  const int r = blockIdx.x * 4 + (threadIdx.x >> 6);   // 16384 rows
  const int lane = threadIdx.x & 63;
  const float* xr = X + ((long)(r & 127) * TT + (r >> 7)) * DD;
  const float* hr = HX + (long)r * DD;
  float a0 = 0.0f, a1 = 0.0f;
  for (int k = lane; k < DD; k += 64){
    float v = fmaxf(xr[k], 0.0f);
    a0 += v * Wlv[k];       a1 += v * Wlv[600 + k];
    float w = fmaxf(hr[k], 0.0f);
    a0 += w * Wlv[300 + k]; a1 += w * Wlv[900 + k];
  }
#pragma unroll
  for (int off = 32; off > 0; off >>= 1){
    a0 += __shfl_down(a0, off);
    a1 += __shfl_down(a1, off);
  }
  if (lane == 0){
    LV[(long)r * 2 + 0] = a0 + blv[0];
    LV[(long)r * 2 + 1] = a1 + blv[1];
  }
}

// ---------------- stage-1 recurrence step ----------------
__global__ __launch_bounds__(256) void k_hx_step(
    const int t, const float* __restrict__ hp, const float* __restrict__ Whh,
    const float* __restrict__ bhh, const float* __restrict__ gi_all,
    float* __restrict__ hx_out)
{
  __shared__ float Hs[32][66];
  __shared__ float Ws[32][32];
  const int tid = threadIdx.x;
  const int jx = tid & 7, bq = tid >> 3;
  const int jjBase = blockIdx.x * 8;
  const int bBase = blockIdx.y * 64;
  float aR[2] = {0,0}, aZ[2] = {0,0}, aN[2] = {0,0};

  for (int k0 = 0; k0 < DD; k0 += 32){
    for (int e = tid; e < 512; e += 256){
      int rr = e >> 3, kq = e & 7;
      int k = k0 + kq * 4;
      float4 v = {0,0,0,0};
      if (k < DD) v = *(const float4*)(hp + (long)(bBase + rr) * DD + k);
      Hs[kq*4+0][rr] = v.x; Hs[kq*4+1][rr] = v.y;
      Hs[kq*4+2][rr] = v.z; Hs[kq*4+3][rr] = v.w;
    }
    if (tid < 192){
      int wr = tid >> 3, kq = tid & 7;
      int g = wr >> 3, jw = wr & 7;
      int jjw = jjBase + jw;
      int k = k0 + kq * 4;
      float4 v = {0,0,0,0};
      if (k < DD && jjw < DD) v = *(const float4*)(Whh + ((long)g * DD + jjw) * DD + k);
      Ws[kq*4+0][jw*4 + g] = v.x; Ws[kq*4+1][jw*4 + g] = v.y;
      Ws[kq*4+2][jw*4 + g] = v.z; Ws[kq*4+3][jw*4 + g] = v.w;
    }
    __syncthreads();
#pragma unroll 8
    for (int kk = 0; kk < 32; ++kk){
      const float2 hv = *(const float2*)&Hs[kk][bq * 2];
      const float4 wv = *(const float4*)&Ws[kk][jx * 4];
      aR[0] += hv.x * wv.x; aZ[0] += hv.x * wv.y; aN[0] += hv.x * wv.z;
      aR[1] += hv.y * wv.x; aZ[1] += hv.y * wv.y; aN[1] += hv.y * wv.z;
    }
    __syncthreads();
  }
  const int jj = jjBase + jx;
  if (jj < DD){
#pragma unroll
    for (int i = 0; i < 2; ++i){
      const int b = bBase + bq * 2 + i;
      const float* gi = gi_all + ((long)t * BB + b) * GG;
      float ghr = aR[i] + bhh[jj];
      float ghz = aZ[i] + bhh[DD + jj];
      float ghn = aN[i] + bhh[2*DD + jj];
      float rr = jsigmoid(gi[jj] + ghr);
      float zz = jsigmoid(gi[DD + jj] + ghz);
      float nn = tanhf(gi[2*DD + jj] + rr * ghn);
      float hv = hp[(long)b * DD + jj];
      hx_out[(long)b * DD + jj] = (1.0f - zz) * nn + zz * hv;
    }
  }
}

// ---------------- sampling: softmax + gumbel-max + normal + texts(bf16) ----------------
__global__ __launch_bounds__(256) void k_sample(
    const float* __restrict__ X, const float* __restrict__ mu_all,
    const float* __restrict__ lv_all, unsigned short* __restrict__ texts_b,
    float* __restrict__ out,
    const uint32_t k0a, const uint32_t k0b, const uint32_t k1a, const uint32_t k1b,
    const uint32_t k2a, const uint32_t k2b, const uint32_t k3a, const uint32_t k3b)
{
  const int r = blockIdx.x;            // t*128 + b
  const int t = r >> 7, b = r & 127;
  const int tid = threadIdx.x;
  const int h = tid >> 7, lane = tid & 127;
  __shared__ float redf[256];
  __shared__ int   redi[256];
  __shared__ float yw[2], lyw[2], att_s[2];

  const uint32_t rowbase = (uint32_t)((t * 256 + b * 2 + h) * 500);
  float zv[4], ev[4];
  float lmax = -3.0e38f;
#pragma unroll
  for (int s = 0; s < 4; ++s){
    const int a = lane + s * 128;
    float z = -3.0e38f;
    if (a < ASP){
      float g = jgumbel(k0a, k0b, rowbase + (uint32_t)a);
      float m = mu_all[(long)r * NMU + h * ASP + a];
      z = (m + g) / 0.8f;
    }
    zv[s] = z;
    lmax = fmaxf(lmax, z);
  }
  redf[tid] = lmax;
  __syncthreads();
  for (int off = 64; off > 0; off >>= 1){
    if (lane < off) redf[tid] = fmaxf(redf[tid], redf[tid + off]);
    __syncthreads();
  }
  const float mx = redf[h << 7];
  __syncthreads();
  float lsum = 0.0f;
#pragma unroll
  for (int s = 0; s < 4; ++s){
    const int a = lane + s * 128;
    float e = 0.0f;
    if (a < ASP) e = expf(zv[s] - mx);
    ev[s] = e;
    lsum += e;
  }
  redf[tid] = lsum;
  __syncthreads();
  for (int off = 64; off > 0; off >>= 1){
    if (lane < off) redf[tid] += redf[tid + off];
    __syncthreads();
  }
  const float S = redf[h << 7];
  __syncthreads();
  float bestv = -3.0e38f;
  int besti = 0x7fffffff;
#pragma unroll
  for (int s = 0; s < 4; ++s){
    const int a = lane + s * 128;
    if (a < ASP){
      float y = ev[s] / S;
      float ly = logf(y);
      float gc = jgumbel(k1a, k1b, rowbase + (uint32_t)a);
      float val = ly + gc;
      if (val > bestv){ bestv = val; besti = a; }
    }
  }
  redf[tid] = bestv; redi[tid] = besti;
  __syncthreads();
  for (int off = 64; off > 0; off >>= 1){
    if (lane < off){
      float v2 = redf[tid + off]; int i2 = redi[tid + off];
      if (v2 > redf[tid] || (v2 == redf[tid] && i2 < redi[tid])){
        redf[tid] = v2; redi[tid] = i2;
      }
    }
    __syncthreads();
  }
  const int ind = redi[h << 7];
#pragma unroll
  for (int s = 0; s < 4; ++s){
    const int a = lane + s * 128;
    if (a == ind){
      float y = ev[s] / S;
      yw[h] = y;
      lyw[h] = logf(y);
    }
  }
  __syncthreads();
  if (lane == 0){
    const float yv = yw[h];
    const float ly = lyw[h];
    const float yh = (1.0f - yv) + yv;
    const float act = ((float)ind * yh) / 500.0f;
    const float lvr = lv_all[(long)r * 2 + h];
    const float lv = fmaxf(lvr, 0.0f) + log1pf(expf(-fabsf(lvr)));
    const float sd = expf(0.5f * lv);
    const uint32_t ei = (uint32_t)(r * 2 + h);
    const float e1 = jnormal(k2a, k2b, ei);
    const float e2 = jnormal(k3a, k3b, ei);
    const float s1 = act + sd * e1;
    const float s2 = act + sd * e2;
    const float dd = (s2 - act) / sd;
    const float lp = -0.5f * (dd * dd) - logf(sd) - 0.9189385332046727f;
    const float attv = 20.0f * jsigmoid(s1);
    out[OUT_SLOG + (long)b * 256 + t * 2 + h]  = ly;
    out[OUT_ACT  + (long)b * 256 + h * 128 + t] = act;
    out[OUT_LOGP + (long)b * 256 + h * 128 + t] = lp;
    att_s[h] = attv;
  }
  __syncthreads();
  const float* xr = X + ((long)b * TT + t) * DD;
  unsigned short* tr = texts_b + (long)r * 320;
  for (int j = tid; j < 320; j += 256){
    unsigned short o = 0;
    if (j < 300) o = f2bf(xr[j] * att_s[j / 150]);
    tr[j] = o;
  }
}

// ---------------- weight conversion to bf16 ----------------
__global__ __launch_bounds__(256) void k_cvt_whh(
    const float* __restrict__ W, unsigned short* __restrict__ O)
{
  const int i = blockIdx.x * 256 + threadIdx.x;   // 3072*1024
  O[i] = f2bf(W[i]);
}

__global__ __launch_bounds__(256) void k_cvt_wih(
    const float* __restrict__ W, unsigned short* __restrict__ O)
{
  const int i = blockIdx.x * 256 + threadIdx.x;   // 3072*320
  const int rw = i / 320, c = i - rw * 320;
  O[i] = (c < DD) ? f2bf(W[(long)rw * DD + c]) : (unsigned short)0;
}

// ---------------- stage-2 fused MFMA step ----------------
// grid (32, 2): nb = N-block (32 cols per gate), mb = M-block (64 rows)
// acc = hin_b @ Whb^T (K=1024)  +  texts_b[t] @ Wib^T (K=320 padded)
// then GRU gates fused in epilogue; h double-buffered.
#define LDSB 8192

__global__ __launch_bounds__(256) void k_step2(
    const int t,
    const unsigned short* __restrict__ hin_b,
    const float* __restrict__ hin_f,
    const unsigned short* __restrict__ texts_b,
    const unsigned short* __restrict__ Whb,
    const unsigned short* __restrict__ Wib,
    const float* __restrict__ bih, const float* __restrict__ bhh,
    const int* __restrict__ lengths,
    float* __restrict__ hout_f, unsigned short* __restrict__ hout_b,
    float* __restrict__ last)
{
  __shared__ __align__(16) char lds[20480];    // A: 64x64 bf16 @0, B: 96x64 bf16 @8192
  const int tid = threadIdx.x;
  const int nb = blockIdx.x, mb = blockIdx.y;
  const int wave = tid >> 6, lane = tid & 63;
  const int wm = wave >> 1, wn = wave & 1;

  using frag = __attribute__((ext_vector_type(8))) short;
  using f32x4 = __attribute__((ext_vector_type(4))) float;
  f32x4 accR[2], accZ[2], accNH[2], accNI[2];
#pragma unroll
  for (int i = 0; i < 2; ++i){
    accR[i] = (f32x4){0.f,0.f,0.f,0.f}; accZ[i] = (f32x4){0.f,0.f,0.f,0.f};
    accNH[i] = (f32x4){0.f,0.f,0.f,0.f}; accNI[i] = (f32x4){0.f,0.f,0.f,0.f};
  }

  uint4 raA[2], rbA[3], raB[2], rbB[3];

  auto issue = [&](int it, uint4* ra, uint4* rb){
    if (it < 16){
      const unsigned short* A = hin_b + (long)(mb * 64) * EE + it * 64;
#pragma unroll
      for (int i = 0; i < 2; ++i){
        const int c = tid + i * 256, row = c >> 3, kq = c & 7;
        ra[i] = *(const uint4*)(A + (long)row * EE + kq * 8);
      }
      const unsigned short* Bs = Whb + (long)(nb * 32) * EE + it * 64;
#pragma unroll
      for (int i = 0; i < 3; ++i){
        const int c = tid + i * 256, row = c >> 3, kq = c & 7;
        rb[i] = *(const uint4*)(Bs + ((long)(row >> 5) * EE + (row & 31)) * EE + kq * 8);
      }
    } else {
      const int k0 = (it - 16) * 64;
      const unsigned short* A = texts_b + ((long)t * BB + mb * 64) * 320 + k0;
#pragma unroll
      for (int i = 0; i < 2; ++i){
        const int c = tid + i * 256, row = c >> 3, kq = c & 7;
        ra[i] = *(const uint4*)(A + (long)row * 320 + kq * 8);
      }
      const unsigned short* Bs = Wib + (long)(nb * 32) * 320 + k0;
#pragma unroll
      for (int i = 0; i < 3; ++i){
        const int c = tid + i * 256, row = c >> 3, kq = c & 7;
        rb[i] = *(const uint4*)(Bs + ((long)(row >> 5) * EE + (row & 31)) * 320 + kq * 8);
      }
    }
  };

  auto commit = [&](uint4* ra, uint4* rb){
#pragma unroll
    for (int i = 0; i < 2; ++i){
      const int c = tid + i * 256, row = c >> 3, kq = c & 7;
      const int off = (row * 128 + kq * 16) ^ ((row & 7) << 4);
      *(uint4*)(lds + off) = ra[i];
    }
#pragma unroll
    for (int i = 0; i < 3; ++i){
      const int c = tid + i * 256, row = c >> 3, kq = c & 7;
      const int off = (row * 128 + kq * 16) ^ ((row & 7) << 4);
      *(uint4*)(lds + LDSB + off) = rb[i];
    }
  };

  auto compute = [&](int it){
    const bool hid = (it < 16);
#pragma unroll
    for (int kf = 0; kf < 2; ++kf){
      frag af[2], bf[3];
#pragma unroll
      for (int rf = 0; rf < 2; ++rf){
        const int row = wm * 32 + rf * 16 + (lane & 15);
        const int off = (row * 128 + kf * 64 + (lane >> 4) * 16) ^ ((row & 7) << 4);
        af[rf] = *(const frag*)(lds + off);
      }
#pragma unroll
      for (int g = 0; g < 3; ++g){
        const int row = g * 32 + wn * 16 + (lane & 15);
        const int off = (row * 128 + kf * 64 + (lane >> 4) * 16) ^ ((row & 7) << 4);
        bf[g] = *(const frag*)(lds + LDSB + off);
      }
#pragma unroll
      for (int rf = 0; rf < 2; ++rf){
        accR[rf] = __builtin_amdgcn_mfma_f32_16x16x32_bf16(af[rf], bf[0], accR[rf], 0, 0, 0);
        accZ[rf] = __builtin_amdgcn_mfma_f32_16x16x32_bf16(af[rf], bf[1], accZ[rf], 0, 0, 0);
        if (hid) accNH[rf] = __builtin_amdgcn_mfma_f32_16x16x32_bf16(af[rf], bf[2], accNH[rf], 0, 0, 0);
        else     accNI[rf] = __builtin_amdgcn_mfma_f32_16x16x32_bf16(af[rf], bf[2], accNI[rf], 0, 0, 0);
      }
    }
  };

  issue(0, raA, rbA);
  for (int it = 0; it < 21; it += 2){
    __syncthreads();
    commit(raA, rbA);
    __syncthreads();
    if (it + 1 < 21) issue(it + 1, raB, rbB);
    compute(it);
    if (it + 1 < 21){
      __syncthreads();
      commit(raB, rbB);
      __syncthreads();
      if (it + 2 < 21) issue(it + 2, raA, rbA);
      compute(it + 1);
    }
  }

  // epilogue: GRU gates
  const int e = nb * 32 + wn * 16 + (lane & 15);
  const float bR = bih[e] + bhh[e];
  const float bZ = bih[EE + e] + bhh[EE + e];
  const float biN = bih[2*EE + e];
  const float bhN = bhh[2*EE + e];
#pragma unroll
  for (int rf = 0; rf < 2; ++rf){
    const int brow0 = mb * 64 + wm * 32 + rf * 16 + (lane >> 4) * 4;
#pragma unroll
    for (int j = 0; j < 4; ++j){
      const int b = brow0 + j;
      const float r = jsigmoid(accR[rf][j] + bR);
      const float z = jsigmoid(accZ[rf][j] + bZ);
      const float n = tanhf(accNI[rf][j] + biN + r * (accNH[rf][j] + bhN));
      const float hp = hin_f[(long)b * EE + e];
      const float hn = (1.0f - z) * n + z * hp;
      hout_f[(long)b * EE + e] = hn;
      hout_b[(long)b * EE + e] = f2bf(hn);
      int li = lengths[b] - 1;
      if (li < 0) li += TT;
      if (t == li) last[(long)b * EE + e] = hn;
    }
  }
}

// ---------------- BatchNorm ----------------
__global__ __launch_bounds__(256) void k_bn_stats(
    const float* __restrict__ last, float* __restrict__ mv)
{
  const int e = blockIdx.x * 256 + threadIdx.x;
  if (e >= EE) return;
  float s = 0.0f;
  for (int b = 0; b < BB; ++b) s += last[(long)b * EE + e];
  const float mean = s / 128.0f;
  float v = 0.0f;
  for (int b = 0; b < BB; ++b){ float d = last[(long)b * EE + e] - mean; v += d * d; }
  mv[e] = mean;
  mv[EE + e] = v / 128.0f;
}

__global__ __launch_bounds__(256) void k_bn_apply(
    const float* __restrict__ last, const float* __restrict__ mv,
    const float* __restrict__ gamma, const float* __restrict__ beta,
    float* __restrict__ out)
{
  const int gid = blockIdx.x * 256 + threadIdx.x;
  const int e = gid & 1023;
  const float xm = last[gid] - mv[e];
  out[gid] = gamma[e] * xm / sqrtf(mv[EE + e] + 1e-5f) + beta[e];
}

// ---------------- launcher ----------------
extern "C" void kernel_launch(void* const* d_in, const int* in_sizes, int n_in,
                              void* d_out, int out_size, void* d_ws, size_t ws_size,
                              hipStream_t stream)
{
  (void)in_sizes; (void)n_in; (void)out_size;
  const float* x     = (const float*)d_in[0];
  const int*   lens  = (const int*)d_in[1];
  const float* Wih_c = (const float*)d_in[3];
  const float* Whh_c = (const float*)d_in[4];
  const float* bih_c = (const float*)d_in[5];
  const float* bhh_c = (const float*)d_in[6];
  const float* Wmu   = (const float*)d_in[7];
  const float* bmu   = (const float*)d_in[8];
  const float* Wlv   = (const float*)d_in[9];
  const float* blv   = (const float*)d_in[10];
  const float* Wih_r = (const float*)d_in[11];
  const float* Whh_r = (const float*)d_in[12];
  const float* bih_r = (const float*)d_in[13];
  const float* bhh_r = (const float*)d_in[14];
  const float* gam   = (const float*)d_in[15];
  const float* bet   = (const float*)d_in[16];
  float* out = (float*)d_out;

  uint32_t nk[4][2];
  for (uint32_t i = 0; i < 4; ++i) tf2x32(0u, 42u, 0u, i, &nk[i][0], &nk[i][1]);

  float* ws = (float*)d_ws;
  size_t off = 0;
  float* U       = ws + off; off += 16384000;  // gi_all then mu_all (aliased)
  float* hx_all  = ws + off; off += 4915200;
  float* lv_all  = ws + off; off += 32768;
  float* hx0     = ws + off; off += 38400;
  float* h2f0    = ws + off; off += 131072;
  float* h2f1    = ws + off; off += 131072;
  float* lastb   = ws + off; off += 131072;
  float* mv      = ws + off; off += 2048;
  unsigned short* texts_b = (unsigned short*)(ws + off); off += 2621440; // 16384x320 bf16
  unsigned short* h2b0    = (unsigned short*)(ws + off); off += 65536;
  unsigned short* h2b1    = (unsigned short*)(ws + off); off += 65536;
  unsigned short* Whb     = (unsigned short*)(ws + off); off += 1572864; // 3072x1024 bf16
  unsigned short* Wib     = (unsigned short*)(ws + off); off += 491520;  // 3072x320 bf16
  if (ws_size < off * sizeof(float)) return;

  hipMemsetAsync(hx0, 0, 38400 * sizeof(float), stream);
  hipMemsetAsync(h2f0, 0, 131072 * sizeof(float), stream);
  hipMemsetAsync(h2b0, 0, 131072 * sizeof(unsigned short), stream);

  // bf16 weight conversions (stage-2)
  k_cvt_whh<<<dim3(12288), 256, 0, stream>>>(Whh_r, Whb);
  k_cvt_wih<<<dim3(3840), 256, 0, stream>>>(Wih_r, Wib);

  // stage-1 input projection
  k_gemm_gi<<<dim3(15, 256), 256, 0, stream>>>(x, Wih_c, bih_c, U);
  // stage-1 recurrence
  for (int t = 0; t < TT; ++t){
    const float* hp = (t == 0) ? hx0 : (hx_all + (long)(t - 1) * BB * DD);
    k_hx_step<<<dim3(38, 2), 256, 0, stream>>>(t, hp, Whh_c, bhh_c, U,
                                               hx_all + (long)t * BB * DD);
  }
  // batched mu / lv / sampling
  k_gemm_mu<<<dim3(16, 256), 256, 0, stream>>>(x, hx_all, Wmu, bmu, U);
  k_lv<<<dim3(4096), 256, 0, stream>>>(x, hx_all, Wlv, blv, lv_all);
  k_sample<<<dim3(16384), 256, 0, stream>>>(x, U, lv_all, texts_b, out,
      nk[0][0], nk[0][1], nk[1][0], nk[1][1],
      nk[2][0], nk[2][1], nk[3][0], nk[3][1]);
  // stage-2 recurrence (fused MFMA + gates, h double-buffered)
  for (int t = 0; t < TT; ++t){
    const int pi = t & 1;
    const unsigned short* hib = pi ? h2b1 : h2b0;
    const float*          hif = pi ? h2f1 : h2f0;
    unsigned short* hob = pi ? h2b0 : h2b1;
    float*          hof = pi ? h2f0 : h2f1;
    k_step2<<<dim3(32, 2), 256, 0, stream>>>(t, hib, hif, texts_b, Whb, Wib,
                                             bih_r, bhh_r, lens, hof, hob, lastb);
  }
  // batchnorm
  k_bn_stats<<<dim3(4), 256, 0, stream>>>(lastb, mv);
  k_bn_apply<<<dim3(512), 256, 0, stream>>>(lastb, mv, gam, bet, out);
}

// Round 3
// 7166.401 us; speedup vs baseline: 1.1427x; 1.1427x over previous
//
#include <hip/hip_runtime.h>
#include <stdint.h>

#define TT 128
#define BB 128
#define DD 300
#define EE 1024
#define GG 900
#define NMU 1000
#define ASP 500

#define OUT_SLOG 131072
#define OUT_ACT  163840
#define OUT_LOGP 196608

// ---------------- threefry2x32 (JAX, 20 rounds) ----------------
__host__ __device__ static inline uint32_t rotl32(uint32_t x, int r){
  return (x << r) | (x >> (32 - r));
}

__host__ __device__ static inline void tf2x32(uint32_t k0, uint32_t k1,
                                              uint32_t x0, uint32_t x1,
                                              uint32_t* o0, uint32_t* o1){
  uint32_t ks2 = k0 ^ k1 ^ 0x1BD11BDAu;
#define TFR(r) { x0 += x1; x1 = rotl32(x1, r); x1 ^= x0; }
  x0 += k0; x1 += k1;
  TFR(13) TFR(15) TFR(26) TFR(6)
  x0 += k1; x1 += ks2 + 1u;
  TFR(17) TFR(29) TFR(16) TFR(24)
  x0 += ks2; x1 += k0 + 2u;
  TFR(13) TFR(15) TFR(26) TFR(6)
  x0 += k0; x1 += k1 + 3u;
  TFR(17) TFR(29) TFR(16) TFR(24)
  x0 += k1; x1 += ks2 + 4u;
  TFR(13) TFR(15) TFR(26) TFR(6)
  x0 += ks2; x1 += k0 + 5u;
#undef TFR
  *o0 = x0; *o1 = x1;
}

__device__ static inline uint32_t rng32(uint32_t k0, uint32_t k1, uint32_t idx){
  uint32_t a, b;
  tf2x32(k0, k1, 0u, idx, &a, &b);
  return a ^ b;
}

__device__ static inline float u01(uint32_t bits){
  return __uint_as_float((bits >> 9) | 0x3f800000u) - 1.0f;
}

__device__ static inline float jgumbel(uint32_t k0, uint32_t k1, uint32_t idx){
  float u = u01(rng32(k0, k1, idx));
  float l1 = logf(u + 1e-20f);
  return -logf(-l1 + 1e-20f);
}

__device__ static inline float erfinv32(float x){   // XLA ErfInv32 (Giles)
  float w = -log1pf(-x * x);
  float p;
  if (w < 5.0f){
    w = w - 2.5f;
    p = 2.81022636e-08f;
    p = 3.43273939e-07f  + p * w;
    p = -3.5233877e-06f  + p * w;
    p = -4.39150654e-06f + p * w;
    p = 0.00021858087f   + p * w;
    p = -0.00125372503f  + p * w;
    p = -0.00417768164f  + p * w;
    p = 0.246640727f     + p * w;
    p = 1.50140941f      + p * w;
  } else {
    w = sqrtf(w) - 3.0f;
    p = -0.000200214257f;
    p = 0.000100950558f  + p * w;
    p = 0.00134934322f   + p * w;
    p = -0.00367342844f  + p * w;
    p = 0.00573950773f   + p * w;
    p = -0.0076224613f   + p * w;
    p = 0.00943887047f   + p * w;
    p = 1.00167406f      + p * w;
    p = 2.83297682f      + p * w;
  }
  return p * x;
}

__device__ static inline float jnormal(uint32_t k0, uint32_t k1, uint32_t idx){
  float u = u01(rng32(k0, k1, idx));
  const float lo = -0.99999994f;
  float v = u * 2.0f + lo;
  v = fmaxf(lo, v);
  return 1.41421356237f * erfinv32(v);
}

__device__ static inline float jsigmoid(float x){
  return 1.0f / (1.0f + expf(-x));
}

__device__ static inline unsigned short f2bf(float f){   // RNE f32->bf16
  uint32_t u = __float_as_uint(f);
  uint32_t r = (u + 0x7fffu + ((u >> 16) & 1u)) >> 16;
  return (unsigned short)r;
}

// ---------------- GEMM1: gi_all[r=(t*BB+b)][900] = x@Wih_c^T + bih ----------------
__global__ __launch_bounds__(256) void k_gemm_gi(
    const float* __restrict__ X, const float* __restrict__ W,
    const float* __restrict__ bias, float* __restrict__ C)
{
  __shared__ float As[16][64];
  __shared__ float Bs[16][68];
  const int tid = threadIdx.x;
  const int rbase = blockIdx.y * 64;
  const int cbase = blockIdx.x * 64;
  const int tx = tid & 15, ty = tid >> 4;
  const int lrow = tid >> 2, lq = tid & 3;

  const int rg = rbase + lrow;
  const float* xrow = X + ((long)(rg & 127) * TT + (rg >> 7)) * DD;
  const int wj = cbase + lrow;

  float4 c0 = {0,0,0,0}, c1 = {0,0,0,0}, c2 = {0,0,0,0}, c3 = {0,0,0,0};

  for (int k0 = 0; k0 < DD; k0 += 16){
    int k = k0 + lq * 4;
    float4 va = {0,0,0,0};
    if (k < DD) va = *(const float4*)(xrow + k);
    As[lq*4+0][lrow] = va.x; As[lq*4+1][lrow] = va.y;
    As[lq*4+2][lrow] = va.z; As[lq*4+3][lrow] = va.w;
    float4 vb = {0,0,0,0};
    if (k < DD && wj < GG) vb = *(const float4*)(W + (long)wj * DD + k);
    Bs[lq*4+0][lrow] = vb.x; Bs[lq*4+1][lrow] = vb.y;
    Bs[lq*4+2][lrow] = vb.z; Bs[lq*4+3][lrow] = vb.w;
    __syncthreads();
#pragma unroll
    for (int kk = 0; kk < 16; ++kk){
      const float4 a = *(const float4*)&As[kk][ty * 4];
      const float4 b = *(const float4*)&Bs[kk][tx * 4];
      c0.x += a.x*b.x; c0.y += a.x*b.y; c0.z += a.x*b.z; c0.w += a.x*b.w;
      c1.x += a.y*b.x; c1.y += a.y*b.y; c1.z += a.y*b.z; c1.w += a.y*b.w;
      c2.x += a.z*b.x; c2.y += a.z*b.y; c2.z += a.z*b.z; c2.w += a.z*b.w;
      c3.x += a.w*b.x; c3.y += a.w*b.y; c3.z += a.w*b.z; c3.w += a.w*b.w;
    }
    __syncthreads();
  }
  const int ci = cbase + tx * 4;
  const int r0 = rbase + ty * 4;
  float bv[4];
#pragma unroll
  for (int j = 0; j < 4; ++j) bv[j] = (ci + j < GG) ? bias[ci + j] : 0.0f;
  float4 rows[4] = {c0, c1, c2, c3};
#pragma unroll
  for (int i = 0; i < 4; ++i){
    float vals[4] = {rows[i].x + bv[0], rows[i].y + bv[1],
                     rows[i].z + bv[2], rows[i].w + bv[3]};
    float* crow = C + (long)(r0 + i) * GG;
    if (ci + 3 < GG){
      float4 st = {vals[0], vals[1], vals[2], vals[3]};
      *(float4*)(crow + ci) = st;
    } else {
#pragma unroll
      for (int j = 0; j < 4; ++j) if (ci + j < GG) crow[ci + j] = vals[j];
    }
  }
}

// ---------------- GEMM-mu: mu_all[r][1000] = relu([img|hx])@Wmu^T + bmu ----------------
__global__ __launch_bounds__(256) void k_gemm_mu(
    const float* __restrict__ X, const float* __restrict__ HX,
    const float* __restrict__ W, const float* __restrict__ bias,
    float* __restrict__ C)
{
  __shared__ float As[16][64];
  __shared__ float Bs[16][68];
  const int tid = threadIdx.x;
  const int rbase = blockIdx.y * 64;
  const int cbase = blockIdx.x * 64;
  const int tx = tid & 15, ty = tid >> 4;
  const int lrow = tid >> 2, lq = tid & 3;

  const int rg = rbase + lrow;
  const float* xrow = X + ((long)(rg & 127) * TT + (rg >> 7)) * DD;
  const float* hrow = HX + (long)rg * DD;
  const int wj = cbase + lrow;

  float4 c0 = {0,0,0,0}, c1 = {0,0,0,0}, c2 = {0,0,0,0}, c3 = {0,0,0,0};

  for (int k0 = 0; k0 < 600; k0 += 16){
    int k = k0 + lq * 4;
    float4 va = {0,0,0,0};
    if (k < 300)      va = *(const float4*)(xrow + k);
    else if (k < 600) va = *(const float4*)(hrow + (k - 300));
    va.x = fmaxf(va.x, 0.0f); va.y = fmaxf(va.y, 0.0f);
    va.z = fmaxf(va.z, 0.0f); va.w = fmaxf(va.w, 0.0f);
    As[lq*4+0][lrow] = va.x; As[lq*4+1][lrow] = va.y;
    As[lq*4+2][lrow] = va.z; As[lq*4+3][lrow] = va.w;
    float4 vb = {0,0,0,0};
    if (k < 600 && wj < NMU) vb = *(const float4*)(W + (long)wj * 600 + k);
    Bs[lq*4+0][lrow] = vb.x; Bs[lq*4+1][lrow] = vb.y;
    Bs[lq*4+2][lrow] = vb.z; Bs[lq*4+3][lrow] = vb.w;
    __syncthreads();
#pragma unroll
    for (int kk = 0; kk < 16; ++kk){
      const float4 a = *(const float4*)&As[kk][ty * 4];
      const float4 b = *(const float4*)&Bs[kk][tx * 4];
      c0.x += a.x*b.x; c0.y += a.x*b.y; c0.z += a.x*b.z; c0.w += a.x*b.w;
      c1.x += a.y*b.x; c1.y += a.y*b.y; c1.z += a.y*b.z; c1.w += a.y*b.w;
      c2.x += a.z*b.x; c2.y += a.z*b.y; c2.z += a.z*b.z; c2.w += a.z*b.w;
      c3.x += a.w*b.x; c3.y += a.w*b.y; c3.z += a.w*b.z; c3.w += a.w*b.w;
    }
    __syncthreads();
  }
  const int ci = cbase + tx * 4;
  const int r0 = rbase + ty * 4;
  float bv[4];
#pragma unroll
  for (int j = 0; j < 4; ++j) bv[j] = (ci + j < NMU) ? bias[ci + j] : 0.0f;
  float4 rows[4] = {c0, c1, c2, c3};
#pragma unroll
  for (int i = 0; i < 4; ++i){
    float vals[4] = {rows[i].x + bv[0], rows[i].y + bv[1],
                     rows[i].z + bv[2], rows[i].w + bv[3]};
    float* crow = C + (long)(r0 + i) * NMU;
    if (ci + 3 < NMU){
      float4 st = {vals[0], vals[1], vals[2], vals[3]};
      *(float4*)(crow + ci) = st;
    } else {
#pragma unroll
      for (int j = 0; j < 4; ++j) if (ci + j < NMU) crow[ci + j] = vals[j];
    }
  }
}

// ---------------- lv (pre-softplus), wave-per-row ----------------
__global__ __launch_bounds__(256) void k_lv(
    const float* __restrict__ X, const float* __restrict__ HX,
    const float* __restrict__ Wlv, const float* __restrict__ blv,
    float* __restrict__ LV)
{
  const int r = blockIdx.x * 4 + (threadIdx.x >> 6);   // 16384 rows
  const int lane = threadIdx.x & 63;
  const float* xr = X + ((long)(r & 127) * TT + (r >> 7)) * DD;
  const float* hr = HX + (long)r * DD;
  float a0 = 0.0f, a1 = 0.0f;
  for (int k = lane; k < DD; k += 64){
    float v = fmaxf(xr[k], 0.0f);
    a0 += v * Wlv[k];       a1 += v * Wlv[600 + k];
    float w = fmaxf(hr[k], 0.0f);
    a0 += w * Wlv[300 + k]; a1 += w * Wlv[900 + k];
  }
#pragma unroll
  for (int off = 32; off > 0; off >>= 1){
    a0 += __shfl_down(a0, off);
    a1 += __shfl_down(a1, off);
  }
  if (lane == 0){
    LV[(long)r * 2 + 0] = a0 + blv[0];
    LV[(long)r * 2 + 1] = a1 + blv[1];
  }
}

// ---------------- Whh_c pack: Wp[kq][1024 j][4 c] = Whh_c[j][4kq+c] ----------------
__global__ __launch_bounds__(256) void k_pack_whh(
    const float* __restrict__ W, float* __restrict__ Wp)
{
  const int i = blockIdx.x * 256 + threadIdx.x;   // 75*1024
  const int kq = i >> 10, j = i & 1023;
  float4 v = {0,0,0,0};
  if (kq < 75 && j < GG){
    const float* s = W + (long)j * DD + kq * 4;
    v.x = s[0]; v.y = s[1]; v.z = s[2]; v.w = s[3];
  }
  *(float4*)(Wp + (long)i * 4) = v;
}

// ---------------- stage-1 persistent: 64 blocks x 512 thr, block owns 2 batch rows ----------------
#define DOT4(A, Wv, Hv) \
  A = fmaf((Wv).x,(Hv).x, fmaf((Wv).y,(Hv).y, fmaf((Wv).z,(Hv).z, fmaf((Wv).w,(Hv).w, (A)))))

__global__ __launch_bounds__(512) void k_stage1(
    const float* __restrict__ Wp, const float* __restrict__ bhh,
    const float* __restrict__ gi_all, float* __restrict__ hx_all)
{
  __shared__ float hs[2][304];
  __shared__ float ghs[2][912];
  __shared__ float bhs[912];
  const int tid = threadIdx.x;
  const int b0 = blockIdx.x * 2;
  for (int j = tid; j < GG; j += 512) bhs[j] = bhh[j];
  for (int j = tid; j < 304; j += 512){ hs[0][j] = 0.f; hs[1][j] = 0.f; }
  __syncthreads();

  const int j0 = tid * 2;
  for (int t = 0; t < TT; ++t){
    float a00 = 0.f, a01 = 0.f, a10 = 0.f, a11 = 0.f;
#pragma unroll 5
    for (int kq = 0; kq < 75; ++kq){
      const float* wp = Wp + ((long)kq * 1024 + j0) * 4;
      const float4 w0 = *(const float4*)(wp);
      const float4 w1 = *(const float4*)(wp + 4);
      const float4 h0v = *(const float4*)&hs[0][kq * 4];
      const float4 h1v = *(const float4*)&hs[1][kq * 4];
      DOT4(a00, w0, h0v); DOT4(a01, w0, h1v);
      DOT4(a10, w1, h0v); DOT4(a11, w1, h1v);
    }
    if (j0 < GG){
      ghs[0][j0]     = a00; ghs[1][j0]     = a01;
      ghs[0][j0 + 1] = a10; ghs[1][j0 + 1] = a11;
    }
    __syncthreads();
    for (int jj = tid; jj < DD; jj += 512){
#pragma unroll
      for (int b = 0; b < 2; ++b){
        const float* gi = gi_all + ((long)t * BB + b0 + b) * GG;
        const float r = jsigmoid(gi[jj]       + ghs[b][jj]       + bhs[jj]);
        const float z = jsigmoid(gi[300 + jj] + ghs[b][300 + jj] + bhs[300 + jj]);
        const float n = tanhf(gi[600 + jj] + r * (ghs[b][600 + jj] + bhs[600 + jj]));
        const float hv = hs[b][jj];
        const float hn = (1.0f - z) * n + z * hv;
        hs[b][jj] = hn;
        hx_all[((long)t * BB + b0 + b) * DD + jj] = hn;
      }
    }
    __syncthreads();
  }
}

// ---------------- sampling: softmax + gumbel-max + normal + texts(bf16) ----------------
__global__ __launch_bounds__(256) void k_sample(
    const float* __restrict__ X, const float* __restrict__ mu_all,
    const float* __restrict__ lv_all, unsigned short* __restrict__ texts_b,
    float* __restrict__ out,
    const uint32_t k0a, const uint32_t k0b, const uint32_t k1a, const uint32_t k1b,
    const uint32_t k2a, const uint32_t k2b, const uint32_t k3a, const uint32_t k3b)
{
  const int r = blockIdx.x;            // t*128 + b
  const int t = r >> 7, b = r & 127;
  const int tid = threadIdx.x;
  const int h = tid >> 7, lane = tid & 127;
  __shared__ float redf[256];
  __shared__ int   redi[256];
  __shared__ float yw[2], lyw[2], att_s[2];

  const uint32_t rowbase = (uint32_t)((t * 256 + b * 2 + h) * 500);
  float zv[4], ev[4];
  float lmax = -3.0e38f;
#pragma unroll
  for (int s = 0; s < 4; ++s){
    const int a = lane + s * 128;
    float z = -3.0e38f;
    if (a < ASP){
      float g = jgumbel(k0a, k0b, rowbase + (uint32_t)a);
      float m = mu_all[(long)r * NMU + h * ASP + a];
      z = (m + g) / 0.8f;
    }
    zv[s] = z;
    lmax = fmaxf(lmax, z);
  }
  redf[tid] = lmax;
  __syncthreads();
  for (int off = 64; off > 0; off >>= 1){
    if (lane < off) redf[tid] = fmaxf(redf[tid], redf[tid + off]);
    __syncthreads();
  }
  const float mx = redf[h << 7];
  __syncthreads();
  float lsum = 0.0f;
#pragma unroll
  for (int s = 0; s < 4; ++s){
    const int a = lane + s * 128;
    float e = 0.0f;
    if (a < ASP) e = expf(zv[s] - mx);
    ev[s] = e;
    lsum += e;
  }
  redf[tid] = lsum;
  __syncthreads();
  for (int off = 64; off > 0; off >>= 1){
    if (lane < off) redf[tid] += redf[tid + off];
    __syncthreads();
  }
  const float S = redf[h << 7];
  __syncthreads();
  float bestv = -3.0e38f;
  int besti = 0x7fffffff;
#pragma unroll
  for (int s = 0; s < 4; ++s){
    const int a = lane + s * 128;
    if (a < ASP){
      float y = ev[s] / S;
      float ly = logf(y);
      float gc = jgumbel(k1a, k1b, rowbase + (uint32_t)a);
      float val = ly + gc;
      if (val > bestv){ bestv = val; besti = a; }
    }
  }
  redf[tid] = bestv; redi[tid] = besti;
  __syncthreads();
  for (int off = 64; off > 0; off >>= 1){
    if (lane < off){
      float v2 = redf[tid + off]; int i2 = redi[tid + off];
      if (v2 > redf[tid] || (v2 == redf[tid] && i2 < redi[tid])){
        redf[tid] = v2; redi[tid] = i2;
      }
    }
    __syncthreads();
  }
  const int ind = redi[h << 7];
#pragma unroll
  for (int s = 0; s < 4; ++s){
    const int a = lane + s * 128;
    if (a == ind){
      float y = ev[s] / S;
      yw[h] = y;
      lyw[h] = logf(y);
    }
  }
  __syncthreads();
  if (lane == 0){
    const float yv = yw[h];
    const float ly = lyw[h];
    const float yh = (1.0f - yv) + yv;
    const float act = ((float)ind * yh) / 500.0f;
    const float lvr = lv_all[(long)r * 2 + h];
    const float lv = fmaxf(lvr, 0.0f) + log1pf(expf(-fabsf(lvr)));
    const float sd = expf(0.5f * lv);
    const uint32_t ei = (uint32_t)(r * 2 + h);
    const float e1 = jnormal(k2a, k2b, ei);
    const float e2 = jnormal(k3a, k3b, ei);
    const float s1 = act + sd * e1;
    const float s2 = act + sd * e2;
    const float dd = (s2 - act) / sd;
    const float lp = -0.5f * (dd * dd) - logf(sd) - 0.9189385332046727f;
    const float attv = 20.0f * jsigmoid(s1);
    out[OUT_SLOG + (long)b * 256 + t * 2 + h]  = ly;
    out[OUT_ACT  + (long)b * 256 + h * 128 + t] = act;
    out[OUT_LOGP + (long)b * 256 + h * 128 + t] = lp;
    att_s[h] = attv;
  }
  __syncthreads();
  const float* xr = X + ((long)b * TT + t) * DD;
  unsigned short* tr = texts_b + (long)r * 320;
  for (int j = tid; j < 320; j += 256){
    unsigned short o = 0;
    if (j < 300) o = f2bf(xr[j] * att_s[j / 150]);
    tr[j] = o;
  }
}

// ---------------- weight conversion to bf16 ----------------
__global__ __launch_bounds__(256) void k_cvt_whh(
    const float* __restrict__ W, unsigned short* __restrict__ O)
{
  const int i = blockIdx.x * 256 + threadIdx.x;   // 3072*1024
  O[i] = f2bf(W[i]);
}

__global__ __launch_bounds__(256) void k_cvt_wih(
    const float* __restrict__ W, unsigned short* __restrict__ O)
{
  const int i = blockIdx.x * 256 + threadIdx.x;   // 3072*320
  const int rw = i / 320, c = i - rw * 320;
  O[i] = (c < DD) ? f2bf(W[(long)rw * DD + c]) : (unsigned short)0;
}

// ---------------- stage-2 persistent: 64 blocks, t-loop + grid barrier ----------------
#define LDSB 8192
#define NBLK2 64

__global__ __launch_bounds__(256) void k_stage2(
    const unsigned short* __restrict__ texts_b,
    const unsigned short* __restrict__ Whb,
    const unsigned short* __restrict__ Wib,
    const float* __restrict__ bih, const float* __restrict__ bhh,
    const int* __restrict__ lengths,
    float* __restrict__ h2f0, float* __restrict__ h2f1,
    unsigned short* __restrict__ h2b0, unsigned short* __restrict__ h2b1,
    float* __restrict__ last,
    unsigned int* __restrict__ bar)
{
  __shared__ __align__(16) char lds[20480];    // A: 64x64 bf16 @0, B: 96x64 bf16 @8192
  const int tid = threadIdx.x;
  const int nb = blockIdx.x & 31, mb = blockIdx.x >> 5;
  const int wave = tid >> 6, lane = tid & 63;
  const int wm = wave >> 1, wn = wave & 1;

  using frag = __attribute__((ext_vector_type(8))) short;
  using f32x4 = __attribute__((ext_vector_type(4))) float;

  // per-thread invariants
  const int e = nb * 32 + wn * 16 + (lane & 15);
  const float bR = bih[e] + bhh[e];
  const float bZ = bih[EE + e] + bhh[EE + e];
  const float biN = bih[2*EE + e];
  const float bhN = bhh[2*EE + e];
  int li_arr[2][4];
#pragma unroll
  for (int rf = 0; rf < 2; ++rf){
    const int brow0 = mb * 64 + wm * 32 + rf * 16 + (lane >> 4) * 4;
#pragma unroll
    for (int j = 0; j < 4; ++j){
      int li = lengths[brow0 + j] - 1;
      if (li < 0) li += TT;
      li_arr[rf][j] = li;
    }
  }

  for (int t = 0; t < TT; ++t){
    const unsigned short* hin_b = (t & 1) ? h2b1 : h2b0;
    const float*          hin_f = (t & 1) ? h2f1 : h2f0;
    float*          hout_f = (t & 1) ? h2f0 : h2f1;
    unsigned short* hout_b = (t & 1) ? h2b0 : h2b1;

    f32x4 accR[2], accZ[2], accNH[2], accNI[2];
#pragma unroll
    for (int i = 0; i < 2; ++i){
      accR[i] = (f32x4){0.f,0.f,0.f,0.f}; accZ[i] = (f32x4){0.f,0.f,0.f,0.f};
      accNH[i] = (f32x4){0.f,0.f,0.f,0.f}; accNI[i] = (f32x4){0.f,0.f,0.f,0.f};
    }

    uint4 raA[2], rbA[3], raB[2], rbB[3];

    auto issue = [&](int it, uint4* ra, uint4* rb){
      if (it < 16){
        const unsigned short* A = hin_b + (long)(mb * 64) * EE + it * 64;
#pragma unroll
        for (int i = 0; i < 2; ++i){
          const int c = tid + i * 256, row = c >> 3, kq = c & 7;
          ra[i] = *(const uint4*)(A + (long)row * EE + kq * 8);
        }
        const unsigned short* Bs = Whb + (long)(nb * 32) * EE + it * 64;
#pragma unroll
        for (int i = 0; i < 3; ++i){
          const int c = tid + i * 256, row = c >> 3, kq = c & 7;
          rb[i] = *(const uint4*)(Bs + ((long)(row >> 5) * EE + (row & 31)) * EE + kq * 8);
        }
      } else {
        const int k0 = (it - 16) * 64;
        const unsigned short* A = texts_b + ((long)t * BB + mb * 64) * 320 + k0;
#pragma unroll
        for (int i = 0; i < 2; ++i){
          const int c = tid + i * 256, row = c >> 3, kq = c & 7;
          ra[i] = *(const uint4*)(A + (long)row * 320 + kq * 8);
        }
        const unsigned short* Bs = Wib + (long)(nb * 32) * 320 + k0;
#pragma unroll
        for (int i = 0; i < 3; ++i){
          const int c = tid + i * 256, row = c >> 3, kq = c & 7;
          rb[i] = *(const uint4*)(Bs + ((long)(row >> 5) * EE + (row & 31)) * 320 + kq * 8);
        }
      }
    };

    auto commit = [&](uint4* ra, uint4* rb){
#pragma unroll
      for (int i = 0; i < 2; ++i){
        const int c = tid + i * 256, row = c >> 3, kq = c & 7;
        const int off = (row * 128 + kq * 16) ^ ((row & 7) << 4);
        *(uint4*)(lds + off) = ra[i];
      }
#pragma unroll
      for (int i = 0; i < 3; ++i){
        const int c = tid + i * 256, row = c >> 3, kq = c & 7;
        const int off = (row * 128 + kq * 16) ^ ((row & 7) << 4);
        *(uint4*)(lds + LDSB + off) = rb[i];
      }
    };

    auto compute = [&](int it){
      const bool hid = (it < 16);
#pragma unroll
      for (int kf = 0; kf < 2; ++kf){
        frag af[2], bf[3];
#pragma unroll
        for (int rf = 0; rf < 2; ++rf){
          const int row = wm * 32 + rf * 16 + (lane & 15);
          const int off = (row * 128 + kf * 64 + (lane >> 4) * 16) ^ ((row & 7) << 4);
          af[rf] = *(const frag*)(lds + off);
        }
#pragma unroll
        for (int g = 0; g < 3; ++g){
          const int row = g * 32 + wn * 16 + (lane & 15);
          const int off = (row * 128 + kf * 64 + (lane >> 4) * 16) ^ ((row & 7) << 4);
          bf[g] = *(const frag*)(lds + LDSB + off);
        }
#pragma unroll
        for (int rf = 0; rf < 2; ++rf){
          accR[rf] = __builtin_amdgcn_mfma_f32_16x16x32_bf16(af[rf], bf[0], accR[rf], 0, 0, 0);
          accZ[rf] = __builtin_amdgcn_mfma_f32_16x16x32_bf16(af[rf], bf[1], accZ[rf], 0, 0, 0);
          if (hid) accNH[rf] = __builtin_amdgcn_mfma_f32_16x16x32_bf16(af[rf], bf[2], accNH[rf], 0, 0, 0);
          else     accNI[rf] = __builtin_amdgcn_mfma_f32_16x16x32_bf16(af[rf], bf[2], accNI[rf], 0, 0, 0);
        }
      }
    };

    issue(0, raA, rbA);
    for (int it = 0; it < 21; it += 2){
      __syncthreads();
      commit(raA, rbA);
      __syncthreads();
      if (it + 1 < 21) issue(it + 1, raB, rbB);
      compute(it);
      if (it + 1 < 21){
        __syncthreads();
        commit(raB, rbB);
        __syncthreads();
        if (it + 2 < 21) issue(it + 2, raA, rbA);
        compute(it + 1);
      }
    }

    // epilogue: GRU gates
#pragma unroll
    for (int rf = 0; rf < 2; ++rf){
      const int brow0 = mb * 64 + wm * 32 + rf * 16 + (lane >> 4) * 4;
#pragma unroll
      for (int j = 0; j < 4; ++j){
        const int b = brow0 + j;
        const float r = jsigmoid(accR[rf][j] + bR);
        const float z = jsigmoid(accZ[rf][j] + bZ);
        const float n = tanhf(accNI[rf][j] + biN + r * (accNH[rf][j] + bhN));
        const float hp = hin_f[(long)b * EE + e];
        const float hn = (1.0f - z) * n + z * hp;
        hout_f[(long)b * EE + e] = hn;
        hout_b[(long)b * EE + e] = f2bf(hn);
        if (t == li_arr[rf][j]) last[(long)b * EE + e] = hn;
      }
    }

    // grid barrier (monotonic counter; 64 co-resident blocks)
    if (t != TT - 1){
      __syncthreads();
      if (tid == 0){
        __threadfence();                       // release: flush L2 -> LLC
        atomicAdd(&bar[0], 1u);
        const unsigned int target = (unsigned int)NBLK2 * (unsigned int)(t + 1);
        while (atomicAdd(&bar[0], 0u) < target){ __builtin_amdgcn_s_sleep(2); }
        __threadfence();                       // acquire: invalidate stale L1/L2
      }
      __syncthreads();
    }
  }
}

// ---------------- BatchNorm ----------------
__global__ __launch_bounds__(256) void k_bn_stats(
    const float* __restrict__ last, float* __restrict__ mv)
{
  const int e = blockIdx.x * 256 + threadIdx.x;
  if (e >= EE) return;
  float s = 0.0f;
  for (int b = 0; b < BB; ++b) s += last[(long)b * EE + e];
  const float mean = s / 128.0f;
  float v = 0.0f;
  for (int b = 0; b < BB; ++b){ float d = last[(long)b * EE + e] - mean; v += d * d; }
  mv[e] = mean;
  mv[EE + e] = v / 128.0f;
}

__global__ __launch_bounds__(256) void k_bn_apply(
    const float* __restrict__ last, const float* __restrict__ mv,
    const float* __restrict__ gamma, const float* __restrict__ beta,
    float* __restrict__ out)
{
  const int gid = blockIdx.x * 256 + threadIdx.x;
  const int e = gid & 1023;
  const float xm = last[gid] - mv[e];
  out[gid] = gamma[e] * xm / sqrtf(mv[EE + e] + 1e-5f) + beta[e];
}

// ---------------- launcher ----------------
extern "C" void kernel_launch(void* const* d_in, const int* in_sizes, int n_in,
                              void* d_out, int out_size, void* d_ws, size_t ws_size,
                              hipStream_t stream)
{
  (void)in_sizes; (void)n_in; (void)out_size;
  const float* x     = (const float*)d_in[0];
  const int*   lens  = (const int*)d_in[1];
  const float* Wih_c = (const float*)d_in[3];
  const float* Whh_c = (const float*)d_in[4];
  const float* bih_c = (const float*)d_in[5];
  const float* bhh_c = (const float*)d_in[6];
  const float* Wmu   = (const float*)d_in[7];
  const float* bmu   = (const float*)d_in[8];
  const float* Wlv   = (const float*)d_in[9];
  const float* blv   = (const float*)d_in[10];
  const float* Wih_r = (const float*)d_in[11];
  const float* Whh_r = (const float*)d_in[12];
  const float* bih_r = (const float*)d_in[13];
  const float* bhh_r = (const float*)d_in[14];
  const float* gam   = (const float*)d_in[15];
  const float* bet   = (const float*)d_in[16];
  float* out = (float*)d_out;

  uint32_t nk[4][2];
  for (uint32_t i = 0; i < 4; ++i) tf2x32(0u, 42u, 0u, i, &nk[i][0], &nk[i][1]);

  float* ws = (float*)d_ws;
  size_t off = 0;
  float* U       = ws + off; off += 16384000;  // gi_all then mu_all (aliased)
  float* hx_all  = ws + off; off += 4915200;
  float* lv_all  = ws + off; off += 32768;
  float* Wp      = ws + off; off += 307200;    // packed Whh_c [75][1024][4]
  float* h2f0    = ws + off; off += 131072;
  float* h2f1    = ws + off; off += 131072;
  float* lastb   = ws + off; off += 131072;
  float* mv      = ws + off; off += 2048;
  unsigned int* bar = (unsigned int*)(ws + off); off += 16;
  unsigned short* texts_b = (unsigned short*)(ws + off); off += 2621440; // 16384x320 bf16
  unsigned short* h2b0    = (unsigned short*)(ws + off); off += 65536;
  unsigned short* h2b1    = (unsigned short*)(ws + off); off += 65536;
  unsigned short* Whb     = (unsigned short*)(ws + off); off += 1572864; // 3072x1024 bf16
  unsigned short* Wib     = (unsigned short*)(ws + off); off += 491520;  // 3072x320 bf16
  if (ws_size < off * sizeof(float)) return;

  hipMemsetAsync(h2f0, 0, 131072 * sizeof(float), stream);
  hipMemsetAsync(h2b0, 0, 131072 * sizeof(unsigned short), stream);
  hipMemsetAsync(bar, 0, 64, stream);

  // weight prep
  k_cvt_whh<<<dim3(12288), 256, 0, stream>>>(Whh_r, Whb);
  k_cvt_wih<<<dim3(3840), 256, 0, stream>>>(Wih_r, Wib);
  k_pack_whh<<<dim3(300), 256, 0, stream>>>(Whh_c, Wp);

  // stage-1 input projection + persistent recurrence
  k_gemm_gi<<<dim3(15, 256), 256, 0, stream>>>(x, Wih_c, bih_c, U);
  k_stage1<<<dim3(64), 512, 0, stream>>>(Wp, bhh_c, U, hx_all);

  // batched mu / lv / sampling
  k_gemm_mu<<<dim3(16, 256), 256, 0, stream>>>(x, hx_all, Wmu, bmu, U);
  k_lv<<<dim3(4096), 256, 0, stream>>>(x, hx_all, Wlv, blv, lv_all);
  k_sample<<<dim3(16384), 256, 0, stream>>>(x, U, lv_all, texts_b, out,
      nk[0][0], nk[0][1], nk[1][0], nk[1][1],
      nk[2][0], nk[2][1], nk[3][0], nk[3][1]);

  // stage-2 persistent recurrence
  k_stage2<<<dim3(NBLK2), 256, 0, stream>>>(texts_b, Whb, Wib, bih_r, bhh_r, lens,
                                            h2f0, h2f1, h2b0, h2b1, lastb, bar);

  // batchnorm
  k_bn_stats<<<dim3(4), 256, 0, stream>>>(lastb, mv);
  k_bn_apply<<<dim3(512), 256, 0, stream>>>(lastb, mv, gam, bet, out);
}

// Round 4
// 5506.043 us; speedup vs baseline: 1.4873x; 1.3016x over previous
//
#include <hip/hip_runtime.h>
#include <stdint.h>

#define TT 128
#define BB 128
#define DD 300
#define EE 1024
#define GG 900
#define NMU 1000
#define ASP 500

#define OUT_SLOG 131072
#define OUT_ACT  163840
#define OUT_LOGP 196608

// ---------------- threefry2x32 (JAX, 20 rounds) ----------------
__host__ __device__ static inline uint32_t rotl32(uint32_t x, int r){
  return (x << r) | (x >> (32 - r));
}

__host__ __device__ static inline void tf2x32(uint32_t k0, uint32_t k1,
                                              uint32_t x0, uint32_t x1,
                                              uint32_t* o0, uint32_t* o1){
  uint32_t ks2 = k0 ^ k1 ^ 0x1BD11BDAu;
#define TFR(r) { x0 += x1; x1 = rotl32(x1, r); x1 ^= x0; }
  x0 += k0; x1 += k1;
  TFR(13) TFR(15) TFR(26) TFR(6)
  x0 += k1; x1 += ks2 + 1u;
  TFR(17) TFR(29) TFR(16) TFR(24)
  x0 += ks2; x1 += k0 + 2u;
  TFR(13) TFR(15) TFR(26) TFR(6)
  x0 += k0; x1 += k1 + 3u;
  TFR(17) TFR(29) TFR(16) TFR(24)
  x0 += k1; x1 += ks2 + 4u;
  TFR(13) TFR(15) TFR(26) TFR(6)
  x0 += ks2; x1 += k0 + 5u;
#undef TFR
  *o0 = x0; *o1 = x1;
}

__device__ static inline uint32_t rng32(uint32_t k0, uint32_t k1, uint32_t idx){
  uint32_t a, b;
  tf2x32(k0, k1, 0u, idx, &a, &b);
  return a ^ b;
}

__device__ static inline float u01(uint32_t bits){
  return __uint_as_float((bits >> 9) | 0x3f800000u) - 1.0f;
}

__device__ static inline float jgumbel(uint32_t k0, uint32_t k1, uint32_t idx){
  float u = u01(rng32(k0, k1, idx));
  float l1 = logf(u + 1e-20f);
  return -logf(-l1 + 1e-20f);
}

__device__ static inline float erfinv32(float x){   // XLA ErfInv32 (Giles)
  float w = -log1pf(-x * x);
  float p;
  if (w < 5.0f){
    w = w - 2.5f;
    p = 2.81022636e-08f;
    p = 3.43273939e-07f  + p * w;
    p = -3.5233877e-06f  + p * w;
    p = -4.39150654e-06f + p * w;
    p = 0.00021858087f   + p * w;
    p = -0.00125372503f  + p * w;
    p = -0.00417768164f  + p * w;
    p = 0.246640727f     + p * w;
    p = 1.50140941f      + p * w;
  } else {
    w = sqrtf(w) - 3.0f;
    p = -0.000200214257f;
    p = 0.000100950558f  + p * w;
    p = 0.00134934322f   + p * w;
    p = -0.00367342844f  + p * w;
    p = 0.00573950773f   + p * w;
    p = -0.0076224613f   + p * w;
    p = 0.00943887047f   + p * w;
    p = 1.00167406f      + p * w;
    p = 2.83297682f      + p * w;
  }
  return p * x;
}

__device__ static inline float jnormal(uint32_t k0, uint32_t k1, uint32_t idx){
  float u = u01(rng32(k0, k1, idx));
  const float lo = -0.99999994f;
  float v = u * 2.0f + lo;
  v = fmaxf(lo, v);
  return 1.41421356237f * erfinv32(v);
}

__device__ static inline float jsigmoid(float x){
  return 1.0f / (1.0f + expf(-x));
}

__device__ static inline unsigned short f2bf(float f){   // RNE f32->bf16
  uint32_t u = __float_as_uint(f);
  uint32_t r = (u + 0x7fffu + ((u >> 16) & 1u)) >> 16;
  return (unsigned short)r;
}

// ---------------- GEMM1: gi_all[r=(t*BB+b)][900] = x@Wih_c^T + bih ----------------
__global__ __launch_bounds__(256) void k_gemm_gi(
    const float* __restrict__ X, const float* __restrict__ W,
    const float* __restrict__ bias, float* __restrict__ C)
{
  __shared__ float As[16][64];
  __shared__ float Bs[16][68];
  const int tid = threadIdx.x;
  const int rbase = blockIdx.y * 64;
  const int cbase = blockIdx.x * 64;
  const int tx = tid & 15, ty = tid >> 4;
  const int lrow = tid >> 2, lq = tid & 3;

  const int rg = rbase + lrow;
  const float* xrow = X + ((long)(rg & 127) * TT + (rg >> 7)) * DD;
  const int wj = cbase + lrow;

  float4 c0 = {0,0,0,0}, c1 = {0,0,0,0}, c2 = {0,0,0,0}, c3 = {0,0,0,0};

  for (int k0 = 0; k0 < DD; k0 += 16){
    int k = k0 + lq * 4;
    float4 va = {0,0,0,0};
    if (k < DD) va = *(const float4*)(xrow + k);
    As[lq*4+0][lrow] = va.x; As[lq*4+1][lrow] = va.y;
    As[lq*4+2][lrow] = va.z; As[lq*4+3][lrow] = va.w;
    float4 vb = {0,0,0,0};
    if (k < DD && wj < GG) vb = *(const float4*)(W + (long)wj * DD + k);
    Bs[lq*4+0][lrow] = vb.x; Bs[lq*4+1][lrow] = vb.y;
    Bs[lq*4+2][lrow] = vb.z; Bs[lq*4+3][lrow] = vb.w;
    __syncthreads();
#pragma unroll
    for (int kk = 0; kk < 16; ++kk){
      const float4 a = *(const float4*)&As[kk][ty * 4];
      const float4 b = *(const float4*)&Bs[kk][tx * 4];
      c0.x += a.x*b.x; c0.y += a.x*b.y; c0.z += a.x*b.z; c0.w += a.x*b.w;
      c1.x += a.y*b.x; c1.y += a.y*b.y; c1.z += a.y*b.z; c1.w += a.y*b.w;
      c2.x += a.z*b.x; c2.y += a.z*b.y; c2.z += a.z*b.z; c2.w += a.z*b.w;
      c3.x += a.w*b.x; c3.y += a.w*b.y; c3.z += a.w*b.z; c3.w += a.w*b.w;
    }
    __syncthreads();
  }
  const int ci = cbase + tx * 4;
  const int r0 = rbase + ty * 4;
  float bv[4];
#pragma unroll
  for (int j = 0; j < 4; ++j) bv[j] = (ci + j < GG) ? bias[ci + j] : 0.0f;
  float4 rows[4] = {c0, c1, c2, c3};
#pragma unroll
  for (int i = 0; i < 4; ++i){
    float vals[4] = {rows[i].x + bv[0], rows[i].y + bv[1],
                     rows[i].z + bv[2], rows[i].w + bv[3]};
    float* crow = C + (long)(r0 + i) * GG;
    if (ci + 3 < GG){
      float4 st = {vals[0], vals[1], vals[2], vals[3]};
      *(float4*)(crow + ci) = st;
    } else {
#pragma unroll
      for (int j = 0; j < 4; ++j) if (ci + j < GG) crow[ci + j] = vals[j];
    }
  }
}

// ---------------- GEMM-mu: mu_all[r][1000] = relu([img|hx])@Wmu^T + bmu ----------------
__global__ __launch_bounds__(256) void k_gemm_mu(
    const float* __restrict__ X, const float* __restrict__ HX,
    const float* __restrict__ W, const float* __restrict__ bias,
    float* __restrict__ C)
{
  __shared__ float As[16][64];
  __shared__ float Bs[16][68];
  const int tid = threadIdx.x;
  const int rbase = blockIdx.y * 64;
  const int cbase = blockIdx.x * 64;
  const int tx = tid & 15, ty = tid >> 4;
  const int lrow = tid >> 2, lq = tid & 3;

  const int rg = rbase + lrow;
  const float* xrow = X + ((long)(rg & 127) * TT + (rg >> 7)) * DD;
  const float* hrow = HX + (long)rg * DD;
  const int wj = cbase + lrow;

  float4 c0 = {0,0,0,0}, c1 = {0,0,0,0}, c2 = {0,0,0,0}, c3 = {0,0,0,0};

  for (int k0 = 0; k0 < 600; k0 += 16){
    int k = k0 + lq * 4;
    float4 va = {0,0,0,0};
    if (k < 300)      va = *(const float4*)(xrow + k);
    else if (k < 600) va = *(const float4*)(hrow + (k - 300));
    va.x = fmaxf(va.x, 0.0f); va.y = fmaxf(va.y, 0.0f);
    va.z = fmaxf(va.z, 0.0f); va.w = fmaxf(va.w, 0.0f);
    As[lq*4+0][lrow] = va.x; As[lq*4+1][lrow] = va.y;
    As[lq*4+2][lrow] = va.z; As[lq*4+3][lrow] = va.w;
    float4 vb = {0,0,0,0};
    if (k < 600 && wj < NMU) vb = *(const float4*)(W + (long)wj * 600 + k);
    Bs[lq*4+0][lrow] = vb.x; Bs[lq*4+1][lrow] = vb.y;
    Bs[lq*4+2][lrow] = vb.z; Bs[lq*4+3][lrow] = vb.w;
    __syncthreads();
#pragma unroll
    for (int kk = 0; kk < 16; ++kk){
      const float4 a = *(const float4*)&As[kk][ty * 4];
      const float4 b = *(const float4*)&Bs[kk][tx * 4];
      c0.x += a.x*b.x; c0.y += a.x*b.y; c0.z += a.x*b.z; c0.w += a.x*b.w;
      c1.x += a.y*b.x; c1.y += a.y*b.y; c1.z += a.y*b.z; c1.w += a.y*b.w;
      c2.x += a.z*b.x; c2.y += a.z*b.y; c2.z += a.z*b.z; c2.w += a.z*b.w;
      c3.x += a.w*b.x; c3.y += a.w*b.y; c3.z += a.w*b.z; c3.w += a.w*b.w;
    }
    __syncthreads();
  }
  const int ci = cbase + tx * 4;
  const int r0 = rbase + ty * 4;
  float bv[4];
#pragma unroll
  for (int j = 0; j < 4; ++j) bv[j] = (ci + j < NMU) ? bias[ci + j] : 0.0f;
  float4 rows[4] = {c0, c1, c2, c3};
#pragma unroll
  for (int i = 0; i < 4; ++i){
    float vals[4] = {rows[i].x + bv[0], rows[i].y + bv[1],
                     rows[i].z + bv[2], rows[i].w + bv[3]};
    float* crow = C + (long)(r0 + i) * NMU;
    if (ci + 3 < NMU){
      float4 st = {vals[0], vals[1], vals[2], vals[3]};
      *(float4*)(crow + ci) = st;
    } else {
#pragma unroll
      for (int j = 0; j < 4; ++j) if (ci + j < NMU) crow[ci + j] = vals[j];
    }
  }
}

// ---------------- lv (pre-softplus), wave-per-row ----------------
__global__ __launch_bounds__(256) void k_lv(
    const float* __restrict__ X, const float* __restrict__ HX,
    const float* __restrict__ Wlv, const float* __restrict__ blv,
    float* __restrict__ LV)
{
  const int r = blockIdx.x * 4 + (threadIdx.x >> 6);   // 16384 rows
  const int lane = threadIdx.x & 63;
  const float* xr = X + ((long)(r & 127) * TT + (r >> 7)) * DD;
  const float* hr = HX + (long)r * DD;
  float a0 = 0.0f, a1 = 0.0f;
  for (int k = lane; k < DD; k += 64){
    float v = fmaxf(xr[k], 0.0f);
    a0 += v * Wlv[k];       a1 += v * Wlv[600 + k];
    float w = fmaxf(hr[k], 0.0f);
    a0 += w * Wlv[300 + k]; a1 += w * Wlv[900 + k];
  }
#pragma unroll
  for (int off = 32; off > 0; off >>= 1){
    a0 += __shfl_down(a0, off);
    a1 += __shfl_down(a1, off);
  }
  if (lane == 0){
    LV[(long)r * 2 + 0] = a0 + blv[0];
    LV[(long)r * 2 + 1] = a1 + blv[1];
  }
}

// ---------------- Whh_c pack: Wp[kq][1024 j][4 c] = Whh_c[j][4kq+c] ----------------
__global__ __launch_bounds__(256) void k_pack_whh(
    const float* __restrict__ W, float* __restrict__ Wp)
{
  const int i = blockIdx.x * 256 + threadIdx.x;   // 75*1024
  const int kq = i >> 10, j = i & 1023;
  float4 v = {0,0,0,0};
  if (kq < 75 && j < GG){
    const float* s = W + (long)j * DD + kq * 4;
    v.x = s[0]; v.y = s[1]; v.z = s[2]; v.w = s[3];
  }
  *(float4*)(Wp + (long)i * 4) = v;
}

// ---------------- stage-1 persistent: 64 blocks x 512 thr, block owns 2 batch rows ----------------
#define DOT4(A, Wv, Hv) \
  A = fmaf((Wv).x,(Hv).x, fmaf((Wv).y,(Hv).y, fmaf((Wv).z,(Hv).z, fmaf((Wv).w,(Hv).w, (A)))))

__global__ __launch_bounds__(512) void k_stage1(
    const float* __restrict__ Wp, const float* __restrict__ bhh,
    const float* __restrict__ gi_all, float* __restrict__ hx_all)
{
  __shared__ float hs[2][304];
  __shared__ float ghs[2][912];
  __shared__ float bhs[912];
  const int tid = threadIdx.x;
  const int b0 = blockIdx.x * 2;
  for (int j = tid; j < GG; j += 512) bhs[j] = bhh[j];
  for (int j = tid; j < 304; j += 512){ hs[0][j] = 0.f; hs[1][j] = 0.f; }
  __syncthreads();

  const int j0 = tid * 2;
  for (int t = 0; t < TT; ++t){
    float a00 = 0.f, a01 = 0.f, a10 = 0.f, a11 = 0.f;
#pragma unroll 5
    for (int kq = 0; kq < 75; ++kq){
      const float* wp = Wp + ((long)kq * 1024 + j0) * 4;
      const float4 w0 = *(const float4*)(wp);
      const float4 w1 = *(const float4*)(wp + 4);
      const float4 h0v = *(const float4*)&hs[0][kq * 4];
      const float4 h1v = *(const float4*)&hs[1][kq * 4];
      DOT4(a00, w0, h0v); DOT4(a01, w0, h1v);
      DOT4(a10, w1, h0v); DOT4(a11, w1, h1v);
    }
    if (j0 < GG){
      ghs[0][j0]     = a00; ghs[1][j0]     = a01;
      ghs[0][j0 + 1] = a10; ghs[1][j0 + 1] = a11;
    }
    __syncthreads();
    for (int jj = tid; jj < DD; jj += 512){
#pragma unroll
      for (int b = 0; b < 2; ++b){
        const float* gi = gi_all + ((long)t * BB + b0 + b) * GG;
        const float r = jsigmoid(gi[jj]       + ghs[b][jj]       + bhs[jj]);
        const float z = jsigmoid(gi[300 + jj] + ghs[b][300 + jj] + bhs[300 + jj]);
        const float n = tanhf(gi[600 + jj] + r * (ghs[b][600 + jj] + bhs[600 + jj]));
        const float hv = hs[b][jj];
        const float hn = (1.0f - z) * n + z * hv;
        hs[b][jj] = hn;
        hx_all[((long)t * BB + b0 + b) * DD + jj] = hn;
      }
    }
    __syncthreads();
  }
}

// ---------------- sampling: softmax + gumbel-max + normal + texts(bf16) ----------------
__global__ __launch_bounds__(256) void k_sample(
    const float* __restrict__ X, const float* __restrict__ mu_all,
    const float* __restrict__ lv_all, unsigned short* __restrict__ texts_b,
    float* __restrict__ out,
    const uint32_t k0a, const uint32_t k0b, const uint32_t k1a, const uint32_t k1b,
    const uint32_t k2a, const uint32_t k2b, const uint32_t k3a, const uint32_t k3b)
{
  const int r = blockIdx.x;            // t*128 + b
  const int t = r >> 7, b = r & 127;
  const int tid = threadIdx.x;
  const int h = tid >> 7, lane = tid & 127;
  __shared__ float redf[256];
  __shared__ int   redi[256];
  __shared__ float yw[2], lyw[2], att_s[2];

  const uint32_t rowbase = (uint32_t)((t * 256 + b * 2 + h) * 500);
  float zv[4], ev[4];
  float lmax = -3.0e38f;
#pragma unroll
  for (int s = 0; s < 4; ++s){
    const int a = lane + s * 128;
    float z = -3.0e38f;
    if (a < ASP){
      float g = jgumbel(k0a, k0b, rowbase + (uint32_t)a);
      float m = mu_all[(long)r * NMU + h * ASP + a];
      z = (m + g) / 0.8f;
    }
    zv[s] = z;
    lmax = fmaxf(lmax, z);
  }
  redf[tid] = lmax;
  __syncthreads();
  for (int off = 64; off > 0; off >>= 1){
    if (lane < off) redf[tid] = fmaxf(redf[tid], redf[tid + off]);
    __syncthreads();
  }
  const float mx = redf[h << 7];
  __syncthreads();
  float lsum = 0.0f;
#pragma unroll
  for (int s = 0; s < 4; ++s){
    const int a = lane + s * 128;
    float e = 0.0f;
    if (a < ASP) e = expf(zv[s] - mx);
    ev[s] = e;
    lsum += e;
  }
  redf[tid] = lsum;
  __syncthreads();
  for (int off = 64; off > 0; off >>= 1){
    if (lane < off) redf[tid] += redf[tid + off];
    __syncthreads();
  }
  const float S = redf[h << 7];
  __syncthreads();
  float bestv = -3.0e38f;
  int besti = 0x7fffffff;
#pragma unroll
  for (int s = 0; s < 4; ++s){
    const int a = lane + s * 128;
    if (a < ASP){
      float y = ev[s] / S;
      float ly = logf(y);
      float gc = jgumbel(k1a, k1b, rowbase + (uint32_t)a);
      float val = ly + gc;
      if (val > bestv){ bestv = val; besti = a; }
    }
  }
  redf[tid] = bestv; redi[tid] = besti;
  __syncthreads();
  for (int off = 64; off > 0; off >>= 1){
    if (lane < off){
      float v2 = redf[tid + off]; int i2 = redi[tid + off];
      if (v2 > redf[tid] || (v2 == redf[tid] && i2 < redi[tid])){
        redf[tid] = v2; redi[tid] = i2;
      }
    }
    __syncthreads();
  }
  const int ind = redi[h << 7];
#pragma unroll
  for (int s = 0; s < 4; ++s){
    const int a = lane + s * 128;
    if (a == ind){
      float y = ev[s] / S;
      yw[h] = y;
      lyw[h] = logf(y);
    }
  }
  __syncthreads();
  if (lane == 0){
    const float yv = yw[h];
    const float ly = lyw[h];
    const float yh = (1.0f - yv) + yv;
    const float act = ((float)ind * yh) / 500.0f;
    const float lvr = lv_all[(long)r * 2 + h];
    const float lv = fmaxf(lvr, 0.0f) + log1pf(expf(-fabsf(lvr)));
    const float sd = expf(0.5f * lv);
    const uint32_t ei = (uint32_t)(r * 2 + h);
    const float e1 = jnormal(k2a, k2b, ei);
    const float e2 = jnormal(k3a, k3b, ei);
    const float s1 = act + sd * e1;
    const float s2 = act + sd * e2;
    const float dd = (s2 - act) / sd;
    const float lp = -0.5f * (dd * dd) - logf(sd) - 0.9189385332046727f;
    const float attv = 20.0f * jsigmoid(s1);
    out[OUT_SLOG + (long)b * 256 + t * 2 + h]  = ly;
    out[OUT_ACT  + (long)b * 256 + h * 128 + t] = act;
    out[OUT_LOGP + (long)b * 256 + h * 128 + t] = lp;
    att_s[h] = attv;
  }
  __syncthreads();
  const float* xr = X + ((long)b * TT + t) * DD;
  unsigned short* tr = texts_b + (long)r * 320;
  for (int j = tid; j < 320; j += 256){
    unsigned short o = 0;
    if (j < 300) o = f2bf(xr[j] * att_s[j / 150]);
    tr[j] = o;
  }
}

// ---------------- weight conversion to bf16 ----------------
__global__ __launch_bounds__(256) void k_cvt_whh(
    const float* __restrict__ W, unsigned short* __restrict__ O)
{
  const int i = blockIdx.x * 256 + threadIdx.x;   // 3072*1024
  O[i] = f2bf(W[i]);
}

__global__ __launch_bounds__(256) void k_cvt_wih(
    const float* __restrict__ W, unsigned short* __restrict__ O)
{
  const int i = blockIdx.x * 256 + threadIdx.x;   // 3072*320
  const int rw = i / 320, c = i - rw * 320;
  O[i] = (c < DD) ? f2bf(W[(long)rw * DD + c]) : (unsigned short)0;
}

// ---------------- stage-2 persistent, weight-resident LDS ----------------
// 64 blocks x 256 thr. Block owns output cols [bid*16, bid*16+16) x 3 gates.
// W (48 rows x 1344) LDS-resident (129,792B, 16B row pad). A streamed through
// 18,432B LDS chunk (K=64). texts chunks computed BEFORE barrier wait (no h dep).
#define NBLK2 64
#define WPITCH 2704   // bytes per W_lds row (1344*2 + 16)
#define APITCH 144    // bytes per A_lds row (64*2 + 16)

__global__ __launch_bounds__(256) void k_stage2(
    const unsigned short* __restrict__ texts_b,
    const unsigned short* __restrict__ Whb,
    const unsigned short* __restrict__ Wib,
    const float* __restrict__ bih, const float* __restrict__ bhh,
    const int* __restrict__ lengths,
    unsigned short* __restrict__ h2b0, unsigned short* __restrict__ h2b1,
    float* __restrict__ last,
    unsigned int* __restrict__ flags, unsigned int* __restrict__ go)
{
  __shared__ __align__(16) char lds[148224];   // W: 48*2704=129792 | A: 128*144=18432
  unsigned short* Wl = (unsigned short*)lds;
  char* Al = lds + 129792;

  const int tid = threadIdx.x;
  const int bid = blockIdx.x;
  const int e0 = bid * 16;
  const int wv = tid >> 6, lane = tid & 63;

  // ---- stage W into LDS once ----
  for (int s = tid; s < 48 * 168; s += 256){
    const int row = s / 168, q = s - row * 168;   // q: 16B unit within row
    const int g = row >> 4, n = row & 15;
    const long wrow = (long)g * EE + e0 + n;
    uint4 v;
    if (q < 128) v = *(const uint4*)(Whb + wrow * EE + q * 8);
    else         v = *(const uint4*)(Wib + wrow * 320 + (q - 128) * 8);
    *(uint4*)((char*)Wl + (long)row * WPITCH + q * 16) = v;
  }

  // per-thread invariants
  const int e = e0 + (lane & 15);
  const float bR = bih[e] + bhh[e];
  const float bZ = bih[EE + e] + bhh[EE + e];
  const float biN = bih[2*EE + e];
  const float bhN = bhh[2*EE + e];
  int li_arr[2][4];
  float hp[2][4];
#pragma unroll
  for (int rr = 0; rr < 2; ++rr){
#pragma unroll
    for (int j = 0; j < 4; ++j){
      const int row = (wv * 2 + rr) * 16 + (lane >> 4) * 4 + j;
      int l = lengths[row] - 1; if (l < 0) l += TT;
      li_arr[rr][j] = l;
      hp[rr][j] = 0.0f;
    }
  }
  __syncthreads();

  using frag = __attribute__((ext_vector_type(8))) short;
  using f32x4 = __attribute__((ext_vector_type(4))) float;

  uint4 sA[4], sB[4];

  for (int t = 0; t < TT; ++t){
    const unsigned short* hb = (t & 1) ? h2b1 : h2b0;
    unsigned short* ho = (t & 1) ? h2b0 : h2b1;
    const unsigned short* tx = texts_b + (long)t * BB * 320;

    f32x4 aR[2], aZ[2], aNH[2], aNI[2];
#pragma unroll
    for (int i = 0; i < 2; ++i){
      aR[i] = (f32x4){0.f,0.f,0.f,0.f};  aZ[i] = (f32x4){0.f,0.f,0.f,0.f};
      aNH[i] = (f32x4){0.f,0.f,0.f,0.f}; aNI[i] = (f32x4){0.f,0.f,0.f,0.f};
    }

    auto loadT = [&](int c, uint4* s){
      const int k0 = (c - 16) * 64;
#pragma unroll
      for (int i = 0; i < 4; ++i){
        const int sl = tid + i * 256, row = sl >> 3, kq = sl & 7;
        s[i] = *(const uint4*)(tx + (long)row * 320 + k0 + kq * 8);
      }
    };
    auto loadH = [&](int c, uint4* s){
      const int k0 = c * 64;
#pragma unroll
      for (int i = 0; i < 4; ++i){
        const int sl = tid + i * 256, row = sl >> 3, kq = sl & 7;
        s[i] = *(const uint4*)(hb + (long)row * EE + k0 + kq * 8);
      }
    };
    auto writeA = [&](uint4* s){
#pragma unroll
      for (int i = 0; i < 4; ++i){
        const int sl = tid + i * 256, row = sl >> 3, kq = sl & 7;
        *(uint4*)(Al + row * APITCH + kq * 16) = s[i];
      }
    };
    auto compute = [&](int c){
      const bool hid = (c < 16);
#pragma unroll
      for (int kf = 0; kf < 2; ++kf){
        frag af[2], bf[3];
#pragma unroll
        for (int rr = 0; rr < 2; ++rr){
          const int row = (wv * 2 + rr) * 16 + (lane & 15);
          af[rr] = *(const frag*)(Al + row * APITCH + kf * 64 + (lane >> 4) * 16);
        }
#pragma unroll
        for (int g = 0; g < 3; ++g){
          const int wr = g * 16 + (lane & 15);
          bf[g] = *(const frag*)((char*)Wl + (long)wr * WPITCH + c * 128 + kf * 64 + (lane >> 4) * 16);
        }
#pragma unroll
        for (int rr = 0; rr < 2; ++rr){
          aR[rr] = __builtin_amdgcn_mfma_f32_16x16x32_bf16(af[rr], bf[0], aR[rr], 0, 0, 0);
          aZ[rr] = __builtin_amdgcn_mfma_f32_16x16x32_bf16(af[rr], bf[1], aZ[rr], 0, 0, 0);
          if (hid) aNH[rr] = __builtin_amdgcn_mfma_f32_16x16x32_bf16(af[rr], bf[2], aNH[rr], 0, 0, 0);
          else     aNI[rr] = __builtin_amdgcn_mfma_f32_16x16x32_bf16(af[rr], bf[2], aNI[rr], 0, 0, 0);
        }
      }
    };

    // phase 1: texts chunks (no dependency on h) — hides barrier latency
    loadT(16, sA);
#pragma unroll
    for (int c = 16; c <= 20; ++c){
      __syncthreads();
      writeA((c & 1) ? sB : sA);
      if (c < 20){ if (c & 1) loadT(c + 1, sA); else loadT(c + 1, sB); }
      __syncthreads();
      compute(c);
    }

    // phase 2: wait for all blocks' h(t-1), then hidden chunks
    if (t > 0 && tid == 0){
      while (__hip_atomic_load(go, __ATOMIC_RELAXED, __HIP_MEMORY_SCOPE_AGENT) < (unsigned)t)
        __builtin_amdgcn_s_sleep(4);
      __threadfence();
    }
    __syncthreads();

    loadH(0, sA);
#pragma unroll
    for (int c = 0; c <= 15; ++c){
      __syncthreads();
      writeA((c & 1) ? sB : sA);
      if (c < 15){ if (c & 1) loadH(c + 1, sA); else loadH(c + 1, sB); }
      __syncthreads();
      compute(c);
    }

    // epilogue: GRU gates, h in registers
#pragma unroll
    for (int rr = 0; rr < 2; ++rr){
#pragma unroll
      for (int j = 0; j < 4; ++j){
        const int row = (wv * 2 + rr) * 16 + (lane >> 4) * 4 + j;
        const float r = jsigmoid(aR[rr][j] + bR);
        const float z = jsigmoid(aZ[rr][j] + bZ);
        const float n = tanhf(aNI[rr][j] + biN + r * (aNH[rr][j] + bhN));
        const float hn = (1.0f - z) * n + z * hp[rr][j];
        hp[rr][j] = hn;
        ho[(long)row * EE + e] = f2bf(hn);
        if (t == li_arr[rr][j]) last[(long)row * EE + e] = hn;
      }
    }

    // arrive: per-block flag (no RMW), block 0 aggregates -> go
    __syncthreads();
    if (tid == 0){
      __threadfence();
      __hip_atomic_store(&flags[bid * 32], (unsigned)(t + 1),
                         __ATOMIC_RELAXED, __HIP_MEMORY_SCOPE_AGENT);
    }
    if (bid == 0){
      if (tid < NBLK2){
        while (__hip_atomic_load(&flags[tid * 32], __ATOMIC_RELAXED,
                                 __HIP_MEMORY_SCOPE_AGENT) < (unsigned)(t + 1))
          __builtin_amdgcn_s_sleep(4);
      }
      __syncthreads();
      if (tid == 0)
        __hip_atomic_store(go, (unsigned)(t + 1),
                           __ATOMIC_RELAXED, __HIP_MEMORY_SCOPE_AGENT);
    }
  }
}

// ---------------- BatchNorm ----------------
__global__ __launch_bounds__(256) void k_bn_stats(
    const float* __restrict__ last, float* __restrict__ mv)
{
  const int e = blockIdx.x * 256 + threadIdx.x;
  if (e >= EE) return;
  float s = 0.0f;
  for (int b = 0; b < BB; ++b) s += last[(long)b * EE + e];
  const float mean = s / 128.0f;
  float v = 0.0f;
  for (int b = 0; b < BB; ++b){ float d = last[(long)b * EE + e] - mean; v += d * d; }
  mv[e] = mean;
  mv[EE + e] = v / 128.0f;
}

__global__ __launch_bounds__(256) void k_bn_apply(
    const float* __restrict__ last, const float* __restrict__ mv,
    const float* __restrict__ gamma, const float* __restrict__ beta,
    float* __restrict__ out)
{
  const int gid = blockIdx.x * 256 + threadIdx.x;
  const int e = gid & 1023;
  const float xm = last[gid] - mv[e];
  out[gid] = gamma[e] * xm / sqrtf(mv[EE + e] + 1e-5f) + beta[e];
}

// ---------------- launcher ----------------
extern "C" void kernel_launch(void* const* d_in, const int* in_sizes, int n_in,
                              void* d_out, int out_size, void* d_ws, size_t ws_size,
                              hipStream_t stream)
{
  (void)in_sizes; (void)n_in; (void)out_size;
  const float* x     = (const float*)d_in[0];
  const int*   lens  = (const int*)d_in[1];
  const float* Wih_c = (const float*)d_in[3];
  const float* Whh_c = (const float*)d_in[4];
  const float* bih_c = (const float*)d_in[5];
  const float* bhh_c = (const float*)d_in[6];
  const float* Wmu   = (const float*)d_in[7];
  const float* bmu   = (const float*)d_in[8];
  const float* Wlv   = (const float*)d_in[9];
  const float* blv   = (const float*)d_in[10];
  const float* Wih_r = (const float*)d_in[11];
  const float* Whh_r = (const float*)d_in[12];
  const float* bih_r = (const float*)d_in[13];
  const float* bhh_r = (const float*)d_in[14];
  const float* gam   = (const float*)d_in[15];
  const float* bet   = (const float*)d_in[16];
  float* out = (float*)d_out;

  uint32_t nk[4][2];
  for (uint32_t i = 0; i < 4; ++i) tf2x32(0u, 42u, 0u, i, &nk[i][0], &nk[i][1]);

  float* ws = (float*)d_ws;
  size_t off = 0;
  float* U       = ws + off; off += 16384000;  // gi_all then mu_all (aliased)
  float* hx_all  = ws + off; off += 4915200;
  float* lv_all  = ws + off; off += 32768;
  float* Wp      = ws + off; off += 307200;    // packed Whh_c [75][1024][4]
  float* lastb   = ws + off; off += 131072;
  float* mv      = ws + off; off += 2048;
  unsigned int* flags = (unsigned int*)(ws + off); off += 2080;  // 64*32 + go
  unsigned int* go = flags + 2048;
  unsigned short* texts_b = (unsigned short*)(ws + off); off += 2621440; // 16384x320 bf16
  unsigned short* h2b0    = (unsigned short*)(ws + off); off += 65536;   // 128x1024 bf16
  unsigned short* h2b1    = (unsigned short*)(ws + off); off += 65536;
  unsigned short* Whb     = (unsigned short*)(ws + off); off += 1572864; // 3072x1024 bf16
  unsigned short* Wib     = (unsigned short*)(ws + off); off += 491520;  // 3072x320 bf16
  if (ws_size < off * sizeof(float)) return;

  hipMemsetAsync(h2b0, 0, 131072 * sizeof(unsigned short), stream);
  hipMemsetAsync(flags, 0, 2080 * sizeof(unsigned int), stream);

  // weight prep
  k_cvt_whh<<<dim3(12288), 256, 0, stream>>>(Whh_r, Whb);
  k_cvt_wih<<<dim3(3840), 256, 0, stream>>>(Wih_r, Wib);
  k_pack_whh<<<dim3(300), 256, 0, stream>>>(Whh_c, Wp);

  // stage-1 input projection + persistent recurrence
  k_gemm_gi<<<dim3(15, 256), 256, 0, stream>>>(x, Wih_c, bih_c, U);
  k_stage1<<<dim3(64), 512, 0, stream>>>(Wp, bhh_c, U, hx_all);

  // batched mu / lv / sampling
  k_gemm_mu<<<dim3(16, 256), 256, 0, stream>>>(x, hx_all, Wmu, bmu, U);
  k_lv<<<dim3(4096), 256, 0, stream>>>(x, hx_all, Wlv, blv, lv_all);
  k_sample<<<dim3(16384), 256, 0, stream>>>(x, U, lv_all, texts_b, out,
      nk[0][0], nk[0][1], nk[1][0], nk[1][1],
      nk[2][0], nk[2][1], nk[3][0], nk[3][1]);

  // stage-2 persistent recurrence (weight-resident LDS + flag barrier)
  k_stage2<<<dim3(NBLK2), 256, 0, stream>>>(texts_b, Whb, Wib, bih_r, bhh_r, lens,
                                            h2b0, h2b1, lastb, flags, go);

  // batchnorm
  k_bn_stats<<<dim3(4), 256, 0, stream>>>(lastb, mv);
  k_bn_apply<<<dim3(512), 256, 0, stream>>>(lastb, mv, gam, bet, out);
}

// Round 5
// 2731.249 us; speedup vs baseline: 2.9983x; 2.0159x over previous
//
#include <hip/hip_runtime.h>
#include <stdint.h>

#define TT 128
#define BB 128
#define DD 300
#define EE 1024
#define GG 900
#define NMU 1000
#define ASP 500

#define OUT_SLOG 131072
#define OUT_ACT  163840
#define OUT_LOGP 196608

typedef unsigned int u32x4 __attribute__((ext_vector_type(4)));

// ---------------- threefry2x32 (JAX, 20 rounds) ----------------
__host__ __device__ static inline uint32_t rotl32(uint32_t x, int r){
  return (x << r) | (x >> (32 - r));
}

__host__ __device__ static inline void tf2x32(uint32_t k0, uint32_t k1,
                                              uint32_t x0, uint32_t x1,
                                              uint32_t* o0, uint32_t* o1){
  uint32_t ks2 = k0 ^ k1 ^ 0x1BD11BDAu;
#define TFR(r) { x0 += x1; x1 = rotl32(x1, r); x1 ^= x0; }
  x0 += k0; x1 += k1;
  TFR(13) TFR(15) TFR(26) TFR(6)
  x0 += k1; x1 += ks2 + 1u;
  TFR(17) TFR(29) TFR(16) TFR(24)
  x0 += ks2; x1 += k0 + 2u;
  TFR(13) TFR(15) TFR(26) TFR(6)
  x0 += k0; x1 += k1 + 3u;
  TFR(17) TFR(29) TFR(16) TFR(24)
  x0 += k1; x1 += ks2 + 4u;
  TFR(13) TFR(15) TFR(26) TFR(6)
  x0 += ks2; x1 += k0 + 5u;
#undef TFR
  *o0 = x0; *o1 = x1;
}

__device__ static inline uint32_t rng32(uint32_t k0, uint32_t k1, uint32_t idx){
  uint32_t a, b;
  tf2x32(k0, k1, 0u, idx, &a, &b);
  return a ^ b;
}

__device__ static inline float u01(uint32_t bits){
  return __uint_as_float((bits >> 9) | 0x3f800000u) - 1.0f;
}

__device__ static inline float jgumbel(uint32_t k0, uint32_t k1, uint32_t idx){
  float u = u01(rng32(k0, k1, idx));
  float l1 = logf(u + 1e-20f);
  return -logf(-l1 + 1e-20f);
}

__device__ static inline float erfinv32(float x){   // XLA ErfInv32 (Giles)
  float w = -log1pf(-x * x);
  float p;
  if (w < 5.0f){
    w = w - 2.5f;
    p = 2.81022636e-08f;
    p = 3.43273939e-07f  + p * w;
    p = -3.5233877e-06f  + p * w;
    p = -4.39150654e-06f + p * w;
    p = 0.00021858087f   + p * w;
    p = -0.00125372503f  + p * w;
    p = -0.00417768164f  + p * w;
    p = 0.246640727f     + p * w;
    p = 1.50140941f      + p * w;
  } else {
    w = sqrtf(w) - 3.0f;
    p = -0.000200214257f;
    p = 0.000100950558f  + p * w;
    p = 0.00134934322f   + p * w;
    p = -0.00367342844f  + p * w;
    p = 0.00573950773f   + p * w;
    p = -0.0076224613f   + p * w;
    p = 0.00943887047f   + p * w;
    p = 1.00167406f      + p * w;
    p = 2.83297682f      + p * w;
  }
  return p * x;
}

__device__ static inline float jnormal(uint32_t k0, uint32_t k1, uint32_t idx){
  float u = u01(rng32(k0, k1, idx));
  const float lo = -0.99999994f;
  float v = u * 2.0f + lo;
  v = fmaxf(lo, v);
  return 1.41421356237f * erfinv32(v);
}

__device__ static inline float jsigmoid(float x){
  return 1.0f / (1.0f + expf(-x));
}

__device__ static inline unsigned short f2bf(float f){   // RNE f32->bf16
  uint32_t u = __float_as_uint(f);
  uint32_t r = (u + 0x7fffu + ((u >> 16) & 1u)) >> 16;
  return (unsigned short)r;
}

// ---- LLC-coherent (cross-XCD) memory ops: sc0 sc1 = bypass L1+L2 ----
__device__ static inline u32x4 load_b128_llc(const void* p){
  u32x4 r;
  asm volatile("global_load_dwordx4 %0, %1, off sc0 sc1"
               : "=v"(r) : "v"(p) : "memory");
  return r;
}
__device__ static inline void store_u16_llc(void* p, unsigned v){
  asm volatile("global_store_short %0, %1, off sc0 sc1"
               :: "v"(p), "v"(v) : "memory");
}
__device__ static inline unsigned poll_u32_llc(const void* p){
  unsigned r;
  asm volatile("global_load_dword %0, %1, off sc0 sc1\n\ts_waitcnt vmcnt(0)"
               : "=v"(r) : "v"(p) : "memory");
  return r;
}
__device__ static inline void store_u32_llc(void* p, unsigned v){
  asm volatile("global_store_dword %0, %1, off sc0 sc1"
               :: "v"(p), "v"(v) : "memory");
}

#define WAITV(N) do{ asm volatile("s_waitcnt vmcnt(" #N ")" ::: "memory"); \
                     __builtin_amdgcn_sched_barrier(0); }while(0)

// ---------------- GEMM1: gi_all[r=(t*BB+b)][900] = x@Wih_c^T + bih ----------------
__global__ __launch_bounds__(256) void k_gemm_gi(
    const float* __restrict__ X, const float* __restrict__ W,
    const float* __restrict__ bias, float* __restrict__ C)
{
  __shared__ float As[16][64];
  __shared__ float Bs[16][68];
  const int tid = threadIdx.x;
  const int rbase = blockIdx.y * 64;
  const int cbase = blockIdx.x * 64;
  const int tx = tid & 15, ty = tid >> 4;
  const int lrow = tid >> 2, lq = tid & 3;

  const int rg = rbase + lrow;
  const float* xrow = X + ((long)(rg & 127) * TT + (rg >> 7)) * DD;
  const int wj = cbase + lrow;

  float4 c0 = {0,0,0,0}, c1 = {0,0,0,0}, c2 = {0,0,0,0}, c3 = {0,0,0,0};

  for (int k0 = 0; k0 < DD; k0 += 16){
    int k = k0 + lq * 4;
    float4 va = {0,0,0,0};
    if (k < DD) va = *(const float4*)(xrow + k);
    As[lq*4+0][lrow] = va.x; As[lq*4+1][lrow] = va.y;
    As[lq*4+2][lrow] = va.z; As[lq*4+3][lrow] = va.w;
    float4 vb = {0,0,0,0};
    if (k < DD && wj < GG) vb = *(const float4*)(W + (long)wj * DD + k);
    Bs[lq*4+0][lrow] = vb.x; Bs[lq*4+1][lrow] = vb.y;
    Bs[lq*4+2][lrow] = vb.z; Bs[lq*4+3][lrow] = vb.w;
    __syncthreads();
#pragma unroll
    for (int kk = 0; kk < 16; ++kk){
      const float4 a = *(const float4*)&As[kk][ty * 4];
      const float4 b = *(const float4*)&Bs[kk][tx * 4];
      c0.x += a.x*b.x; c0.y += a.x*b.y; c0.z += a.x*b.z; c0.w += a.x*b.w;
      c1.x += a.y*b.x; c1.y += a.y*b.y; c1.z += a.y*b.z; c1.w += a.y*b.w;
      c2.x += a.z*b.x; c2.y += a.z*b.y; c2.z += a.z*b.z; c2.w += a.z*b.w;
      c3.x += a.w*b.x; c3.y += a.w*b.y; c3.z += a.w*b.z; c3.w += a.w*b.w;
    }
    __syncthreads();
  }
  const int ci = cbase + tx * 4;
  const int r0 = rbase + ty * 4;
  float bv[4];
#pragma unroll
  for (int j = 0; j < 4; ++j) bv[j] = (ci + j < GG) ? bias[ci + j] : 0.0f;
  float4 rows[4] = {c0, c1, c2, c3};
#pragma unroll
  for (int i = 0; i < 4; ++i){
    float vals[4] = {rows[i].x + bv[0], rows[i].y + bv[1],
                     rows[i].z + bv[2], rows[i].w + bv[3]};
    float* crow = C + (long)(r0 + i) * GG;
    if (ci + 3 < GG){
      float4 st = {vals[0], vals[1], vals[2], vals[3]};
      *(float4*)(crow + ci) = st;
    } else {
#pragma unroll
      for (int j = 0; j < 4; ++j) if (ci + j < GG) crow[ci + j] = vals[j];
    }
  }
}

// ---------------- GEMM-mu: 128x64 tile, 8x4 per thread ----------------
#define FMA4(ACC, S, B) { ACC.x += (S)*(B).x; ACC.y += (S)*(B).y; \
                          ACC.z += (S)*(B).z; ACC.w += (S)*(B).w; }

__global__ __launch_bounds__(256) void k_gemm_mu(
    const float* __restrict__ X, const float* __restrict__ HX,
    const float* __restrict__ W, const float* __restrict__ bias,
    float* __restrict__ C)
{
  __shared__ float As[16][132];
  __shared__ float Bs[16][68];
  const int tid = threadIdx.x;
  const int rbase = blockIdx.y * 128;
  const int cbase = blockIdx.x * 64;
  const int tx = tid & 15, ty = tid >> 4;
  const int sr = tid >> 2, sq = tid & 3;
  const int wj = cbase + sr;

  float4 acc[8];
#pragma unroll
  for (int i = 0; i < 8; ++i) acc[i] = (float4){0,0,0,0};

  for (int k0 = 0; k0 < 608; k0 += 16){
    const int k = k0 + sq * 4;
#pragma unroll
    for (int i = 0; i < 2; ++i){
      const int row = sr + i * 64;
      const int rg = rbase + row;
      float4 va = {0,0,0,0};
      if (k < 300)      va = *(const float4*)(X + ((long)(rg & 127) * TT + (rg >> 7)) * DD + k);
      else if (k < 600) va = *(const float4*)(HX + (long)rg * DD + (k - 300));
      va.x = fmaxf(va.x, 0.f); va.y = fmaxf(va.y, 0.f);
      va.z = fmaxf(va.z, 0.f); va.w = fmaxf(va.w, 0.f);
      As[sq*4+0][row] = va.x; As[sq*4+1][row] = va.y;
      As[sq*4+2][row] = va.z; As[sq*4+3][row] = va.w;
    }
    {
      float4 vb = {0,0,0,0};
      if (k < 600 && wj < NMU) vb = *(const float4*)(W + (long)wj * 600 + k);
      Bs[sq*4+0][sr] = vb.x; Bs[sq*4+1][sr] = vb.y;
      Bs[sq*4+2][sr] = vb.z; Bs[sq*4+3][sr] = vb.w;
    }
    __syncthreads();
#pragma unroll
    for (int kk = 0; kk < 16; ++kk){
      const float4 b  = *(const float4*)&Bs[kk][tx * 4];
      const float4 a0 = *(const float4*)&As[kk][ty * 8];
      const float4 a1 = *(const float4*)&As[kk][ty * 8 + 4];
      FMA4(acc[0], a0.x, b); FMA4(acc[1], a0.y, b);
      FMA4(acc[2], a0.z, b); FMA4(acc[3], a0.w, b);
      FMA4(acc[4], a1.x, b); FMA4(acc[5], a1.y, b);
      FMA4(acc[6], a1.z, b); FMA4(acc[7], a1.w, b);
    }
    __syncthreads();
  }
  const int ci = cbase + tx * 4;
  float bv[4];
#pragma unroll
  for (int j = 0; j < 4; ++j) bv[j] = (ci + j < NMU) ? bias[ci + j] : 0.0f;
#pragma unroll
  for (int i = 0; i < 8; ++i){
    const int r = rbase + ty * 8 + i;
    float vals[4] = {acc[i].x + bv[0], acc[i].y + bv[1],
                     acc[i].z + bv[2], acc[i].w + bv[3]};
    float* crow = C + (long)r * NMU;
    if (ci + 3 < NMU){
      float4 st = {vals[0], vals[1], vals[2], vals[3]};
      *(float4*)(crow + ci) = st;
    } else {
#pragma unroll
      for (int j = 0; j < 4; ++j) if (ci + j < NMU) crow[ci + j] = vals[j];
    }
  }
}

// ---------------- lv (pre-softplus), wave-per-row ----------------
__global__ __launch_bounds__(256) void k_lv(
    const float* __restrict__ X, const float* __restrict__ HX,
    const float* __restrict__ Wlv, const float* __restrict__ blv,
    float* __restrict__ LV)
{
  const int r = blockIdx.x * 4 + (threadIdx.x >> 6);   // 16384 rows
  const int lane = threadIdx.x & 63;
  const float* xr = X + ((long)(r & 127) * TT + (r >> 7)) * DD;
  const float* hr = HX + (long)r * DD;
  float a0 = 0.0f, a1 = 0.0f;
  for (int k = lane; k < DD; k += 64){
    float v = fmaxf(xr[k], 0.0f);
    a0 += v * Wlv[k];       a1 += v * Wlv[600 + k];
    float w = fmaxf(hr[k], 0.0f);
    a0 += w * Wlv[300 + k]; a1 += w * Wlv[900 + k];
  }
#pragma unroll
  for (int off = 32; off > 0; off >>= 1){
    a0 += __shfl_down(a0, off);
    a1 += __shfl_down(a1, off);
  }
  if (lane == 0){
    LV[(long)r * 2 + 0] = a0 + blv[0];
    LV[(long)r * 2 + 1] = a1 + blv[1];
  }
}

// ---------------- Whh_c pack ----------------
__global__ __launch_bounds__(256) void k_pack_whh(
    const float* __restrict__ W, float* __restrict__ Wp)
{
  const int i = blockIdx.x * 256 + threadIdx.x;   // 75*1024
  const int kq = i >> 10, j = i & 1023;
  float4 v = {0,0,0,0};
  if (kq < 75 && j < GG){
    const float* s = W + (long)j * DD + kq * 4;
    v.x = s[0]; v.y = s[1]; v.z = s[2]; v.w = s[3];
  }
  *(float4*)(Wp + (long)i * 4) = v;
}

// ---------------- stage-1 persistent ----------------
#define DOT4(A, Wv, Hv) \
  A = fmaf((Wv).x,(Hv).x, fmaf((Wv).y,(Hv).y, fmaf((Wv).z,(Hv).z, fmaf((Wv).w,(Hv).w, (A)))))

__global__ __launch_bounds__(512) void k_stage1(
    const float* __restrict__ Wp, const float* __restrict__ bhh,
    const float* __restrict__ gi_all, float* __restrict__ hx_all)
{
  __shared__ float hs[2][304];
  __shared__ float ghs[2][912];
  __shared__ float bhs[912];
  const int tid = threadIdx.x;
  const int b0 = blockIdx.x * 2;
  for (int j = tid; j < GG; j += 512) bhs[j] = bhh[j];
  for (int j = tid; j < 304; j += 512){ hs[0][j] = 0.f; hs[1][j] = 0.f; }
  __syncthreads();

  const int j0 = tid * 2;
  for (int t = 0; t < TT; ++t){
    float a00 = 0.f, a01 = 0.f, a10 = 0.f, a11 = 0.f;
#pragma unroll 5
    for (int kq = 0; kq < 75; ++kq){
      const float* wp = Wp + ((long)kq * 1024 + j0) * 4;
      const float4 w0 = *(const float4*)(wp);
      const float4 w1 = *(const float4*)(wp + 4);
      const float4 h0v = *(const float4*)&hs[0][kq * 4];
      const float4 h1v = *(const float4*)&hs[1][kq * 4];
      DOT4(a00, w0, h0v); DOT4(a01, w0, h1v);
      DOT4(a10, w1, h0v); DOT4(a11, w1, h1v);
    }
    if (j0 < GG){
      ghs[0][j0]     = a00; ghs[1][j0]     = a01;
      ghs[0][j0 + 1] = a10; ghs[1][j0 + 1] = a11;
    }
    __syncthreads();
    for (int jj = tid; jj < DD; jj += 512){
#pragma unroll
      for (int b = 0; b < 2; ++b){
        const float* gi = gi_all + ((long)t * BB + b0 + b) * GG;
        const float r = jsigmoid(gi[jj]       + ghs[b][jj]       + bhs[jj]);
        const float z = jsigmoid(gi[300 + jj] + ghs[b][300 + jj] + bhs[300 + jj]);
        const float n = tanhf(gi[600 + jj] + r * (ghs[b][600 + jj] + bhs[600 + jj]));
        const float hv = hs[b][jj];
        const float hn = (1.0f - z) * n + z * hv;
        hs[b][jj] = hn;
        hx_all[((long)t * BB + b0 + b) * DD + jj] = hn;
      }
    }
    __syncthreads();
  }
}

// ---------------- sampling ----------------
__global__ __launch_bounds__(256) void k_sample(
    const float* __restrict__ X, const float* __restrict__ mu_all,
    const float* __restrict__ lv_all, unsigned short* __restrict__ texts_b,
    float* __restrict__ out,
    const uint32_t k0a, const uint32_t k0b, const uint32_t k1a, const uint32_t k1b,
    const uint32_t k2a, const uint32_t k2b, const uint32_t k3a, const uint32_t k3b)
{
  const int r = blockIdx.x;            // t*128 + b
  const int t = r >> 7, b = r & 127;
  const int tid = threadIdx.x;
  const int h = tid >> 7, lane = tid & 127;
  __shared__ float redf[256];
  __shared__ int   redi[256];
  __shared__ float yw[2], lyw[2], att_s[2];

  const uint32_t rowbase = (uint32_t)((t * 256 + b * 2 + h) * 500);
  float zv[4], ev[4];
  float lmax = -3.0e38f;
#pragma unroll
  for (int s = 0; s < 4; ++s){
    const int a = lane + s * 128;
    float z = -3.0e38f;
    if (a < ASP){
      float g = jgumbel(k0a, k0b, rowbase + (uint32_t)a);
      float m = mu_all[(long)r * NMU + h * ASP + a];
      z = (m + g) / 0.8f;
    }
    zv[s] = z;
    lmax = fmaxf(lmax, z);
  }
  redf[tid] = lmax;
  __syncthreads();
  for (int off = 64; off > 0; off >>= 1){
    if (lane < off) redf[tid] = fmaxf(redf[tid], redf[tid + off]);
    __syncthreads();
  }
  const float mx = redf[h << 7];
  __syncthreads();
  float lsum = 0.0f;
#pragma unroll
  for (int s = 0; s < 4; ++s){
    const int a = lane + s * 128;
    float e = 0.0f;
    if (a < ASP) e = expf(zv[s] - mx);
    ev[s] = e;
    lsum += e;
  }
  redf[tid] = lsum;
  __syncthreads();
  for (int off = 64; off > 0; off >>= 1){
    if (lane < off) redf[tid] += redf[tid + off];
    __syncthreads();
  }
  const float S = redf[h << 7];
  __syncthreads();
  float bestv = -3.0e38f;
  int besti = 0x7fffffff;
#pragma unroll
  for (int s = 0; s < 4; ++s){
    const int a = lane + s * 128;
    if (a < ASP){
      float y = ev[s] / S;
      float ly = logf(y);
      float gc = jgumbel(k1a, k1b, rowbase + (uint32_t)a);
      float val = ly + gc;
      if (val > bestv){ bestv = val; besti = a; }
    }
  }
  redf[tid] = bestv; redi[tid] = besti;
  __syncthreads();
  for (int off = 64; off > 0; off >>= 1){
    if (lane < off){
      float v2 = redf[tid + off]; int i2 = redi[tid + off];
      if (v2 > redf[tid] || (v2 == redf[tid] && i2 < redi[tid])){
        redf[tid] = v2; redi[tid] = i2;
      }
    }
    __syncthreads();
  }
  const int ind = redi[h << 7];
#pragma unroll
  for (int s = 0; s < 4; ++s){
    const int a = lane + s * 128;
    if (a == ind){
      float y = ev[s] / S;
      yw[h] = y;
      lyw[h] = logf(y);
    }
  }
  __syncthreads();
  if (lane == 0){
    const float yv = yw[h];
    const float ly = lyw[h];
    const float yh = (1.0f - yv) + yv;
    const float act = ((float)ind * yh) / 500.0f;
    const float lvr = lv_all[(long)r * 2 + h];
    const float lv = fmaxf(lvr, 0.0f) + log1pf(expf(-fabsf(lvr)));
    const float sd = expf(0.5f * lv);
    const uint32_t ei = (uint32_t)(r * 2 + h);
    const float e1 = jnormal(k2a, k2b, ei);
    const float e2 = jnormal(k3a, k3b, ei);
    const float s1 = act + sd * e1;
    const float s2 = act + sd * e2;
    const float dd = (s2 - act) / sd;
    const float lp = -0.5f * (dd * dd) - logf(sd) - 0.9189385332046727f;
    const float attv = 20.0f * jsigmoid(s1);
    out[OUT_SLOG + (long)b * 256 + t * 2 + h]  = ly;
    out[OUT_ACT  + (long)b * 256 + h * 128 + t] = act;
    out[OUT_LOGP + (long)b * 256 + h * 128 + t] = lp;
    att_s[h] = attv;
  }
  __syncthreads();
  const float* xr = X + ((long)b * TT + t) * DD;
  unsigned short* tr = texts_b + (long)r * 320;
  for (int j = tid; j < 320; j += 256){
    unsigned short o = 0;
    if (j < 300) o = f2bf(xr[j] * att_s[j / 150]);
    tr[j] = o;
  }
}

// ---------------- weight conversion to bf16 ----------------
__global__ __launch_bounds__(256) void k_cvt_whh(
    const float* __restrict__ W, unsigned short* __restrict__ O)
{
  const int i = blockIdx.x * 256 + threadIdx.x;   // 3072*1024
  O[i] = f2bf(W[i]);
}

__global__ __launch_bounds__(256) void k_cvt_wih(
    const float* __restrict__ W, unsigned short* __restrict__ O)
{
  const int i = blockIdx.x * 256 + threadIdx.x;   // 3072*320
  const int rw = i / 320, c = i - rw * 320;
  O[i] = (c < DD) ? f2bf(W[(long)rw * DD + c]) : (unsigned short)0;
}

// ---------------- stage-2 persistent: 128 blocks, LLC-coherent h + flat barrier ----------------
// block bid: m = bid>>6 (batch rows m*64..+64), n = bid&63 (cols n*16..+16 x 3 gates)
// W (48x1344 bf16) LDS-resident; A chunks (64x64 bf16) double-buffered, XOR-swizzled,
// depth-4 counted-vmcnt pipeline. h exchanged via sc0sc1 (LLC), flags sc0sc1, no fences.
#define NBLK2 128
#define WPITCH 2704   // 1344*2 + 16
#define ACH 9216      // 64 rows * 144B

__global__ __launch_bounds__(256) void k_stage2(
    const unsigned short* __restrict__ texts_b,
    const unsigned short* __restrict__ Whb,
    const unsigned short* __restrict__ Wib,
    const float* __restrict__ bih, const float* __restrict__ bhh,
    const int* __restrict__ lengths,
    unsigned short* __restrict__ h2b0, unsigned short* __restrict__ h2b1,
    float* __restrict__ last,
    unsigned int* __restrict__ flags)
{
  __shared__ __align__(16) char lds[148224];   // W: 129792 | A: 2*9216
  unsigned short* Wl = (unsigned short*)lds;
  char* Al = lds + 129792;

  const int tid = threadIdx.x;
  const int bid = blockIdx.x;
  const int m = bid >> 6, n = bid & 63;
  const int e0 = n * 16;
  const int mrow = m * 64;
  const int wv = tid >> 6, lane = tid & 63;

  // ---- stage W into LDS once ----
  for (int s = tid; s < 48 * 168; s += 256){
    const int row = s / 168, q = s - row * 168;
    const int g = row >> 4, nn = row & 15;
    const long wrow = (long)g * EE + e0 + nn;
    uint4 v;
    if (q < 128) v = *(const uint4*)(Whb + wrow * EE + q * 8);
    else         v = *(const uint4*)(Wib + wrow * 320 + (q - 128) * 8);
    *(uint4*)((char*)Wl + (long)row * WPITCH + q * 16) = v;
  }

  const int e = e0 + (lane & 15);
  const float bR = bih[e] + bhh[e];
  const float bZ = bih[EE + e] + bhh[EE + e];
  const float biN = bih[2*EE + e];
  const float bhN = bhh[2*EE + e];
  int li[4];
  float hp[4];
#pragma unroll
  for (int j = 0; j < 4; ++j){
    const int brow = wv * 16 + (lane >> 4) * 4 + j;
    int l = lengths[mrow + brow] - 1; if (l < 0) l += TT;
    li[j] = l;
    hp[j] = 0.0f;
  }
  __syncthreads();

  using frag = __attribute__((ext_vector_type(8))) short;
  using f32x4 = __attribute__((ext_vector_type(4))) float;

  const int arow = wv * 16 + (lane & 15);
  const int ahi = lane >> 4;
  // B (W) byte offsets per gate
  int boff[3];
#pragma unroll
  for (int g = 0; g < 3; ++g) boff[g] = (g * 16 + (lane & 15)) * WPITCH + ahi * 16;

  u32x4 rg[4][2];
  unsigned int* flagp = flags + bid * 16;

  for (int t = 0; t < TT; ++t){
    const unsigned short* hb = (t & 1) ? h2b1 : h2b0;
    unsigned short* ho = (t & 1) ? h2b0 : h2b1;
    const unsigned short* txp = texts_b + (long)t * BB * 320;

    f32x4 aR = {0,0,0,0}, aZ = {0,0,0,0}, aNH = {0,0,0,0}, aNI = {0,0,0,0};

    auto issueT = [&](int c, u32x4* r){
#pragma unroll
      for (int i = 0; i < 2; ++i){
        const int sl = tid + i * 256, row = sl >> 3, kq = sl & 7;
        r[i] = load_b128_llc(txp + (long)(mrow + row) * 320 + (c - 16) * 64 + kq * 8);
      }
    };
    auto issueH = [&](int c, u32x4* r){
#pragma unroll
      for (int i = 0; i < 2; ++i){
        const int sl = tid + i * 256, row = sl >> 3, kq = sl & 7;
        r[i] = load_b128_llc(hb + (long)(mrow + row) * EE + c * 64 + kq * 8);
      }
    };
    auto writeA = [&](int buf, u32x4* r){
#pragma unroll
      for (int i = 0; i < 2; ++i){
        const int sl = tid + i * 256, row = sl >> 3, kq = sl & 7;
        const int off = row * 144 + ((kq ^ (row & 7)) << 4);
        *(u32x4*)(Al + buf * ACH + off) = r[i];
      }
    };
    auto compute = [&](int c, bool hid){
      const char* Ab = Al + (c & 1) * ACH;
#pragma unroll
      for (int kf = 0; kf < 2; ++kf){
        const int g4 = kf * 4 + ahi;
        frag a = *(const frag*)(Ab + arow * 144 + ((g4 ^ (arow & 7)) << 4));
        frag b0 = *(const frag*)((char*)Wl + boff[0] + c * 128 + kf * 64);
        frag b1 = *(const frag*)((char*)Wl + boff[1] + c * 128 + kf * 64);
        frag b2 = *(const frag*)((char*)Wl + boff[2] + c * 128 + kf * 64);
        aR = __builtin_amdgcn_mfma_f32_16x16x32_bf16(a, b0, aR, 0, 0, 0);
        aZ = __builtin_amdgcn_mfma_f32_16x16x32_bf16(a, b1, aZ, 0, 0, 0);
        if (hid) aNH = __builtin_amdgcn_mfma_f32_16x16x32_bf16(a, b2, aNH, 0, 0, 0);
        else     aNI = __builtin_amdgcn_mfma_f32_16x16x32_bf16(a, b2, aNI, 0, 0, 0);
      }
    };

#define CHUNK(c, WN, ISSUE, HID) do{ \
    __syncthreads(); \
    WAITV(WN); \
    writeA((c) & 1, rg[(c) & 3]); \
    ISSUE; \
    __syncthreads(); \
    compute((c), (HID)); \
  }while(0)

    // ---- texts phase (no h dependency) ----
    issueT(16, rg[0]); issueT(17, rg[1]); issueT(18, rg[2]); issueT(19, rg[3]);
    CHUNK(16, 6, issueT(20, rg[0]), false);
    CHUNK(17, 6, (void)0, false);
    CHUNK(18, 4, (void)0, false);
    CHUNK(19, 2, (void)0, false);
    CHUNK(20, 0, (void)0, false);

    // ---- barrier + hidden phase ----
    if (t > 0){
      if (tid < NBLK2){
        const unsigned int* fp = flags + tid * 16;
        unsigned v = poll_u32_llc(fp);
        while (v < (unsigned)t){
          __builtin_amdgcn_s_sleep(2);
          v = poll_u32_llc(fp);
        }
      }
      __syncthreads();

      issueH(0, rg[0]); issueH(1, rg[1]); issueH(2, rg[2]); issueH(3, rg[3]);
#pragma unroll
      for (int c = 0; c < 12; ++c){
        CHUNK(c, 6, issueH(c + 4, rg[c & 3]), true);
      }
      CHUNK(12, 6, (void)0, true);
      CHUNK(13, 4, (void)0, true);
      CHUNK(14, 2, (void)0, true);
      CHUNK(15, 0, (void)0, true);
    }
#undef CHUNK

    // ---- GRU gates epilogue ----
#pragma unroll
    for (int j = 0; j < 4; ++j){
      const int brow = wv * 16 + (lane >> 4) * 4 + j;
      const float r = jsigmoid(aR[j] + bR);
      const float z = jsigmoid(aZ[j] + bZ);
      const float nn2 = tanhf(aNI[j] + biN + r * (aNH[j] + bhN));
      const float hn = (1.0f - z) * nn2 + z * hp[j];
      hp[j] = hn;
      store_u16_llc(ho + (long)(mrow + brow) * EE + e, (unsigned)f2bf(hn));
      if (t == li[j]) last[(long)(mrow + brow) * EE + e] = hn;
    }

    if (t < TT - 1){
      asm volatile("s_waitcnt vmcnt(0)" ::: "memory");
      __syncthreads();
      if (tid == 0) store_u32_llc(flagp, (unsigned)(t + 1));
    }
  }
}

// ---------------- BatchNorm ----------------
__global__ __launch_bounds__(256) void k_bn_stats(
    const float* __restrict__ last, float* __restrict__ mv)
{
  const int e = blockIdx.x * 256 + threadIdx.x;
  if (e >= EE) return;
  float s = 0.0f;
  for (int b = 0; b < BB; ++b) s += last[(long)b * EE + e];
  const float mean = s / 128.0f;
  float v = 0.0f;
  for (int b = 0; b < BB; ++b){ float d = last[(long)b * EE + e] - mean; v += d * d; }
  mv[e] = mean;
  mv[EE + e] = v / 128.0f;
}

__global__ __launch_bounds__(256) void k_bn_apply(
    const float* __restrict__ last, const float* __restrict__ mv,
    const float* __restrict__ gamma, const float* __restrict__ beta,
    float* __restrict__ out)
{
  const int gid = blockIdx.x * 256 + threadIdx.x;
  const int e = gid & 1023;
  const float xm = last[gid] - mv[e];
  out[gid] = gamma[e] * xm / sqrtf(mv[EE + e] + 1e-5f) + beta[e];
}

// ---------------- launcher ----------------
extern "C" void kernel_launch(void* const* d_in, const int* in_sizes, int n_in,
                              void* d_out, int out_size, void* d_ws, size_t ws_size,
                              hipStream_t stream)
{
  (void)in_sizes; (void)n_in; (void)out_size;
  const float* x     = (const float*)d_in[0];
  const int*   lens  = (const int*)d_in[1];
  const float* Wih_c = (const float*)d_in[3];
  const float* Whh_c = (const float*)d_in[4];
  const float* bih_c = (const float*)d_in[5];
  const float* bhh_c = (const float*)d_in[6];
  const float* Wmu   = (const float*)d_in[7];
  const float* bmu   = (const float*)d_in[8];
  const float* Wlv   = (const float*)d_in[9];
  const float* blv   = (const float*)d_in[10];
  const float* Wih_r = (const float*)d_in[11];
  const float* Whh_r = (const float*)d_in[12];
  const float* bih_r = (const float*)d_in[13];
  const float* bhh_r = (const float*)d_in[14];
  const float* gam   = (const float*)d_in[15];
  const float* bet   = (const float*)d_in[16];
  float* out = (float*)d_out;

  uint32_t nk[4][2];
  for (uint32_t i = 0; i < 4; ++i) tf2x32(0u, 42u, 0u, i, &nk[i][0], &nk[i][1]);

  float* ws = (float*)d_ws;
  size_t off = 0;
  float* U       = ws + off; off += 16384000;  // gi_all then mu_all (aliased)
  float* hx_all  = ws + off; off += 4915200;
  float* lv_all  = ws + off; off += 32768;
  float* Wp      = ws + off; off += 307200;    // packed Whh_c
  float* lastb   = ws + off; off += 131072;
  float* mv      = ws + off; off += 2048;
  unsigned int* flags = (unsigned int*)(ws + off); off += 2048;  // 128*16 uints
  unsigned short* texts_b = (unsigned short*)(ws + off); off += 2621440; // 16384x320 bf16
  unsigned short* h2b0    = (unsigned short*)(ws + off); off += 65536;   // 128x1024 bf16
  unsigned short* h2b1    = (unsigned short*)(ws + off); off += 65536;
  unsigned short* Whb     = (unsigned short*)(ws + off); off += 1572864; // 3072x1024 bf16
  unsigned short* Wib     = (unsigned short*)(ws + off); off += 491520;  // 3072x320 bf16
  if (ws_size < off * sizeof(float)) return;

  hipMemsetAsync(flags, 0, 2048 * sizeof(unsigned int), stream);

  // weight prep
  k_cvt_whh<<<dim3(12288), 256, 0, stream>>>(Whh_r, Whb);
  k_cvt_wih<<<dim3(3840), 256, 0, stream>>>(Wih_r, Wib);
  k_pack_whh<<<dim3(300), 256, 0, stream>>>(Whh_c, Wp);

  // stage-1 input projection + persistent recurrence
  k_gemm_gi<<<dim3(15, 256), 256, 0, stream>>>(x, Wih_c, bih_c, U);
  k_stage1<<<dim3(64), 512, 0, stream>>>(Wp, bhh_c, U, hx_all);

  // batched mu / lv / sampling
  k_gemm_mu<<<dim3(16, 128), 256, 0, stream>>>(x, hx_all, Wmu, bmu, U);
  k_lv<<<dim3(4096), 256, 0, stream>>>(x, hx_all, Wlv, blv, lv_all);
  k_sample<<<dim3(16384), 256, 0, stream>>>(x, U, lv_all, texts_b, out,
      nk[0][0], nk[0][1], nk[1][0], nk[1][1],
      nk[2][0], nk[2][1], nk[3][0], nk[3][1]);

  // stage-2 persistent recurrence (LLC-coherent h + flat barrier)
  k_stage2<<<dim3(NBLK2), 256, 0, stream>>>(texts_b, Whb, Wib, bih_r, bhh_r, lens,
                                            h2b0, h2b1, lastb, flags);

  // batchnorm
  k_bn_stats<<<dim3(4), 256, 0, stream>>>(lastb, mv);
  k_bn_apply<<<dim3(512), 256, 0, stream>>>(lastb, mv, gam, bet, out);
}

// Round 6
// 2716.317 us; speedup vs baseline: 3.0148x; 1.0055x over previous
//
#include <hip/hip_runtime.h>
#include <stdint.h>

#define TT 128
#define BB 128
#define DD 300
#define EE 1024
#define GG 900
#define NMU 1000
#define ASP 500

#define OUT_SLOG 131072
#define OUT_ACT  163840
#define OUT_LOGP 196608

typedef unsigned int u32x4 __attribute__((ext_vector_type(4)));

// ---------------- threefry2x32 (JAX, 20 rounds) ----------------
__host__ __device__ static inline uint32_t rotl32(uint32_t x, int r){
  return (x << r) | (x >> (32 - r));
}

__host__ __device__ static inline void tf2x32(uint32_t k0, uint32_t k1,
                                              uint32_t x0, uint32_t x1,
                                              uint32_t* o0, uint32_t* o1){
  uint32_t ks2 = k0 ^ k1 ^ 0x1BD11BDAu;
#define TFR(r) { x0 += x1; x1 = rotl32(x1, r); x1 ^= x0; }
  x0 += k0; x1 += k1;
  TFR(13) TFR(15) TFR(26) TFR(6)
  x0 += k1; x1 += ks2 + 1u;
  TFR(17) TFR(29) TFR(16) TFR(24)
  x0 += ks2; x1 += k0 + 2u;
  TFR(13) TFR(15) TFR(26) TFR(6)
  x0 += k0; x1 += k1 + 3u;
  TFR(17) TFR(29) TFR(16) TFR(24)
  x0 += k1; x1 += ks2 + 4u;
  TFR(13) TFR(15) TFR(26) TFR(6)
  x0 += ks2; x1 += k0 + 5u;
#undef TFR
  *o0 = x0; *o1 = x1;
}

__device__ static inline uint32_t rng32(uint32_t k0, uint32_t k1, uint32_t idx){
  uint32_t a, b;
  tf2x32(k0, k1, 0u, idx, &a, &b);
  return a ^ b;
}

__device__ static inline float u01(uint32_t bits){
  return __uint_as_float((bits >> 9) | 0x3f800000u) - 1.0f;
}

__device__ static inline float jgumbel(uint32_t k0, uint32_t k1, uint32_t idx){
  float u = u01(rng32(k0, k1, idx));
  float l1 = logf(u + 1e-20f);
  return -logf(-l1 + 1e-20f);
}

__device__ static inline float erfinv32(float x){   // XLA ErfInv32 (Giles)
  float w = -log1pf(-x * x);
  float p;
  if (w < 5.0f){
    w = w - 2.5f;
    p = 2.81022636e-08f;
    p = 3.43273939e-07f  + p * w;
    p = -3.5233877e-06f  + p * w;
    p = -4.39150654e-06f + p * w;
    p = 0.00021858087f   + p * w;
    p = -0.00125372503f  + p * w;
    p = -0.00417768164f  + p * w;
    p = 0.246640727f     + p * w;
    p = 1.50140941f      + p * w;
  } else {
    w = sqrtf(w) - 3.0f;
    p = -0.000200214257f;
    p = 0.000100950558f  + p * w;
    p = 0.00134934322f   + p * w;
    p = -0.00367342844f  + p * w;
    p = 0.00573950773f   + p * w;
    p = -0.0076224613f   + p * w;
    p = 0.00943887047f   + p * w;
    p = 1.00167406f      + p * w;
    p = 2.83297682f      + p * w;
  }
  return p * x;
}

__device__ static inline float jnormal(uint32_t k0, uint32_t k1, uint32_t idx){
  float u = u01(rng32(k0, k1, idx));
  const float lo = -0.99999994f;
  float v = u * 2.0f + lo;
  v = fmaxf(lo, v);
  return 1.41421356237f * erfinv32(v);
}

__device__ static inline float jsigmoid(float x){
  return 1.0f / (1.0f + expf(-x));
}

__device__ static inline unsigned short f2bf(float f){   // RNE f32->bf16
  uint32_t u = __float_as_uint(f);
  uint32_t r = (u + 0x7fffu + ((u >> 16) & 1u)) >> 16;
  return (unsigned short)r;
}

// ---- LLC-coherent (cross-XCD) memory ops: sc0 sc1 = bypass L1+L2 ----
__device__ static inline u32x4 load_b128_llc(const void* p){
  u32x4 r;
  asm volatile("global_load_dwordx4 %0, %1, off sc0 sc1"
               : "=v"(r) : "v"(p) : "memory");
  return r;
}
__device__ static inline void store_u16_llc(void* p, unsigned v){
  asm volatile("global_store_short %0, %1, off sc0 sc1"
               :: "v"(p), "v"(v) : "memory");
}
__device__ static inline unsigned poll_u32_llc(const void* p){
  unsigned r;
  asm volatile("global_load_dword %0, %1, off sc0 sc1\n\ts_waitcnt vmcnt(0)"
               : "=v"(r) : "v"(p) : "memory");
  return r;
}
__device__ static inline void store_u32_llc(void* p, unsigned v){
  asm volatile("global_store_dword %0, %1, off sc0 sc1"
               :: "v"(p), "v"(v) : "memory");
}

#define WAITV(N) do{ asm volatile("s_waitcnt vmcnt(" #N ")" ::: "memory"); \
                     __builtin_amdgcn_sched_barrier(0); }while(0)

// ---------------- GEMM1: gi_all[r=(t*BB+b)][900] = x@Wih_c^T + bih ----------------
// 128x64 tile, 8x4 per thread, K=300
#define FMA4(ACC, S, B) { ACC.x += (S)*(B).x; ACC.y += (S)*(B).y; \
                          ACC.z += (S)*(B).z; ACC.w += (S)*(B).w; }

__global__ __launch_bounds__(256) void k_gemm_gi(
    const float* __restrict__ X, const float* __restrict__ W,
    const float* __restrict__ bias, float* __restrict__ C)
{
  __shared__ float As[16][132];
  __shared__ float Bs[16][68];
  const int tid = threadIdx.x;
  const int rbase = blockIdx.y * 128;
  const int cbase = blockIdx.x * 64;
  const int tx = tid & 15, ty = tid >> 4;
  const int sr = tid >> 2, sq = tid & 3;
  const int wj = cbase + sr;

  float4 acc[8];
#pragma unroll
  for (int i = 0; i < 8; ++i) acc[i] = (float4){0,0,0,0};

  for (int k0 = 0; k0 < 304; k0 += 16){
    const int k = k0 + sq * 4;
#pragma unroll
    for (int i = 0; i < 2; ++i){
      const int row = sr + i * 64;
      const int rg = rbase + row;
      float4 va = {0,0,0,0};
      if (k < DD) va = *(const float4*)(X + ((long)(rg & 127) * TT + (rg >> 7)) * DD + k);
      As[sq*4+0][row] = va.x; As[sq*4+1][row] = va.y;
      As[sq*4+2][row] = va.z; As[sq*4+3][row] = va.w;
    }
    {
      float4 vb = {0,0,0,0};
      if (k < DD && wj < GG) vb = *(const float4*)(W + (long)wj * DD + k);
      Bs[sq*4+0][sr] = vb.x; Bs[sq*4+1][sr] = vb.y;
      Bs[sq*4+2][sr] = vb.z; Bs[sq*4+3][sr] = vb.w;
    }
    __syncthreads();
#pragma unroll
    for (int kk = 0; kk < 16; ++kk){
      const float4 b  = *(const float4*)&Bs[kk][tx * 4];
      const float4 a0 = *(const float4*)&As[kk][ty * 8];
      const float4 a1 = *(const float4*)&As[kk][ty * 8 + 4];
      FMA4(acc[0], a0.x, b); FMA4(acc[1], a0.y, b);
      FMA4(acc[2], a0.z, b); FMA4(acc[3], a0.w, b);
      FMA4(acc[4], a1.x, b); FMA4(acc[5], a1.y, b);
      FMA4(acc[6], a1.z, b); FMA4(acc[7], a1.w, b);
    }
    __syncthreads();
  }
  const int ci = cbase + tx * 4;
  float bv[4];
#pragma unroll
  for (int j = 0; j < 4; ++j) bv[j] = (ci + j < GG) ? bias[ci + j] : 0.0f;
#pragma unroll
  for (int i = 0; i < 8; ++i){
    const int r = rbase + ty * 8 + i;
    float vals[4] = {acc[i].x + bv[0], acc[i].y + bv[1],
                     acc[i].z + bv[2], acc[i].w + bv[3]};
    float* crow = C + (long)r * GG;
    if (ci + 3 < GG){
      float4 st = {vals[0], vals[1], vals[2], vals[3]};
      *(float4*)(crow + ci) = st;
    } else {
#pragma unroll
      for (int j = 0; j < 4; ++j) if (ci + j < GG) crow[ci + j] = vals[j];
    }
  }
}

// ---------------- GEMM-mu: 128x64 tile, 8x4 per thread ----------------
__global__ __launch_bounds__(256) void k_gemm_mu(
    const float* __restrict__ X, const float* __restrict__ HX,
    const float* __restrict__ W, const float* __restrict__ bias,
    float* __restrict__ C)
{
  __shared__ float As[16][132];
  __shared__ float Bs[16][68];
  const int tid = threadIdx.x;
  const int rbase = blockIdx.y * 128;
  const int cbase = blockIdx.x * 64;
  const int tx = tid & 15, ty = tid >> 4;
  const int sr = tid >> 2, sq = tid & 3;
  const int wj = cbase + sr;

  float4 acc[8];
#pragma unroll
  for (int i = 0; i < 8; ++i) acc[i] = (float4){0,0,0,0};

  for (int k0 = 0; k0 < 608; k0 += 16){
    const int k = k0 + sq * 4;
#pragma unroll
    for (int i = 0; i < 2; ++i){
      const int row = sr + i * 64;
      const int rg = rbase + row;
      float4 va = {0,0,0,0};
      if (k < 300)      va = *(const float4*)(X + ((long)(rg & 127) * TT + (rg >> 7)) * DD + k);
      else if (k < 600) va = *(const float4*)(HX + (long)rg * DD + (k - 300));
      va.x = fmaxf(va.x, 0.f); va.y = fmaxf(va.y, 0.f);
      va.z = fmaxf(va.z, 0.f); va.w = fmaxf(va.w, 0.f);
      As[sq*4+0][row] = va.x; As[sq*4+1][row] = va.y;
      As[sq*4+2][row] = va.z; As[sq*4+3][row] = va.w;
    }
    {
      float4 vb = {0,0,0,0};
      if (k < 600 && wj < NMU) vb = *(const float4*)(W + (long)wj * 600 + k);
      Bs[sq*4+0][sr] = vb.x; Bs[sq*4+1][sr] = vb.y;
      Bs[sq*4+2][sr] = vb.z; Bs[sq*4+3][sr] = vb.w;
    }
    __syncthreads();
#pragma unroll
    for (int kk = 0; kk < 16; ++kk){
      const float4 b  = *(const float4*)&Bs[kk][tx * 4];
      const float4 a0 = *(const float4*)&As[kk][ty * 8];
      const float4 a1 = *(const float4*)&As[kk][ty * 8 + 4];
      FMA4(acc[0], a0.x, b); FMA4(acc[1], a0.y, b);
      FMA4(acc[2], a0.z, b); FMA4(acc[3], a0.w, b);
      FMA4(acc[4], a1.x, b); FMA4(acc[5], a1.y, b);
      FMA4(acc[6], a1.z, b); FMA4(acc[7], a1.w, b);
    }
    __syncthreads();
  }
  const int ci = cbase + tx * 4;
  float bv[4];
#pragma unroll
  for (int j = 0; j < 4; ++j) bv[j] = (ci + j < NMU) ? bias[ci + j] : 0.0f;
#pragma unroll
  for (int i = 0; i < 8; ++i){
    const int r = rbase + ty * 8 + i;
    float vals[4] = {acc[i].x + bv[0], acc[i].y + bv[1],
                     acc[i].z + bv[2], acc[i].w + bv[3]};
    float* crow = C + (long)r * NMU;
    if (ci + 3 < NMU){
      float4 st = {vals[0], vals[1], vals[2], vals[3]};
      *(float4*)(crow + ci) = st;
    } else {
#pragma unroll
      for (int j = 0; j < 4; ++j) if (ci + j < NMU) crow[ci + j] = vals[j];
    }
  }
}

// ---------------- lv (pre-softplus), wave-per-row ----------------
__global__ __launch_bounds__(256) void k_lv(
    const float* __restrict__ X, const float* __restrict__ HX,
    const float* __restrict__ Wlv, const float* __restrict__ blv,
    float* __restrict__ LV)
{
  const int r = blockIdx.x * 4 + (threadIdx.x >> 6);   // 16384 rows
  const int lane = threadIdx.x & 63;
  const float* xr = X + ((long)(r & 127) * TT + (r >> 7)) * DD;
  const float* hr = HX + (long)r * DD;
  float a0 = 0.0f, a1 = 0.0f;
  for (int k = lane; k < DD; k += 64){
    float v = fmaxf(xr[k], 0.0f);
    a0 += v * Wlv[k];       a1 += v * Wlv[600 + k];
    float w = fmaxf(hr[k], 0.0f);
    a0 += w * Wlv[300 + k]; a1 += w * Wlv[900 + k];
  }
#pragma unroll
  for (int off = 32; off > 0; off >>= 1){
    a0 += __shfl_down(a0, off);
    a1 += __shfl_down(a1, off);
  }
  if (lane == 0){
    LV[(long)r * 2 + 0] = a0 + blv[0];
    LV[(long)r * 2 + 1] = a1 + blv[1];
  }
}

// ---------------- Whh_c pack: Wp[kq][1024 j][4 c] = Whh_c[j][4kq+c] ----------------
__global__ __launch_bounds__(256) void k_pack_whh(
    const float* __restrict__ W, float* __restrict__ Wp)
{
  const int i = blockIdx.x * 256 + threadIdx.x;   // 75*1024
  const int kq = i >> 10, j = i & 1023;
  float4 v = {0,0,0,0};
  if (kq < 75 && j < GG){
    const float* s = W + (long)j * DD + kq * 4;
    v.x = s[0]; v.y = s[1]; v.z = s[2]; v.w = s[3];
  }
  *(float4*)(Wp + (long)i * 4) = v;
}

// ---------------- stage-1 persistent: 64 blocks x 1024 thr ----------------
// Block owns batch rows {2bid, 2bid+1}. Thread j (=tid, 900 active) computes
// gh[j] for both rows via 8 independent flat FMA chains; coalesced Wp loads.
__global__ __launch_bounds__(1024) void k_stage1(
    const float* __restrict__ Wp, const float* __restrict__ bhh,
    const float* __restrict__ gi_all, float* __restrict__ hx_all)
{
  __shared__ float hs[2][304];
  __shared__ float ghs[2][912];
  __shared__ float bhs[912];
  const int tid = threadIdx.x;
  const int b0 = blockIdx.x * 2;
  for (int j = tid; j < GG; j += 1024) bhs[j] = bhh[j];
  if (tid < 304){ hs[0][tid] = 0.f; hs[1][tid] = 0.f; }
  __syncthreads();

  const float* wbase = Wp + (long)tid * 4;

  for (int t = 0; t < TT; ++t){
    // prefetch gate inputs (independent of matvec)
    float gi0r = 0.f, gi0z = 0.f, gi0n = 0.f, gi1r = 0.f, gi1z = 0.f, gi1n = 0.f;
    if (tid < DD){
      const float* g0 = gi_all + ((long)t * BB + b0) * GG;
      const float* g1 = g0 + GG;
      gi0r = g0[tid]; gi0z = g0[DD + tid]; gi0n = g0[2*DD + tid];
      gi1r = g1[tid]; gi1z = g1[DD + tid]; gi1n = g1[2*DD + tid];
    }

    float4 a0 = {0,0,0,0}, a1 = {0,0,0,0};
#pragma unroll 5
    for (int kq = 0; kq < 75; ++kq){
      const float4 w  = *(const float4*)(wbase + (long)kq * 4096);
      const float4 h0 = *(const float4*)&hs[0][kq * 4];
      const float4 h1 = *(const float4*)&hs[1][kq * 4];
      a0.x = fmaf(w.x, h0.x, a0.x); a0.y = fmaf(w.y, h0.y, a0.y);
      a0.z = fmaf(w.z, h0.z, a0.z); a0.w = fmaf(w.w, h0.w, a0.w);
      a1.x = fmaf(w.x, h1.x, a1.x); a1.y = fmaf(w.y, h1.y, a1.y);
      a1.z = fmaf(w.z, h1.z, a1.z); a1.w = fmaf(w.w, h1.w, a1.w);
    }
    if (tid < GG){
      ghs[0][tid] = (a0.x + a0.y) + (a0.z + a0.w);
      ghs[1][tid] = (a1.x + a1.y) + (a1.z + a1.w);
    }
    __syncthreads();

    if (tid < DD){
      const float bhr = bhs[tid], bhz = bhs[DD + tid], bhn = bhs[2*DD + tid];
      {
        const float r = jsigmoid(gi0r + ghs[0][tid] + bhr);
        const float z = jsigmoid(gi0z + ghs[0][DD + tid] + bhz);
        const float n = tanhf(gi0n + r * (ghs[0][2*DD + tid] + bhn));
        const float hn = (1.0f - z) * n + z * hs[0][tid];
        hs[0][tid] = hn;
        hx_all[((long)t * BB + b0) * DD + tid] = hn;
      }
      {
        const float r = jsigmoid(gi1r + ghs[1][tid] + bhr);
        const float z = jsigmoid(gi1z + ghs[1][DD + tid] + bhz);
        const float n = tanhf(gi1n + r * (ghs[1][2*DD + tid] + bhn));
        const float hn = (1.0f - z) * n + z * hs[1][tid];
        hs[1][tid] = hn;
        hx_all[((long)t * BB + b0 + 1) * DD + tid] = hn;
      }
    }
    __syncthreads();
  }
}

// ---------------- sampling ----------------
__global__ __launch_bounds__(256) void k_sample(
    const float* __restrict__ X, const float* __restrict__ mu_all,
    const float* __restrict__ lv_all, unsigned short* __restrict__ texts_b,
    float* __restrict__ out,
    const uint32_t k0a, const uint32_t k0b, const uint32_t k1a, const uint32_t k1b,
    const uint32_t k2a, const uint32_t k2b, const uint32_t k3a, const uint32_t k3b)
{
  const int r = blockIdx.x;            // t*128 + b
  const int t = r >> 7, b = r & 127;
  const int tid = threadIdx.x;
  const int h = tid >> 7, lane = tid & 127;
  __shared__ float redf[256];
  __shared__ int   redi[256];
  __shared__ float yw[2], lyw[2], att_s[2];

  const uint32_t rowbase = (uint32_t)((t * 256 + b * 2 + h) * 500);
  float zv[4], ev[4];
  float lmax = -3.0e38f;
#pragma unroll
  for (int s = 0; s < 4; ++s){
    const int a = lane + s * 128;
    float z = -3.0e38f;
    if (a < ASP){
      float g = jgumbel(k0a, k0b, rowbase + (uint32_t)a);
      float m = mu_all[(long)r * NMU + h * ASP + a];
      z = (m + g) / 0.8f;
    }
    zv[s] = z;
    lmax = fmaxf(lmax, z);
  }
  redf[tid] = lmax;
  __syncthreads();
  for (int off = 64; off > 0; off >>= 1){
    if (lane < off) redf[tid] = fmaxf(redf[tid], redf[tid + off]);
    __syncthreads();
  }
  const float mx = redf[h << 7];
  __syncthreads();
  float lsum = 0.0f;
#pragma unroll
  for (int s = 0; s < 4; ++s){
    const int a = lane + s * 128;
    float e = 0.0f;
    if (a < ASP) e = expf(zv[s] - mx);
    ev[s] = e;
    lsum += e;
  }
  redf[tid] = lsum;
  __syncthreads();
  for (int off = 64; off > 0; off >>= 1){
    if (lane < off) redf[tid] += redf[tid + off];
    __syncthreads();
  }
  const float S = redf[h << 7];
  __syncthreads();
  float bestv = -3.0e38f;
  int besti = 0x7fffffff;
#pragma unroll
  for (int s = 0; s < 4; ++s){
    const int a = lane + s * 128;
    if (a < ASP){
      float y = ev[s] / S;
      float ly = logf(y);
      float gc = jgumbel(k1a, k1b, rowbase + (uint32_t)a);
      float val = ly + gc;
      if (val > bestv){ bestv = val; besti = a; }
    }
  }
  redf[tid] = bestv; redi[tid] = besti;
  __syncthreads();
  for (int off = 64; off > 0; off >>= 1){
    if (lane < off){
      float v2 = redf[tid + off]; int i2 = redi[tid + off];
      if (v2 > redf[tid] || (v2 == redf[tid] && i2 < redi[tid])){
        redf[tid] = v2; redi[tid] = i2;
      }
    }
    __syncthreads();
  }
  const int ind = redi[h << 7];
#pragma unroll
  for (int s = 0; s < 4; ++s){
    const int a = lane + s * 128;
    if (a == ind){
      float y = ev[s] / S;
      yw[h] = y;
      lyw[h] = logf(y);
    }
  }
  __syncthreads();
  if (lane == 0){
    const float yv = yw[h];
    const float ly = lyw[h];
    const float yh = (1.0f - yv) + yv;
    const float act = ((float)ind * yh) / 500.0f;
    const float lvr = lv_all[(long)r * 2 + h];
    const float lv = fmaxf(lvr, 0.0f) + log1pf(expf(-fabsf(lvr)));
    const float sd = expf(0.5f * lv);
    const uint32_t ei = (uint32_t)(r * 2 + h);
    const float e1 = jnormal(k2a, k2b, ei);
    const float e2 = jnormal(k3a, k3b, ei);
    const float s1 = act + sd * e1;
    const float s2 = act + sd * e2;
    const float dd = (s2 - act) / sd;
    const float lp = -0.5f * (dd * dd) - logf(sd) - 0.9189385332046727f;
    const float attv = 20.0f * jsigmoid(s1);
    out[OUT_SLOG + (long)b * 256 + t * 2 + h]  = ly;
    out[OUT_ACT  + (long)b * 256 + h * 128 + t] = act;
    out[OUT_LOGP + (long)b * 256 + h * 128 + t] = lp;
    att_s[h] = attv;
  }
  __syncthreads();
  const float* xr = X + ((long)b * TT + t) * DD;
  unsigned short* tr = texts_b + (long)r * 320;
  for (int j = tid; j < 320; j += 256){
    unsigned short o = 0;
    if (j < 300) o = f2bf(xr[j] * att_s[j / 150]);
    tr[j] = o;
  }
}

// ---------------- weight conversion to bf16 ----------------
__global__ __launch_bounds__(256) void k_cvt_whh(
    const float* __restrict__ W, unsigned short* __restrict__ O)
{
  const int i = blockIdx.x * 256 + threadIdx.x;   // 3072*1024
  O[i] = f2bf(W[i]);
}

__global__ __launch_bounds__(256) void k_cvt_wih(
    const float* __restrict__ W, unsigned short* __restrict__ O)
{
  const int i = blockIdx.x * 256 + threadIdx.x;   // 3072*320
  const int rw = i / 320, c = i - rw * 320;
  O[i] = (c < DD) ? f2bf(W[(long)rw * DD + c]) : (unsigned short)0;
}

// ---------------- stage-2 persistent: 128 blocks, LLC-coherent h + flat barrier ----------------
#define NBLK2 128
#define WPITCH 2704   // 1344*2 + 16
#define ACH 9216      // 64 rows * 144B

__global__ __launch_bounds__(256) void k_stage2(
    const unsigned short* __restrict__ texts_b,
    const unsigned short* __restrict__ Whb,
    const unsigned short* __restrict__ Wib,
    const float* __restrict__ bih, const float* __restrict__ bhh,
    const int* __restrict__ lengths,
    unsigned short* __restrict__ h2b0, unsigned short* __restrict__ h2b1,
    float* __restrict__ last,
    unsigned int* __restrict__ flags)
{
  __shared__ __align__(16) char lds[148224];   // W: 129792 | A: 2*9216
  unsigned short* Wl = (unsigned short*)lds;
  char* Al = lds + 129792;

  const int tid = threadIdx.x;
  const int bid = blockIdx.x;
  const int m = bid >> 6, n = bid & 63;
  const int e0 = n * 16;
  const int mrow = m * 64;
  const int wv = tid >> 6, lane = tid & 63;

  // ---- stage W into LDS once ----
  for (int s = tid; s < 48 * 168; s += 256){
    const int row = s / 168, q = s - row * 168;
    const int g = row >> 4, nn = row & 15;
    const long wrow = (long)g * EE + e0 + nn;
    uint4 v;
    if (q < 128) v = *(const uint4*)(Whb + wrow * EE + q * 8);
    else         v = *(const uint4*)(Wib + wrow * 320 + (q - 128) * 8);
    *(uint4*)((char*)Wl + (long)row * WPITCH + q * 16) = v;
  }

  const int e = e0 + (lane & 15);
  const float bR = bih[e] + bhh[e];
  const float bZ = bih[EE + e] + bhh[EE + e];
  const float biN = bih[2*EE + e];
  const float bhN = bhh[2*EE + e];
  int li[4];
  float hp[4];
#pragma unroll
  for (int j = 0; j < 4; ++j){
    const int brow = wv * 16 + (lane >> 4) * 4 + j;
    int l = lengths[mrow + brow] - 1; if (l < 0) l += TT;
    li[j] = l;
    hp[j] = 0.0f;
  }
  __syncthreads();

  using frag = __attribute__((ext_vector_type(8))) short;
  using f32x4 = __attribute__((ext_vector_type(4))) float;

  const int arow = wv * 16 + (lane & 15);
  const int ahi = lane >> 4;
  int boff[3];
#pragma unroll
  for (int g = 0; g < 3; ++g) boff[g] = (g * 16 + (lane & 15)) * WPITCH + ahi * 16;

  u32x4 rg[4][2];
  unsigned int* flagp = flags + bid * 16;

  for (int t = 0; t < TT; ++t){
    const unsigned short* hb = (t & 1) ? h2b1 : h2b0;
    unsigned short* ho = (t & 1) ? h2b0 : h2b1;
    const unsigned short* txp = texts_b + (long)t * BB * 320;

    f32x4 aR = {0,0,0,0}, aZ = {0,0,0,0}, aNH = {0,0,0,0}, aNI = {0,0,0,0};

    auto issueT = [&](int c, u32x4* r){
#pragma unroll
      for (int i = 0; i < 2; ++i){
        const int sl = tid + i * 256, row = sl >> 3, kq = sl & 7;
        r[i] = load_b128_llc(txp + (long)(mrow + row) * 320 + (c - 16) * 64 + kq * 8);
      }
    };
    auto issueH = [&](int c, u32x4* r){
#pragma unroll
      for (int i = 0; i < 2; ++i){
        const int sl = tid + i * 256, row = sl >> 3, kq = sl & 7;
        r[i] = load_b128_llc(hb + (long)(mrow + row) * EE + c * 64 + kq * 8);
      }
    };
    auto writeA = [&](int buf, u32x4* r){
#pragma unroll
      for (int i = 0; i < 2; ++i){
        const int sl = tid + i * 256, row = sl >> 3, kq = sl & 7;
        const int off = row * 144 + ((kq ^ (row & 7)) << 4);
        *(u32x4*)(Al + buf * ACH + off) = r[i];
      }
    };
    auto compute = [&](int c, bool hid){
      const char* Ab = Al + (c & 1) * ACH;
#pragma unroll
      for (int kf = 0; kf < 2; ++kf){
        const int g4 = kf * 4 + ahi;
        frag a = *(const frag*)(Ab + arow * 144 + ((g4 ^ (arow & 7)) << 4));
        frag b0 = *(const frag*)((char*)Wl + boff[0] + c * 128 + kf * 64);
        frag b1 = *(const frag*)((char*)Wl + boff[1] + c * 128 + kf * 64);
        frag b2 = *(const frag*)((char*)Wl + boff[2] + c * 128 + kf * 64);
        aR = __builtin_amdgcn_mfma_f32_16x16x32_bf16(a, b0, aR, 0, 0, 0);
        aZ = __builtin_amdgcn_mfma_f32_16x16x32_bf16(a, b1, aZ, 0, 0, 0);
        if (hid) aNH = __builtin_amdgcn_mfma_f32_16x16x32_bf16(a, b2, aNH, 0, 0, 0);
        else     aNI = __builtin_amdgcn_mfma_f32_16x16x32_bf16(a, b2, aNI, 0, 0, 0);
      }
    };

#define CHUNK(c, WN, ISSUE, HID) do{ \
    __syncthreads(); \
    WAITV(WN); \
    writeA((c) & 1, rg[(c) & 3]); \
    ISSUE; \
    __syncthreads(); \
    compute((c), (HID)); \
  }while(0)

    // ---- texts phase (no h dependency) ----
    issueT(16, rg[0]); issueT(17, rg[1]); issueT(18, rg[2]); issueT(19, rg[3]);
    CHUNK(16, 6, issueT(20, rg[0]), false);
    CHUNK(17, 6, (void)0, false);
    CHUNK(18, 4, (void)0, false);
    CHUNK(19, 2, (void)0, false);
    CHUNK(20, 0, (void)0, false);

    // ---- barrier + hidden phase ----
    if (t > 0){
      if (tid < NBLK2){
        const unsigned int* fp = flags + tid * 16;
        unsigned v = poll_u32_llc(fp);
        while (v < (unsigned)t){
          __builtin_amdgcn_s_sleep(2);
          v = poll_u32_llc(fp);
        }
      }
      __syncthreads();

      issueH(0, rg[0]); issueH(1, rg[1]); issueH(2, rg[2]); issueH(3, rg[3]);
#pragma unroll
      for (int c = 0; c < 12; ++c){
        CHUNK(c, 6, issueH(c + 4, rg[c & 3]), true);
      }
      CHUNK(12, 6, (void)0, true);
      CHUNK(13, 4, (void)0, true);
      CHUNK(14, 2, (void)0, true);
      CHUNK(15, 0, (void)0, true);
    }
#undef CHUNK

    // ---- GRU gates epilogue ----
#pragma unroll
    for (int j = 0; j < 4; ++j){
      const int brow = wv * 16 + (lane >> 4) * 4 + j;
      const float r = jsigmoid(aR[j] + bR);
      const float z = jsigmoid(aZ[j] + bZ);
      const float nn2 = tanhf(aNI[j] + biN + r * (aNH[j] + bhN));
      const float hn = (1.0f - z) * nn2 + z * hp[j];
      hp[j] = hn;
      store_u16_llc(ho + (long)(mrow + brow) * EE + e, (unsigned)f2bf(hn));
      if (t == li[j]) last[(long)(mrow + brow) * EE + e] = hn;
    }

    if (t < TT - 1){
      asm volatile("s_waitcnt vmcnt(0)" ::: "memory");
      __syncthreads();
      if (tid == 0) store_u32_llc(flagp, (unsigned)(t + 1));
    }
  }
}

// ---------------- BatchNorm ----------------
__global__ __launch_bounds__(256) void k_bn_stats(
    const float* __restrict__ last, float* __restrict__ mv)
{
  const int e = blockIdx.x * 256 + threadIdx.x;
  if (e >= EE) return;
  float s = 0.0f;
  for (int b = 0; b < BB; ++b) s += last[(long)b * EE + e];
  const float mean = s / 128.0f;
  float v = 0.0f;
  for (int b = 0; b < BB; ++b){ float d = last[(long)b * EE + e] - mean; v += d * d; }
  mv[e] = mean;
  mv[EE + e] = v / 128.0f;
}

__global__ __launch_bounds__(256) void k_bn_apply(
    const float* __restrict__ last, const float* __restrict__ mv,
    const float* __restrict__ gamma, const float* __restrict__ beta,
    float* __restrict__ out)
{
  const int gid = blockIdx.x * 256 + threadIdx.x;
  const int e = gid & 1023;
  const float xm = last[gid] - mv[e];
  out[gid] = gamma[e] * xm / sqrtf(mv[EE + e] + 1e-5f) + beta[e];
}

// ---------------- launcher ----------------
extern "C" void kernel_launch(void* const* d_in, const int* in_sizes, int n_in,
                              void* d_out, int out_size, void* d_ws, size_t ws_size,
                              hipStream_t stream)
{
  (void)in_sizes; (void)n_in; (void)out_size;
  const float* x     = (const float*)d_in[0];
  const int*   lens  = (const int*)d_in[1];
  const float* Wih_c = (const float*)d_in[3];
  const float* Whh_c = (const float*)d_in[4];
  const float* bih_c = (const float*)d_in[5];
  const float* bhh_c = (const float*)d_in[6];
  const float* Wmu   = (const float*)d_in[7];
  const float* bmu   = (const float*)d_in[8];
  const float* Wlv   = (const float*)d_in[9];
  const float* blv   = (const float*)d_in[10];
  const float* Wih_r = (const float*)d_in[11];
  const float* Whh_r = (const float*)d_in[12];
  const float* bih_r = (const float*)d_in[13];
  const float* bhh_r = (const float*)d_in[14];
  const float* gam   = (const float*)d_in[15];
  const float* bet   = (const float*)d_in[16];
  float* out = (float*)d_out;

  uint32_t nk[4][2];
  for (uint32_t i = 0; i < 4; ++i) tf2x32(0u, 42u, 0u, i, &nk[i][0], &nk[i][1]);

  float* ws = (float*)d_ws;
  size_t off = 0;
  float* U       = ws + off; off += 16384000;  // gi_all then mu_all (aliased)
  float* hx_all  = ws + off; off += 4915200;
  float* lv_all  = ws + off; off += 32768;
  float* Wp      = ws + off; off += 307200;    // packed Whh_c
  float* lastb   = ws + off; off += 131072;
  float* mv      = ws + off; off += 2048;
  unsigned int* flags = (unsigned int*)(ws + off); off += 2048;  // 128*16 uints
  unsigned short* texts_b = (unsigned short*)(ws + off); off += 2621440; // 16384x320 bf16
  unsigned short* h2b0    = (unsigned short*)(ws + off); off += 65536;   // 128x1024 bf16
  unsigned short* h2b1    = (unsigned short*)(ws + off); off += 65536;
  unsigned short* Whb     = (unsigned short*)(ws + off); off += 1572864; // 3072x1024 bf16
  unsigned short* Wib     = (unsigned short*)(ws + off); off += 491520;  // 3072x320 bf16
  if (ws_size < off * sizeof(float)) return;

  hipMemsetAsync(flags, 0, 2048 * sizeof(unsigned int), stream);

  // weight prep
  k_cvt_whh<<<dim3(12288), 256, 0, stream>>>(Whh_r, Whb);
  k_cvt_wih<<<dim3(3840), 256, 0, stream>>>(Wih_r, Wib);
  k_pack_whh<<<dim3(300), 256, 0, stream>>>(Whh_c, Wp);

  // stage-1 input projection + persistent recurrence
  k_gemm_gi<<<dim3(15, 128), 256, 0, stream>>>(x, Wih_c, bih_c, U);
  k_stage1<<<dim3(64), 1024, 0, stream>>>(Wp, bhh_c, U, hx_all);

  // batched mu / lv / sampling
  k_gemm_mu<<<dim3(16, 128), 256, 0, stream>>>(x, hx_all, Wmu, bmu, U);
  k_lv<<<dim3(4096), 256, 0, stream>>>(x, hx_all, Wlv, blv, lv_all);
  k_sample<<<dim3(16384), 256, 0, stream>>>(x, U, lv_all, texts_b, out,
      nk[0][0], nk[0][1], nk[1][0], nk[1][1],
      nk[2][0], nk[2][1], nk[3][0], nk[3][1]);

  // stage-2 persistent recurrence (LLC-coherent h + flat barrier)
  k_stage2<<<dim3(NBLK2), 256, 0, stream>>>(texts_b, Whb, Wib, bih_r, bhh_r, lens,
                                            h2b0, h2b1, lastb, flags);

  // batchnorm
  k_bn_stats<<<dim3(4), 256, 0, stream>>>(lastb, mv);
  k_bn_apply<<<dim3(512), 256, 0, stream>>>(lastb, mv, gam, bet, out);
}

// Round 7
// 2236.255 us; speedup vs baseline: 3.6620x; 1.2147x over previous
//
#include <hip/hip_runtime.h>
#include <stdint.h>

#define TT 128
#define BB 128
#define DD 300
#define EE 1024
#define GG 900
#define NMU 1000
#define ASP 500

#define OUT_SLOG 131072
#define OUT_ACT  163840
#define OUT_LOGP 196608

typedef unsigned int u32x4 __attribute__((ext_vector_type(4)));

// ---------------- threefry2x32 (JAX, 20 rounds) ----------------
__host__ __device__ static inline uint32_t rotl32(uint32_t x, int r){
  return (x << r) | (x >> (32 - r));
}

__host__ __device__ static inline void tf2x32(uint32_t k0, uint32_t k1,
                                              uint32_t x0, uint32_t x1,
                                              uint32_t* o0, uint32_t* o1){
  uint32_t ks2 = k0 ^ k1 ^ 0x1BD11BDAu;
#define TFR(r) { x0 += x1; x1 = rotl32(x1, r); x1 ^= x0; }
  x0 += k0; x1 += k1;
  TFR(13) TFR(15) TFR(26) TFR(6)
  x0 += k1; x1 += ks2 + 1u;
  TFR(17) TFR(29) TFR(16) TFR(24)
  x0 += ks2; x1 += k0 + 2u;
  TFR(13) TFR(15) TFR(26) TFR(6)
  x0 += k0; x1 += k1 + 3u;
  TFR(17) TFR(29) TFR(16) TFR(24)
  x0 += k1; x1 += ks2 + 4u;
  TFR(13) TFR(15) TFR(26) TFR(6)
  x0 += ks2; x1 += k0 + 5u;
#undef TFR
  *o0 = x0; *o1 = x1;
}

__device__ static inline uint32_t rng32(uint32_t k0, uint32_t k1, uint32_t idx){
  uint32_t a, b;
  tf2x32(k0, k1, 0u, idx, &a, &b);
  return a ^ b;
}

__device__ static inline float u01(uint32_t bits){
  return __uint_as_float((bits >> 9) | 0x3f800000u) - 1.0f;
}

__device__ static inline float jgumbel(uint32_t k0, uint32_t k1, uint32_t idx){
  float u = u01(rng32(k0, k1, idx));
  float l1 = logf(u + 1e-20f);
  return -logf(-l1 + 1e-20f);
}

__device__ static inline float erfinv32(float x){   // XLA ErfInv32 (Giles)
  float w = -log1pf(-x * x);
  float p;
  if (w < 5.0f){
    w = w - 2.5f;
    p = 2.81022636e-08f;
    p = 3.43273939e-07f  + p * w;
    p = -3.5233877e-06f  + p * w;
    p = -4.39150654e-06f + p * w;
    p = 0.00021858087f   + p * w;
    p = -0.00125372503f  + p * w;
    p = -0.00417768164f  + p * w;
    p = 0.246640727f     + p * w;
    p = 1.50140941f      + p * w;
  } else {
    w = sqrtf(w) - 3.0f;
    p = -0.000200214257f;
    p = 0.000100950558f  + p * w;
    p = 0.00134934322f   + p * w;
    p = -0.00367342844f  + p * w;
    p = 0.00573950773f   + p * w;
    p = -0.0076224613f   + p * w;
    p = 0.00943887047f   + p * w;
    p = 1.00167406f      + p * w;
    p = 2.83297682f      + p * w;
  }
  return p * x;
}

__device__ static inline float jnormal(uint32_t k0, uint32_t k1, uint32_t idx){
  float u = u01(rng32(k0, k1, idx));
  const float lo = -0.99999994f;
  float v = u * 2.0f + lo;
  v = fmaxf(lo, v);
  return 1.41421356237f * erfinv32(v);
}

__device__ static inline float jsigmoid(float x){
  return 1.0f / (1.0f + expf(-x));
}

__device__ static inline unsigned short f2bf(float f){   // RNE f32->bf16
  uint32_t u = __float_as_uint(f);
  uint32_t r = (u + 0x7fffu + ((u >> 16) & 1u)) >> 16;
  return (unsigned short)r;
}

// ---- LLC-coherent (cross-XCD) memory ops: sc0 sc1 = bypass L1+L2 ----
__device__ static inline u32x4 load_b128_llc(const void* p){
  u32x4 r;
  asm volatile("global_load_dwordx4 %0, %1, off sc0 sc1"
               : "=v"(r) : "v"(p) : "memory");
  return r;
}
__device__ static inline void store_u16_llc(void* p, unsigned v){
  asm volatile("global_store_short %0, %1, off sc0 sc1"
               :: "v"(p), "v"(v) : "memory");
}
__device__ static inline unsigned poll_u32_llc(const void* p){
  unsigned r;
  asm volatile("global_load_dword %0, %1, off sc0 sc1\n\ts_waitcnt vmcnt(0)"
               : "=v"(r) : "v"(p) : "memory");
  return r;
}
__device__ static inline void store_u32_llc(void* p, unsigned v){
  asm volatile("global_store_dword %0, %1, off sc0 sc1"
               :: "v"(p), "v"(v) : "memory");
}

#define WAITV(N) do{ asm volatile("s_waitcnt vmcnt(" #N ")" ::: "memory"); \
                     __builtin_amdgcn_sched_barrier(0); }while(0)

// ---------------- GEMM1: gi_all[r=(t*BB+b)][900] = x@Wih_c^T + bih ----------------
// 128x64 tile, 8x4 per thread, K=300
#define FMA4(ACC, S, B) { ACC.x += (S)*(B).x; ACC.y += (S)*(B).y; \
                          ACC.z += (S)*(B).z; ACC.w += (S)*(B).w; }

__global__ __launch_bounds__(256) void k_gemm_gi(
    const float* __restrict__ X, const float* __restrict__ W,
    const float* __restrict__ bias, float* __restrict__ C)
{
  __shared__ float As[16][132];
  __shared__ float Bs[16][68];
  const int tid = threadIdx.x;
  const int rbase = blockIdx.y * 128;
  const int cbase = blockIdx.x * 64;
  const int tx = tid & 15, ty = tid >> 4;
  const int sr = tid >> 2, sq = tid & 3;
  const int wj = cbase + sr;

  float4 acc[8];
#pragma unroll
  for (int i = 0; i < 8; ++i) acc[i] = (float4){0,0,0,0};

  for (int k0 = 0; k0 < 304; k0 += 16){
    const int k = k0 + sq * 4;
#pragma unroll
    for (int i = 0; i < 2; ++i){
      const int row = sr + i * 64;
      const int rg = rbase + row;
      float4 va = {0,0,0,0};
      if (k < DD) va = *(const float4*)(X + ((long)(rg & 127) * TT + (rg >> 7)) * DD + k);
      As[sq*4+0][row] = va.x; As[sq*4+1][row] = va.y;
      As[sq*4+2][row] = va.z; As[sq*4+3][row] = va.w;
    }
    {
      float4 vb = {0,0,0,0};
      if (k < DD && wj < GG) vb = *(const float4*)(W + (long)wj * DD + k);
      Bs[sq*4+0][sr] = vb.x; Bs[sq*4+1][sr] = vb.y;
      Bs[sq*4+2][sr] = vb.z; Bs[sq*4+3][sr] = vb.w;
    }
    __syncthreads();
#pragma unroll
    for (int kk = 0; kk < 16; ++kk){
      const float4 b  = *(const float4*)&Bs[kk][tx * 4];
      const float4 a0 = *(const float4*)&As[kk][ty * 8];
      const float4 a1 = *(const float4*)&As[kk][ty * 8 + 4];
      FMA4(acc[0], a0.x, b); FMA4(acc[1], a0.y, b);
      FMA4(acc[2], a0.z, b); FMA4(acc[3], a0.w, b);
      FMA4(acc[4], a1.x, b); FMA4(acc[5], a1.y, b);
      FMA4(acc[6], a1.z, b); FMA4(acc[7], a1.w, b);
    }
    __syncthreads();
  }
  const int ci = cbase + tx * 4;
  float bv[4];
#pragma unroll
  for (int j = 0; j < 4; ++j) bv[j] = (ci + j < GG) ? bias[ci + j] : 0.0f;
#pragma unroll
  for (int i = 0; i < 8; ++i){
    const int r = rbase + ty * 8 + i;
    float vals[4] = {acc[i].x + bv[0], acc[i].y + bv[1],
                     acc[i].z + bv[2], acc[i].w + bv[3]};
    float* crow = C + (long)r * GG;
    if (ci + 3 < GG){
      float4 st = {vals[0], vals[1], vals[2], vals[3]};
      *(float4*)(crow + ci) = st;
    } else {
#pragma unroll
      for (int j = 0; j < 4; ++j) if (ci + j < GG) crow[ci + j] = vals[j];
    }
  }
}

// ---------------- GEMM-mu: 128x64 tile, 8x4 per thread ----------------
__global__ __launch_bounds__(256) void k_gemm_mu(
    const float* __restrict__ X, const float* __restrict__ HX,
    const float* __restrict__ W, const float* __restrict__ bias,
    float* __restrict__ C)
{
  __shared__ float As[16][132];
  __shared__ float Bs[16][68];
  const int tid = threadIdx.x;
  const int rbase = blockIdx.y * 128;
  const int cbase = blockIdx.x * 64;
  const int tx = tid & 15, ty = tid >> 4;
  const int sr = tid >> 2, sq = tid & 3;
  const int wj = cbase + sr;

  float4 acc[8];
#pragma unroll
  for (int i = 0; i < 8; ++i) acc[i] = (float4){0,0,0,0};

  for (int k0 = 0; k0 < 608; k0 += 16){
    const int k = k0 + sq * 4;
#pragma unroll
    for (int i = 0; i < 2; ++i){
      const int row = sr + i * 64;
      const int rg = rbase + row;
      float4 va = {0,0,0,0};
      if (k < 300)      va = *(const float4*)(X + ((long)(rg & 127) * TT + (rg >> 7)) * DD + k);
      else if (k < 600) va = *(const float4*)(HX + (long)rg * DD + (k - 300));
      va.x = fmaxf(va.x, 0.f); va.y = fmaxf(va.y, 0.f);
      va.z = fmaxf(va.z, 0.f); va.w = fmaxf(va.w, 0.f);
      As[sq*4+0][row] = va.x; As[sq*4+1][row] = va.y;
      As[sq*4+2][row] = va.z; As[sq*4+3][row] = va.w;
    }
    {
      float4 vb = {0,0,0,0};
      if (k < 600 && wj < NMU) vb = *(const float4*)(W + (long)wj * 600 + k);
      Bs[sq*4+0][sr] = vb.x; Bs[sq*4+1][sr] = vb.y;
      Bs[sq*4+2][sr] = vb.z; Bs[sq*4+3][sr] = vb.w;
    }
    __syncthreads();
#pragma unroll
    for (int kk = 0; kk < 16; ++kk){
      const float4 b  = *(const float4*)&Bs[kk][tx * 4];
      const float4 a0 = *(const float4*)&As[kk][ty * 8];
      const float4 a1 = *(const float4*)&As[kk][ty * 8 + 4];
      FMA4(acc[0], a0.x, b); FMA4(acc[1], a0.y, b);
      FMA4(acc[2], a0.z, b); FMA4(acc[3], a0.w, b);
      FMA4(acc[4], a1.x, b); FMA4(acc[5], a1.y, b);
      FMA4(acc[6], a1.z, b); FMA4(acc[7], a1.w, b);
    }
    __syncthreads();
  }
  const int ci = cbase + tx * 4;
  float bv[4];
#pragma unroll
  for (int j = 0; j < 4; ++j) bv[j] = (ci + j < NMU) ? bias[ci + j] : 0.0f;
#pragma unroll
  for (int i = 0; i < 8; ++i){
    const int r = rbase + ty * 8 + i;
    float vals[4] = {acc[i].x + bv[0], acc[i].y + bv[1],
                     acc[i].z + bv[2], acc[i].w + bv[3]};
    float* crow = C + (long)r * NMU;
    if (ci + 3 < NMU){
      float4 st = {vals[0], vals[1], vals[2], vals[3]};
      *(float4*)(crow + ci) = st;
    } else {
#pragma unroll
      for (int j = 0; j < 4; ++j) if (ci + j < NMU) crow[ci + j] = vals[j];
    }
  }
}

// ---------------- lv (pre-softplus), wave-per-row ----------------
__global__ __launch_bounds__(256) void k_lv(
    const float* __restrict__ X, const float* __restrict__ HX,
    const float* __restrict__ Wlv, const float* __restrict__ blv,
    float* __restrict__ LV)
{
  const int r = blockIdx.x * 4 + (threadIdx.x >> 6);   // 16384 rows
  const int lane = threadIdx.x & 63;
  const float* xr = X + ((long)(r & 127) * TT + (r >> 7)) * DD;
  const float* hr = HX + (long)r * DD;
  float a0 = 0.0f, a1 = 0.0f;
  for (int k = lane; k < DD; k += 64){
    float v = fmaxf(xr[k], 0.0f);
    a0 += v * Wlv[k];       a1 += v * Wlv[600 + k];
    float w = fmaxf(hr[k], 0.0f);
    a0 += w * Wlv[300 + k]; a1 += w * Wlv[900 + k];
  }
#pragma unroll
  for (int off = 32; off > 0; off >>= 1){
    a0 += __shfl_down(a0, off);
    a1 += __shfl_down(a1, off);
  }
  if (lane == 0){
    LV[(long)r * 2 + 0] = a0 + blv[0];
    LV[(long)r * 2 + 1] = a1 + blv[1];
  }
}

// ---------------- Whh_c pack: Wp[kq][1024 j][4 c] = Whh_c[j][4kq+c] ----------------
__global__ __launch_bounds__(256) void k_pack_whh(
    const float* __restrict__ W, float* __restrict__ Wp)
{
  const int i = blockIdx.x * 256 + threadIdx.x;   // 75*1024
  const int kq = i >> 10, j = i & 1023;
  float4 v = {0,0,0,0};
  if (kq < 75 && j < GG){
    const float* s = W + (long)j * DD + kq * 4;
    v.x = s[0]; v.y = s[1]; v.z = s[2]; v.w = s[3];
  }
  *(float4*)(Wp + (long)i * 4) = v;
}

// ---------------- stage-1: 256 blocks = 64 batch-pairs x 4 jj-slices ----------------
// Block (bp, js): owns batch rows {2bp,2bp+1} x hidden slice jj in [js*75, js*75+75),
// all 3 gates. Per-CU weight stream drops 1.2MB -> 270KB/step (L1->L2 request-path
// was the R6 wall at ~121GB/s/CU). h exchanged in the 4-block cluster via LLC
// (sc0 sc1) with parity double-buffer + per-block flag.
#define S1PAD 304

__global__ __launch_bounds__(256) void k_stage1(
    const float* __restrict__ Wp, const float* __restrict__ bhh,
    const float* __restrict__ gi_all, float* __restrict__ hx_all,
    float* __restrict__ hex, unsigned int* __restrict__ flagsA)
{
  __shared__ float hs[2][S1PAD];
  __shared__ float ghs[2][240];
  const int tid = threadIdx.x;
  const int bid = blockIdx.x;
  const int bp = bid >> 2, js = bid & 3;
  const int b0 = bp * 2;
  const int jj0 = js * 75;

  const bool mact = tid < 225;                        // matvec thread
  const int mg = tid / 75, mj = tid - mg * 75;
  const int jcol = mg * 300 + jj0 + mj;               // flat j in [0,900)
  const float* wbase = Wp + (long)jcol * 4;

  const bool gact = tid < 150;                        // gate thread
  const int grow = tid / 75, gj = tid - grow * 75;
  const int gjj = jj0 + gj;
  float bhr = 0.f, bhz = 0.f, bhn = 0.f;
  if (gact){ bhr = bhh[gjj]; bhz = bhh[DD + gjj]; bhn = bhh[2*DD + gjj]; }

  for (int i = tid; i < 2 * S1PAD; i += 256) ((float*)hs)[i] = 0.f;
  __syncthreads();

  unsigned int* myflag = flagsA + bid * 16;

  for (int t = 0; t < TT; ++t){
    // gi prefetch (independent of h)
    float gir = 0.f, giz = 0.f, gin = 0.f;
    if (gact){
      const float* gp = gi_all + ((long)t * BB + b0 + grow) * GG;
      gir = gp[gjj]; giz = gp[DD + gjj]; gin = gp[2*DD + gjj];
    }

    // matvec: gh[jcol] for both rows (h from LDS broadcast, W from L2)
    if (mact){
      float4 a0 = {0,0,0,0}, a1 = {0,0,0,0};
#pragma unroll 5
      for (int kq = 0; kq < 75; ++kq){
        const float4 w  = *(const float4*)(wbase + (long)kq * 4096);
        const float4 h0 = *(const float4*)&hs[0][kq * 4];
        const float4 h1 = *(const float4*)&hs[1][kq * 4];
        a0.x = fmaf(w.x, h0.x, a0.x); a0.y = fmaf(w.y, h0.y, a0.y);
        a0.z = fmaf(w.z, h0.z, a0.z); a0.w = fmaf(w.w, h0.w, a0.w);
        a1.x = fmaf(w.x, h1.x, a1.x); a1.y = fmaf(w.y, h1.y, a1.y);
        a1.z = fmaf(w.z, h1.z, a1.z); a1.w = fmaf(w.w, h1.w, a1.w);
      }
      ghs[0][mg * 80 + mj] = (a0.x + a0.y) + (a0.z + a0.w);
      ghs[1][mg * 80 + mj] = (a1.x + a1.y) + (a1.z + a1.w);
    }
    __syncthreads();

    // gates + h update + exchange store (own slice)
    const int par = t & 1;
    if (gact){
      const float r = jsigmoid(gir + ghs[grow][gj] + bhr);
      const float z = jsigmoid(giz + ghs[grow][80 + gj] + bhz);
      const float n = tanhf(gin + r * (ghs[grow][160 + gj] + bhn));
      const float hn = (1.0f - z) * n + z * hs[grow][gjj];
      hx_all[((long)t * BB + b0 + grow) * DD + gjj] = hn;
      if (t < TT - 1)
        store_u32_llc(hex + ((long)par * BB + b0 + grow) * S1PAD + gjj,
                      __float_as_uint(hn));
    }

    if (t < TT - 1){
      asm volatile("s_waitcnt vmcnt(0)" ::: "memory");
      __syncthreads();
      if (tid == 0) store_u32_llc(myflag, (unsigned)(t + 1));
      if (tid < 4){
        const unsigned int* fp = flagsA + (bp * 4 + tid) * 16;
        unsigned v = poll_u32_llc(fp);
        while (v < (unsigned)(t + 1)){
          __builtin_amdgcn_s_sleep(1);
          v = poll_u32_llc(fp);
        }
      }
      __syncthreads();
      // refresh full h (600 floats) from LLC exchange buffer
      {
        const float* src = hex + (long)par * BB * S1PAD + (long)b0 * S1PAD;
        const int i0 = tid, i1 = tid + 256, i2 = tid + 512;
        const int r0 = i0 / 300, c0 = i0 - r0 * 300;
        const int r1 = i1 / 300, c1 = i1 - r1 * 300;
        unsigned v0, v1, v2 = 0;
        v0 = poll_u32_llc(src + r0 * S1PAD + c0);
        v1 = poll_u32_llc(src + r1 * S1PAD + c1);
        if (i2 < 600){
          const int r2 = i2 / 300, c2 = i2 - r2 * 300;
          v2 = poll_u32_llc(src + r2 * S1PAD + c2);
          hs[r2][c2] = __uint_as_float(v2);
        }
        hs[r0][c0] = __uint_as_float(v0);
        hs[r1][c1] = __uint_as_float(v1);
      }
      __syncthreads();
    }
  }
}

// ---------------- sampling ----------------
__global__ __launch_bounds__(256) void k_sample(
    const float* __restrict__ X, const float* __restrict__ mu_all,
    const float* __restrict__ lv_all, unsigned short* __restrict__ texts_b,
    float* __restrict__ out,
    const uint32_t k0a, const uint32_t k0b, const uint32_t k1a, const uint32_t k1b,
    const uint32_t k2a, const uint32_t k2b, const uint32_t k3a, const uint32_t k3b)
{
  const int r = blockIdx.x;            // t*128 + b
  const int t = r >> 7, b = r & 127;
  const int tid = threadIdx.x;
  const int h = tid >> 7, lane = tid & 127;
  __shared__ float redf[256];
  __shared__ int   redi[256];
  __shared__ float yw[2], lyw[2], att_s[2];

  const uint32_t rowbase = (uint32_t)((t * 256 + b * 2 + h) * 500);
  float zv[4], ev[4];
  float lmax = -3.0e38f;
#pragma unroll
  for (int s = 0; s < 4; ++s){
    const int a = lane + s * 128;
    float z = -3.0e38f;
    if (a < ASP){
      float g = jgumbel(k0a, k0b, rowbase + (uint32_t)a);
      float m = mu_all[(long)r * NMU + h * ASP + a];
      z = (m + g) / 0.8f;
    }
    zv[s] = z;
    lmax = fmaxf(lmax, z);
  }
  redf[tid] = lmax;
  __syncthreads();
  for (int off = 64; off > 0; off >>= 1){
    if (lane < off) redf[tid] = fmaxf(redf[tid], redf[tid + off]);
    __syncthreads();
  }
  const float mx = redf[h << 7];
  __syncthreads();
  float lsum = 0.0f;
#pragma unroll
  for (int s = 0; s < 4; ++s){
    const int a = lane + s * 128;
    float e = 0.0f;
    if (a < ASP) e = expf(zv[s] - mx);
    ev[s] = e;
    lsum += e;
  }
  redf[tid] = lsum;
  __syncthreads();
  for (int off = 64; off > 0; off >>= 1){
    if (lane < off) redf[tid] += redf[tid + off];
    __syncthreads();
  }
  const float S = redf[h << 7];
  __syncthreads();
  float bestv = -3.0e38f;
  int besti = 0x7fffffff;
#pragma unroll
  for (int s = 0; s < 4; ++s){
    const int a = lane + s * 128;
    if (a < ASP){
      float y = ev[s] / S;
      float ly = logf(y);
      float gc = jgumbel(k1a, k1b, rowbase + (uint32_t)a);
      float val = ly + gc;
      if (val > bestv){ bestv = val; besti = a; }
    }
  }
  redf[tid] = bestv; redi[tid] = besti;
  __syncthreads();
  for (int off = 64; off > 0; off >>= 1){
    if (lane < off){
      float v2 = redf[tid + off]; int i2 = redi[tid + off];
      if (v2 > redf[tid] || (v2 == redf[tid] && i2 < redi[tid])){
        redf[tid] = v2; redi[tid] = i2;
      }
    }
    __syncthreads();
  }
  const int ind = redi[h << 7];
#pragma unroll
  for (int s = 0; s < 4; ++s){
    const int a = lane + s * 128;
    if (a == ind){
      float y = ev[s] / S;
      yw[h] = y;
      lyw[h] = logf(y);
    }
  }
  __syncthreads();
  if (lane == 0){
    const float yv = yw[h];
    const float ly = lyw[h];
    const float yh = (1.0f - yv) + yv;
    const float act = ((float)ind * yh) / 500.0f;
    const float lvr = lv_all[(long)r * 2 + h];
    const float lv = fmaxf(lvr, 0.0f) + log1pf(expf(-fabsf(lvr)));
    const float sd = expf(0.5f * lv);
    const uint32_t ei = (uint32_t)(r * 2 + h);
    const float e1 = jnormal(k2a, k2b, ei);
    const float e2 = jnormal(k3a, k3b, ei);
    const float s1 = act + sd * e1;
    const float s2 = act + sd * e2;
    const float dd = (s2 - act) / sd;
    const float lp = -0.5f * (dd * dd) - logf(sd) - 0.9189385332046727f;
    const float attv = 20.0f * jsigmoid(s1);
    out[OUT_SLOG + (long)b * 256 + t * 2 + h]  = ly;
    out[OUT_ACT  + (long)b * 256 + h * 128 + t] = act;
    out[OUT_LOGP + (long)b * 256 + h * 128 + t] = lp;
    att_s[h] = attv;
  }
  __syncthreads();
  const float* xr = X + ((long)b * TT + t) * DD;
  unsigned short* tr = texts_b + (long)r * 320;
  for (int j = tid; j < 320; j += 256){
    unsigned short o = 0;
    if (j < 300) o = f2bf(xr[j] * att_s[j / 150]);
    tr[j] = o;
  }
}

// ---------------- weight conversion to bf16 ----------------
__global__ __launch_bounds__(256) void k_cvt_whh(
    const float* __restrict__ W, unsigned short* __restrict__ O)
{
  const int i = blockIdx.x * 256 + threadIdx.x;   // 3072*1024
  O[i] = f2bf(W[i]);
}

__global__ __launch_bounds__(256) void k_cvt_wih(
    const float* __restrict__ W, unsigned short* __restrict__ O)
{
  const int i = blockIdx.x * 256 + threadIdx.x;   // 3072*320
  const int rw = i / 320, c = i - rw * 320;
  O[i] = (c < DD) ? f2bf(W[(long)rw * DD + c]) : (unsigned short)0;
}

// ---------------- stage-2 persistent: 128 blocks, LLC-coherent h + flat barrier ----------------
#define NBLK2 128
#define WPITCH 2704   // 1344*2 + 16
#define ACH 9216      // 64 rows * 144B

__global__ __launch_bounds__(256) void k_stage2(
    const unsigned short* __restrict__ texts_b,
    const unsigned short* __restrict__ Whb,
    const unsigned short* __restrict__ Wib,
    const float* __restrict__ bih, const float* __restrict__ bhh,
    const int* __restrict__ lengths,
    unsigned short* __restrict__ h2b0, unsigned short* __restrict__ h2b1,
    float* __restrict__ last,
    unsigned int* __restrict__ flags)
{
  __shared__ __align__(16) char lds[148224];   // W: 129792 | A: 2*9216
  unsigned short* Wl = (unsigned short*)lds;
  char* Al = lds + 129792;

  const int tid = threadIdx.x;
  const int bid = blockIdx.x;
  const int m = bid >> 6, n = bid & 63;
  const int e0 = n * 16;
  const int mrow = m * 64;
  const int wv = tid >> 6, lane = tid & 63;

  // ---- stage W into LDS once ----
  for (int s = tid; s < 48 * 168; s += 256){
    const int row = s / 168, q = s - row * 168;
    const int g = row >> 4, nn = row & 15;
    const long wrow = (long)g * EE + e0 + nn;
    uint4 v;
    if (q < 128) v = *(const uint4*)(Whb + wrow * EE + q * 8);
    else         v = *(const uint4*)(Wib + wrow * 320 + (q - 128) * 8);
    *(uint4*)((char*)Wl + (long)row * WPITCH + q * 16) = v;
  }

  const int e = e0 + (lane & 15);
  const float bR = bih[e] + bhh[e];
  const float bZ = bih[EE + e] + bhh[EE + e];
  const float biN = bih[2*EE + e];
  const float bhN = bhh[2*EE + e];
  int li[4];
  float hp[4];
#pragma unroll
  for (int j = 0; j < 4; ++j){
    const int brow = wv * 16 + (lane >> 4) * 4 + j;
    int l = lengths[mrow + brow] - 1; if (l < 0) l += TT;
    li[j] = l;
    hp[j] = 0.0f;
  }
  __syncthreads();

  using frag = __attribute__((ext_vector_type(8))) short;
  using f32x4 = __attribute__((ext_vector_type(4))) float;

  const int arow = wv * 16 + (lane & 15);
  const int ahi = lane >> 4;
  int boff[3];
#pragma unroll
  for (int g = 0; g < 3; ++g) boff[g] = (g * 16 + (lane & 15)) * WPITCH + ahi * 16;

  u32x4 rg[4][2];
  unsigned int* flagp = flags + bid * 16;

  for (int t = 0; t < TT; ++t){
    const unsigned short* hb = (t & 1) ? h2b1 : h2b0;
    unsigned short* ho = (t & 1) ? h2b0 : h2b1;
    const unsigned short* txp = texts_b + (long)t * BB * 320;

    f32x4 aR = {0,0,0,0}, aZ = {0,0,0,0}, aNH = {0,0,0,0}, aNI = {0,0,0,0};

    auto issueT = [&](int c, u32x4* r){
#pragma unroll
      for (int i = 0; i < 2; ++i){
        const int sl = tid + i * 256, row = sl >> 3, kq = sl & 7;
        r[i] = load_b128_llc(txp + (long)(mrow + row) * 320 + (c - 16) * 64 + kq * 8);
      }
    };
    auto issueH = [&](int c, u32x4* r){
#pragma unroll
      for (int i = 0; i < 2; ++i){
        const int sl = tid + i * 256, row = sl >> 3, kq = sl & 7;
        r[i] = load_b128_llc(hb + (long)(mrow + row) * EE + c * 64 + kq * 8);
      }
    };
    auto writeA = [&](int buf, u32x4* r){
#pragma unroll
      for (int i = 0; i < 2; ++i){
        const int sl = tid + i * 256, row = sl >> 3, kq = sl & 7;
        const int off = row * 144 + ((kq ^ (row & 7)) << 4);
        *(u32x4*)(Al + buf * ACH + off) = r[i];
      }
    };
    auto compute = [&](int c, bool hid){
      const char* Ab = Al + (c & 1) * ACH;
#pragma unroll
      for (int kf = 0; kf < 2; ++kf){
        const int g4 = kf * 4 + ahi;
        frag a = *(const frag*)(Ab + arow * 144 + ((g4 ^ (arow & 7)) << 4));
        frag b0 = *(const frag*)((char*)Wl + boff[0] + c * 128 + kf * 64);
        frag b1 = *(const frag*)((char*)Wl + boff[1] + c * 128 + kf * 64);
        frag b2 = *(const frag*)((char*)Wl + boff[2] + c * 128 + kf * 64);
        aR = __builtin_amdgcn_mfma_f32_16x16x32_bf16(a, b0, aR, 0, 0, 0);
        aZ = __builtin_amdgcn_mfma_f32_16x16x32_bf16(a, b1, aZ, 0, 0, 0);
        if (hid) aNH = __builtin_amdgcn_mfma_f32_16x16x32_bf16(a, b2, aNH, 0, 0, 0);
        else     aNI = __builtin_amdgcn_mfma_f32_16x16x32_bf16(a, b2, aNI, 0, 0, 0);
      }
    };

#define CHUNK(c, WN, ISSUE, HID) do{ \
    __syncthreads(); \
    WAITV(WN); \
    writeA((c) & 1, rg[(c) & 3]); \
    ISSUE; \
    __syncthreads(); \
    compute((c), (HID)); \
  }while(0)

    // ---- texts phase (no h dependency) ----
    issueT(16, rg[0]); issueT(17, rg[1]); issueT(18, rg[2]); issueT(19, rg[3]);
    CHUNK(16, 6, issueT(20, rg[0]), false);
    CHUNK(17, 6, (void)0, false);
    CHUNK(18, 4, (void)0, false);
    CHUNK(19, 2, (void)0, false);
    CHUNK(20, 0, (void)0, false);

    // ---- barrier + hidden phase ----
    if (t > 0){
      if (tid < NBLK2){
        const unsigned int* fp = flags + tid * 16;
        unsigned v = poll_u32_llc(fp);
        while (v < (unsigned)t){
          __builtin_amdgcn_s_sleep(2);
          v = poll_u32_llc(fp);
        }
      }
      __syncthreads();

      issueH(0, rg[0]); issueH(1, rg[1]); issueH(2, rg[2]); issueH(3, rg[3]);
#pragma unroll
      for (int c = 0; c < 12; ++c){
        CHUNK(c, 6, issueH(c + 4, rg[c & 3]), true);
      }
      CHUNK(12, 6, (void)0, true);
      CHUNK(13, 4, (void)0, true);
      CHUNK(14, 2, (void)0, true);
      CHUNK(15, 0, (void)0, true);
    }
#undef CHUNK

    // ---- GRU gates epilogue ----
#pragma unroll
    for (int j = 0; j < 4; ++j){
      const int brow = wv * 16 + (lane >> 4) * 4 + j;
      const float r = jsigmoid(aR[j] + bR);
      const float z = jsigmoid(aZ[j] + bZ);
      const float nn2 = tanhf(aNI[j] + biN + r * (aNH[j] + bhN));
      const float hn = (1.0f - z) * nn2 + z * hp[j];
      hp[j] = hn;
      store_u16_llc(ho + (long)(mrow + brow) * EE + e, (unsigned)f2bf(hn));
      if (t == li[j]) last[(long)(mrow + brow) * EE + e] = hn;
    }

    if (t < TT - 1){
      asm volatile("s_waitcnt vmcnt(0)" ::: "memory");
      __syncthreads();
      if (tid == 0) store_u32_llc(flagp, (unsigned)(t + 1));
    }
  }
}

// ---------------- BatchNorm ----------------
__global__ __launch_bounds__(256) void k_bn_stats(
    const float* __restrict__ last, float* __restrict__ mv)
{
  const int e = blockIdx.x * 256 + threadIdx.x;
  if (e >= EE) return;
  float s = 0.0f;
  for (int b = 0; b < BB; ++b) s += last[(long)b * EE + e];
  const float mean = s / 128.0f;
  float v = 0.0f;
  for (int b = 0; b < BB; ++b){ float d = last[(long)b * EE + e] - mean; v += d * d; }
  mv[e] = mean;
  mv[EE + e] = v / 128.0f;
}

__global__ __launch_bounds__(256) void k_bn_apply(
    const float* __restrict__ last, const float* __restrict__ mv,
    const float* __restrict__ gamma, const float* __restrict__ beta,
    float* __restrict__ out)
{
  const int gid = blockIdx.x * 256 + threadIdx.x;
  const int e = gid & 1023;
  const float xm = last[gid] - mv[e];
  out[gid] = gamma[e] * xm / sqrtf(mv[EE + e] + 1e-5f) + beta[e];
}

// ---------------- launcher ----------------
extern "C" void kernel_launch(void* const* d_in, const int* in_sizes, int n_in,
                              void* d_out, int out_size, void* d_ws, size_t ws_size,
                              hipStream_t stream)
{
  (void)in_sizes; (void)n_in; (void)out_size;
  const float* x     = (const float*)d_in[0];
  const int*   lens  = (const int*)d_in[1];
  const float* Wih_c = (const float*)d_in[3];
  const float* Whh_c = (const float*)d_in[4];
  const float* bih_c = (const float*)d_in[5];
  const float* bhh_c = (const float*)d_in[6];
  const float* Wmu   = (const float*)d_in[7];
  const float* bmu   = (const float*)d_in[8];
  const float* Wlv   = (const float*)d_in[9];
  const float* blv   = (const float*)d_in[10];
  const float* Wih_r = (const float*)d_in[11];
  const float* Whh_r = (const float*)d_in[12];
  const float* bih_r = (const float*)d_in[13];
  const float* bhh_r = (const float*)d_in[14];
  const float* gam   = (const float*)d_in[15];
  const float* bet   = (const float*)d_in[16];
  float* out = (float*)d_out;

  uint32_t nk[4][2];
  for (uint32_t i = 0; i < 4; ++i) tf2x32(0u, 42u, 0u, i, &nk[i][0], &nk[i][1]);

  float* ws = (float*)d_ws;
  size_t off = 0;
  float* U       = ws + off; off += 16384000;  // gi_all then mu_all (aliased)
  float* hx_all  = ws + off; off += 4915200;
  float* lv_all  = ws + off; off += 32768;
  float* Wp      = ws + off; off += 307200;    // packed Whh_c
  float* lastb   = ws + off; off += 131072;
  float* mv      = ws + off; off += 2048;
  float* hex     = ws + off; off += 77824;     // [2][128][304] f32 stage-1 exchange
  unsigned int* flags  = (unsigned int*)(ws + off); off += 2048;  // stage-2: 128*16
  unsigned int* flagsA = (unsigned int*)(ws + off); off += 4096;  // stage-1: 256*16
  unsigned short* texts_b = (unsigned short*)(ws + off); off += 2621440; // 16384x320 bf16
  unsigned short* h2b0    = (unsigned short*)(ws + off); off += 65536;   // 128x1024 bf16
  unsigned short* h2b1    = (unsigned short*)(ws + off); off += 65536;
  unsigned short* Whb     = (unsigned short*)(ws + off); off += 1572864; // 3072x1024 bf16
  unsigned short* Wib     = (unsigned short*)(ws + off); off += 491520;  // 3072x320 bf16
  if (ws_size < off * sizeof(float)) return;

  hipMemsetAsync(flags, 0, 2048 * sizeof(unsigned int), stream);
  hipMemsetAsync(flagsA, 0, 4096 * sizeof(unsigned int), stream);

  // weight prep
  k_cvt_whh<<<dim3(12288), 256, 0, stream>>>(Whh_r, Whb);
  k_cvt_wih<<<dim3(3840), 256, 0, stream>>>(Wih_r, Wib);
  k_pack_whh<<<dim3(300), 256, 0, stream>>>(Whh_c, Wp);

  // stage-1 input projection + persistent jj-split recurrence
  k_gemm_gi<<<dim3(15, 128), 256, 0, stream>>>(x, Wih_c, bih_c, U);
  k_stage1<<<dim3(256), 256, 0, stream>>>(Wp, bhh_c, U, hx_all, hex, flagsA);

  // batched mu / lv / sampling
  k_gemm_mu<<<dim3(16, 128), 256, 0, stream>>>(x, hx_all, Wmu, bmu, U);
  k_lv<<<dim3(4096), 256, 0, stream>>>(x, hx_all, Wlv, blv, lv_all);
  k_sample<<<dim3(16384), 256, 0, stream>>>(x, U, lv_all, texts_b, out,
      nk[0][0], nk[0][1], nk[1][0], nk[1][1],
      nk[2][0], nk[2][1], nk[3][0], nk[3][1]);

  // stage-2 persistent recurrence (LLC-coherent h + flat barrier)
  k_stage2<<<dim3(NBLK2), 256, 0, stream>>>(texts_b, Whb, Wib, bih_r, bhh_r, lens,
                                            h2b0, h2b1, lastb, flags);

  // batchnorm
  k_bn_stats<<<dim3(4), 256, 0, stream>>>(lastb, mv);
  k_bn_apply<<<dim3(512), 256, 0, stream>>>(lastb, mv, gam, bet, out);
}

// Round 9
// 2187.802 us; speedup vs baseline: 3.7431x; 1.0221x over previous
//
#include <hip/hip_runtime.h>
#include <stdint.h>

#define TT 128
#define BB 128
#define DD 300
#define EE 1024
#define GG 900
#define NMU 1000
#define ASP 500

#define OUT_SLOG 131072
#define OUT_ACT  163840
#define OUT_LOGP 196608

typedef unsigned int u32x4 __attribute__((ext_vector_type(4)));

// ---------------- threefry2x32 (JAX, 20 rounds) ----------------
__host__ __device__ static inline uint32_t rotl32(uint32_t x, int r){
  return (x << r) | (x >> (32 - r));
}

__host__ __device__ static inline void tf2x32(uint32_t k0, uint32_t k1,
                                              uint32_t x0, uint32_t x1,
                                              uint32_t* o0, uint32_t* o1){
  uint32_t ks2 = k0 ^ k1 ^ 0x1BD11BDAu;
#define TFR(r) { x0 += x1; x1 = rotl32(x1, r); x1 ^= x0; }
  x0 += k0; x1 += k1;
  TFR(13) TFR(15) TFR(26) TFR(6)
  x0 += k1; x1 += ks2 + 1u;
  TFR(17) TFR(29) TFR(16) TFR(24)
  x0 += ks2; x1 += k0 + 2u;
  TFR(13) TFR(15) TFR(26) TFR(6)
  x0 += k0; x1 += k1 + 3u;
  TFR(17) TFR(29) TFR(16) TFR(24)
  x0 += k1; x1 += ks2 + 4u;
  TFR(13) TFR(15) TFR(26) TFR(6)
  x0 += ks2; x1 += k0 + 5u;
#undef TFR
  *o0 = x0; *o1 = x1;
}

__device__ static inline uint32_t rng32(uint32_t k0, uint32_t k1, uint32_t idx){
  uint32_t a, b;
  tf2x32(k0, k1, 0u, idx, &a, &b);
  return a ^ b;
}

__device__ static inline float u01(uint32_t bits){
  return __uint_as_float((bits >> 9) | 0x3f800000u) - 1.0f;
}

__device__ static inline float jgumbel(uint32_t k0, uint32_t k1, uint32_t idx){
  float u = u01(rng32(k0, k1, idx));
  float l1 = logf(u + 1e-20f);
  return -logf(-l1 + 1e-20f);
}

__device__ static inline float erfinv32(float x){   // XLA ErfInv32 (Giles)
  float w = -log1pf(-x * x);
  float p;
  if (w < 5.0f){
    w = w - 2.5f;
    p = 2.81022636e-08f;
    p = 3.43273939e-07f  + p * w;
    p = -3.5233877e-06f  + p * w;
    p = -4.39150654e-06f + p * w;
    p = 0.00021858087f   + p * w;
    p = -0.00125372503f  + p * w;
    p = -0.00417768164f  + p * w;
    p = 0.246640727f     + p * w;
    p = 1.50140941f      + p * w;
  } else {
    w = sqrtf(w) - 3.0f;
    p = -0.000200214257f;
    p = 0.000100950558f  + p * w;
    p = 0.00134934322f   + p * w;
    p = -0.00367342844f  + p * w;
    p = 0.00573950773f   + p * w;
    p = -0.0076224613f   + p * w;
    p = 0.00943887047f   + p * w;
    p = 1.00167406f      + p * w;
    p = 2.83297682f      + p * w;
  }
  return p * x;
}

__device__ static inline float jnormal(uint32_t k0, uint32_t k1, uint32_t idx){
  float u = u01(rng32(k0, k1, idx));
  const float lo = -0.99999994f;
  float v = u * 2.0f + lo;
  v = fmaxf(lo, v);
  return 1.41421356237f * erfinv32(v);
}

__device__ static inline float jsigmoid(float x){
  return 1.0f / (1.0f + expf(-x));
}

__device__ static inline unsigned short f2bf(float f){   // RNE f32->bf16
  uint32_t u = __float_as_uint(f);
  uint32_t r = (u + 0x7fffu + ((u >> 16) & 1u)) >> 16;
  return (unsigned short)r;
}

// ---- LLC-coherent (cross-XCD) memory ops: sc0 sc1 = bypass L1+L2 ----
__device__ static inline u32x4 load_b128_llc(const void* p){
  u32x4 r;
  asm volatile("global_load_dwordx4 %0, %1, off sc0 sc1"
               : "=v"(r) : "v"(p) : "memory");
  return r;
}
__device__ static inline void store_u16_llc(void* p, unsigned v){
  asm volatile("global_store_short %0, %1, off sc0 sc1"
               :: "v"(p), "v"(v) : "memory");
}
__device__ static inline unsigned poll_u32_llc(const void* p){
  unsigned r;
  asm volatile("global_load_dword %0, %1, off sc0 sc1\n\ts_waitcnt vmcnt(0)"
               : "=v"(r) : "v"(p) : "memory");
  return r;
}
__device__ static inline void store_u32_llc(void* p, unsigned v){
  asm volatile("global_store_dword %0, %1, off sc0 sc1"
               :: "v"(p), "v"(v) : "memory");
}

#define WAITV(N) do{ asm volatile("s_waitcnt vmcnt(" #N ")" ::: "memory"); \
                     __builtin_amdgcn_sched_barrier(0); }while(0)

// ---------------- GEMM1: gi_all[r=(t*BB+b)][900] = x@Wih_c^T + bih ----------------
#define FMA4(ACC, S, B) { ACC.x += (S)*(B).x; ACC.y += (S)*(B).y; \
                          ACC.z += (S)*(B).z; ACC.w += (S)*(B).w; }

__global__ __launch_bounds__(256) void k_gemm_gi(
    const float* __restrict__ X, const float* __restrict__ W,
    const float* __restrict__ bias, float* __restrict__ C)
{
  __shared__ float As[16][132];
  __shared__ float Bs[16][68];
  const int tid = threadIdx.x;
  const int rbase = blockIdx.y * 128;
  const int cbase = blockIdx.x * 64;
  const int tx = tid & 15, ty = tid >> 4;
  const int sr = tid >> 2, sq = tid & 3;
  const int wj = cbase + sr;

  float4 acc[8];
#pragma unroll
  for (int i = 0; i < 8; ++i) acc[i] = (float4){0,0,0,0};

  for (int k0 = 0; k0 < 304; k0 += 16){
    const int k = k0 + sq * 4;
#pragma unroll
    for (int i = 0; i < 2; ++i){
      const int row = sr + i * 64;
      const int rg = rbase + row;
      float4 va = {0,0,0,0};
      if (k < DD) va = *(const float4*)(X + ((long)(rg & 127) * TT + (rg >> 7)) * DD + k);
      As[sq*4+0][row] = va.x; As[sq*4+1][row] = va.y;
      As[sq*4+2][row] = va.z; As[sq*4+3][row] = va.w;
    }
    {
      float4 vb = {0,0,0,0};
      if (k < DD && wj < GG) vb = *(const float4*)(W + (long)wj * DD + k);
      Bs[sq*4+0][sr] = vb.x; Bs[sq*4+1][sr] = vb.y;
      Bs[sq*4+2][sr] = vb.z; Bs[sq*4+3][sr] = vb.w;
    }
    __syncthreads();
#pragma unroll
    for (int kk = 0; kk < 16; ++kk){
      const float4 b  = *(const float4*)&Bs[kk][tx * 4];
      const float4 a0 = *(const float4*)&As[kk][ty * 8];
      const float4 a1 = *(const float4*)&As[kk][ty * 8 + 4];
      FMA4(acc[0], a0.x, b); FMA4(acc[1], a0.y, b);
      FMA4(acc[2], a0.z, b); FMA4(acc[3], a0.w, b);
      FMA4(acc[4], a1.x, b); FMA4(acc[5], a1.y, b);
      FMA4(acc[6], a1.z, b); FMA4(acc[7], a1.w, b);
    }
    __syncthreads();
  }
  const int ci = cbase + tx * 4;
  float bv[4];
#pragma unroll
  for (int j = 0; j < 4; ++j) bv[j] = (ci + j < GG) ? bias[ci + j] : 0.0f;
#pragma unroll
  for (int i = 0; i < 8; ++i){
    const int r = rbase + ty * 8 + i;
    float vals[4] = {acc[i].x + bv[0], acc[i].y + bv[1],
                     acc[i].z + bv[2], acc[i].w + bv[3]};
    float* crow = C + (long)r * GG;
    if (ci + 3 < GG){
      float4 st = {vals[0], vals[1], vals[2], vals[3]};
      *(float4*)(crow + ci) = st;
    } else {
#pragma unroll
      for (int j = 0; j < 4; ++j) if (ci + j < GG) crow[ci + j] = vals[j];
    }
  }
}

// ---------------- GEMM-mu: 128x64 tile, 8x4 per thread ----------------
__global__ __launch_bounds__(256) void k_gemm_mu(
    const float* __restrict__ X, const float* __restrict__ HX,
    const float* __restrict__ W, const float* __restrict__ bias,
    float* __restrict__ C)
{
  __shared__ float As[16][132];
  __shared__ float Bs[16][68];
  const int tid = threadIdx.x;
  const int rbase = blockIdx.y * 128;
  const int cbase = blockIdx.x * 64;
  const int tx = tid & 15, ty = tid >> 4;
  const int sr = tid >> 2, sq = tid & 3;
  const int wj = cbase + sr;

  float4 acc[8];
#pragma unroll
  for (int i = 0; i < 8; ++i) acc[i] = (float4){0,0,0,0};

  for (int k0 = 0; k0 < 608; k0 += 16){
    const int k = k0 + sq * 4;
#pragma unroll
    for (int i = 0; i < 2; ++i){
      const int row = sr + i * 64;
      const int rg = rbase + row;
      float4 va = {0,0,0,0};
      if (k < 300)      va = *(const float4*)(X + ((long)(rg & 127) * TT + (rg >> 7)) * DD + k);
      else if (k < 600) va = *(const float4*)(HX + (long)rg * DD + (k - 300));
      va.x = fmaxf(va.x, 0.f); va.y = fmaxf(va.y, 0.f);
      va.z = fmaxf(va.z, 0.f); va.w = fmaxf(va.w, 0.f);
      As[sq*4+0][row] = va.x; As[sq*4+1][row] = va.y;
      As[sq*4+2][row] = va.z; As[sq*4+3][row] = va.w;
    }
    {
      float4 vb = {0,0,0,0};
      if (k < 600 && wj < NMU) vb = *(const float4*)(W + (long)wj * 600 + k);
      Bs[sq*4+0][sr] = vb.x; Bs[sq*4+1][sr] = vb.y;
      Bs[sq*4+2][sr] = vb.z; Bs[sq*4+3][sr] = vb.w;
    }
    __syncthreads();
#pragma unroll
    for (int kk = 0; kk < 16; ++kk){
      const float4 b  = *(const float4*)&Bs[kk][tx * 4];
      const float4 a0 = *(const float4*)&As[kk][ty * 8];
      const float4 a1 = *(const float4*)&As[kk][ty * 8 + 4];
      FMA4(acc[0], a0.x, b); FMA4(acc[1], a0.y, b);
      FMA4(acc[2], a0.z, b); FMA4(acc[3], a0.w, b);
      FMA4(acc[4], a1.x, b); FMA4(acc[5], a1.y, b);
      FMA4(acc[6], a1.z, b); FMA4(acc[7], a1.w, b);
    }
    __syncthreads();
  }
  const int ci = cbase + tx * 4;
  float bv[4];
#pragma unroll
  for (int j = 0; j < 4; ++j) bv[j] = (ci + j < NMU) ? bias[ci + j] : 0.0f;
#pragma unroll
  for (int i = 0; i < 8; ++i){
    const int r = rbase + ty * 8 + i;
    float vals[4] = {acc[i].x + bv[0], acc[i].y + bv[1],
                     acc[i].z + bv[2], acc[i].w + bv[3]};
    float* crow = C + (long)r * NMU;
    if (ci + 3 < NMU){
      float4 st = {vals[0], vals[1], vals[2], vals[3]};
      *(float4*)(crow + ci) = st;
    } else {
#pragma unroll
      for (int j = 0; j < 4; ++j) if (ci + j < NMU) crow[ci + j] = vals[j];
    }
  }
}

// ---------------- lv (pre-softplus), wave-per-row ----------------
__global__ __launch_bounds__(256) void k_lv(
    const float* __restrict__ X, const float* __restrict__ HX,
    const float* __restrict__ Wlv, const float* __restrict__ blv,
    float* __restrict__ LV)
{
  const int r = blockIdx.x * 4 + (threadIdx.x >> 6);   // 16384 rows
  const int lane = threadIdx.x & 63;
  const float* xr = X + ((long)(r & 127) * TT + (r >> 7)) * DD;
  const float* hr = HX + (long)r * DD;
  float a0 = 0.0f, a1 = 0.0f;
  for (int k = lane; k < DD; k += 64){
    float v = fmaxf(xr[k], 0.0f);
    a0 += v * Wlv[k];       a1 += v * Wlv[600 + k];
    float w = fmaxf(hr[k], 0.0f);
    a0 += w * Wlv[300 + k]; a1 += w * Wlv[900 + k];
  }
#pragma unroll
  for (int off = 32; off > 0; off >>= 1){
    a0 += __shfl_down(a0, off);
    a1 += __shfl_down(a1, off);
  }
  if (lane == 0){
    LV[(long)r * 2 + 0] = a0 + blv[0];
    LV[(long)r * 2 + 1] = a1 + blv[1];
  }
}

// ---------------- Whh_c pack: Wp[kq][1024 j][4 c] = Whh_c[j][4kq+c] ----------------
__global__ __launch_bounds__(256) void k_pack_whh(
    const float* __restrict__ W, float* __restrict__ Wp)
{
  const int i = blockIdx.x * 256 + threadIdx.x;   // 75*1024
  const int kq = i >> 10, j = i & 1023;
  float4 v = {0,0,0,0};
  if (kq < 75 && j < GG){
    const float* s = W + (long)j * DD + kq * 4;
    v.x = s[0]; v.y = s[1]; v.z = s[2]; v.w = s[3];
  }
  *(float4*)(Wp + (long)i * 4) = v;
}

// ---------------- stage-1: 256 blocks = 64 batch-pairs x 4 jj-slices ----------------
#define S1PAD 304

__global__ __launch_bounds__(256) void k_stage1(
    const float* __restrict__ Wp, const float* __restrict__ bhh,
    const float* __restrict__ gi_all, float* __restrict__ hx_all,
    float* __restrict__ hex, unsigned int* __restrict__ flagsA)
{
  __shared__ float hs[2][S1PAD];
  __shared__ float ghs[2][240];
  const int tid = threadIdx.x;
  const int bid = blockIdx.x;
  const int bp = bid >> 2, js = bid & 3;
  const int b0 = bp * 2;
  const int jj0 = js * 75;

  const bool mact = tid < 225;                        // matvec thread
  const int mg = tid / 75, mj = tid - mg * 75;
  const int jcol = mg * 300 + jj0 + mj;               // flat j in [0,900)
  const float* wbase = Wp + (long)jcol * 4;

  const bool gact = tid < 150;                        // gate thread
  const int grow = tid / 75, gj = tid - grow * 75;
  const int gjj = jj0 + gj;
  float bhr = 0.f, bhz = 0.f, bhn = 0.f;
  if (gact){ bhr = bhh[gjj]; bhz = bhh[DD + gjj]; bhn = bhh[2*DD + gjj]; }

  for (int i = tid; i < 2 * S1PAD; i += 256) ((float*)hs)[i] = 0.f;
  __syncthreads();

  unsigned int* myflag = flagsA + bid * 16;

  for (int t = 0; t < TT; ++t){
    float gir = 0.f, giz = 0.f, gin = 0.f;
    if (gact){
      const float* gp = gi_all + ((long)t * BB + b0 + grow) * GG;
      gir = gp[gjj]; giz = gp[DD + gjj]; gin = gp[2*DD + gjj];
    }

    if (mact){
      float4 a0 = {0,0,0,0}, a1 = {0,0,0,0};
#pragma unroll 5
      for (int kq = 0; kq < 75; ++kq){
        const float4 w  = *(const float4*)(wbase + (long)kq * 4096);
        const float4 h0 = *(const float4*)&hs[0][kq * 4];
        const float4 h1 = *(const float4*)&hs[1][kq * 4];
        a0.x = fmaf(w.x, h0.x, a0.x); a0.y = fmaf(w.y, h0.y, a0.y);
        a0.z = fmaf(w.z, h0.z, a0.z); a0.w = fmaf(w.w, h0.w, a0.w);
        a1.x = fmaf(w.x, h1.x, a1.x); a1.y = fmaf(w.y, h1.y, a1.y);
        a1.z = fmaf(w.z, h1.z, a1.z); a1.w = fmaf(w.w, h1.w, a1.w);
      }
      ghs[0][mg * 80 + mj] = (a0.x + a0.y) + (a0.z + a0.w);
      ghs[1][mg * 80 + mj] = (a1.x + a1.y) + (a1.z + a1.w);
    }
    __syncthreads();

    const int par = t & 1;
    if (gact){
      const float r = jsigmoid(gir + ghs[grow][gj] + bhr);
      const float z = jsigmoid(giz + ghs[grow][80 + gj] + bhz);
      const float n = tanhf(gin + r * (ghs[grow][160 + gj] + bhn));
      const float hn = (1.0f - z) * n + z * hs[grow][gjj];
      hx_all[((long)t * BB + b0 + grow) * DD + gjj] = hn;
      if (t < TT - 1)
        store_u32_llc(hex + ((long)par * BB + b0 + grow) * S1PAD + gjj,
                      __float_as_uint(hn));
    }

    if (t < TT - 1){
      asm volatile("s_waitcnt vmcnt(0)" ::: "memory");
      __syncthreads();
      if (tid == 0) store_u32_llc(myflag, (unsigned)(t + 1));
      if (tid < 4){
        const unsigned int* fp = flagsA + (bp * 4 + tid) * 16;
        unsigned v = poll_u32_llc(fp);
        while (v < (unsigned)(t + 1)){
          __builtin_amdgcn_s_sleep(1);
          v = poll_u32_llc(fp);
        }
      }
      __syncthreads();
      {
        const float* src = hex + (long)par * BB * S1PAD + (long)b0 * S1PAD;
        const int i0 = tid, i1 = tid + 256, i2 = tid + 512;
        const int r0 = i0 / 300, c0 = i0 - r0 * 300;
        const int r1 = i1 / 300, c1 = i1 - r1 * 300;
        unsigned v0, v1, v2 = 0;
        v0 = poll_u32_llc(src + r0 * S1PAD + c0);
        v1 = poll_u32_llc(src + r1 * S1PAD + c1);
        if (i2 < 600){
          const int r2 = i2 / 300, c2 = i2 - r2 * 300;
          v2 = poll_u32_llc(src + r2 * S1PAD + c2);
          hs[r2][c2] = __uint_as_float(v2);
        }
        hs[r0][c0] = __uint_as_float(v0);
        hs[r1][c1] = __uint_as_float(v1);
      }
      __syncthreads();
    }
  }
}

// ---------------- sampling ----------------
__global__ __launch_bounds__(256) void k_sample(
    const float* __restrict__ X, const float* __restrict__ mu_all,
    const float* __restrict__ lv_all, unsigned short* __restrict__ texts_b,
    float* __restrict__ out,
    const uint32_t k0a, const uint32_t k0b, const uint32_t k1a, const uint32_t k1b,
    const uint32_t k2a, const uint32_t k2b, const uint32_t k3a, const uint32_t k3b)
{
  const int r = blockIdx.x;            // t*128 + b
  const int t = r >> 7, b = r & 127;
  const int tid = threadIdx.x;
  const int h = tid >> 7, lane = tid & 127;
  __shared__ float redf[256];
  __shared__ int   redi[256];
  __shared__ float yw[2], lyw[2], att_s[2];

  const uint32_t rowbase = (uint32_t)((t * 256 + b * 2 + h) * 500);
  float zv[4], ev[4];
  float lmax = -3.0e38f;
#pragma unroll
  for (int s = 0; s < 4; ++s){
    const int a = lane + s * 128;
    float z = -3.0e38f;
    if (a < ASP){
      float g = jgumbel(k0a, k0b, rowbase + (uint32_t)a);
      float m = mu_all[(long)r * NMU + h * ASP + a];
      z = (m + g) / 0.8f;
    }
    zv[s] = z;
    lmax = fmaxf(lmax, z);
  }
  redf[tid] = lmax;
  __syncthreads();
  for (int off = 64; off > 0; off >>= 1){
    if (lane < off) redf[tid] = fmaxf(redf[tid], redf[tid + off]);
    __syncthreads();
  }
  const float mx = redf[h << 7];
  __syncthreads();
  float lsum = 0.0f;
#pragma unroll
  for (int s = 0; s < 4; ++s){
    const int a = lane + s * 128;
    float e = 0.0f;
    if (a < ASP) e = expf(zv[s] - mx);
    ev[s] = e;
    lsum += e;
  }
  redf[tid] = lsum;
  __syncthreads();
  for (int off = 64; off > 0; off >>= 1){
    if (lane < off) redf[tid] += redf[tid + off];
    __syncthreads();
  }
  const float S = redf[h << 7];
  __syncthreads();
  float bestv = -3.0e38f;
  int besti = 0x7fffffff;
#pragma unroll
  for (int s = 0; s < 4; ++s){
    const int a = lane + s * 128;
    if (a < ASP){
      float y = ev[s] / S;
      float ly = logf(y);
      float gc = jgumbel(k1a, k1b, rowbase + (uint32_t)a);
      float val = ly + gc;
      if (val > bestv){ bestv = val; besti = a; }
    }
  }
  redf[tid] = bestv; redi[tid] = besti;
  __syncthreads();
  for (int off = 64; off > 0; off >>= 1){
    if (lane < off){
      float v2 = redf[tid + off]; int i2 = redi[tid + off];
      if (v2 > redf[tid] || (v2 == redf[tid] && i2 < redi[tid])){
        redf[tid] = v2; redi[tid] = i2;
      }
    }
    __syncthreads();
  }
  const int ind = redi[h << 7];
#pragma unroll
  for (int s = 0; s < 4; ++s){
    const int a = lane + s * 128;
    if (a == ind){
      float y = ev[s] / S;
      yw[h] = y;
      lyw[h] = logf(y);
    }
  }
  __syncthreads();
  if (lane == 0){
    const float yv = yw[h];
    const float ly = lyw[h];
    const float yh = (1.0f - yv) + yv;
    const float act = ((float)ind * yh) / 500.0f;
    const float lvr = lv_all[(long)r * 2 + h];
    const float lv = fmaxf(lvr, 0.0f) + log1pf(expf(-fabsf(lvr)));
    const float sd = expf(0.5f * lv);
    const uint32_t ei = (uint32_t)(r * 2 + h);
    const float e1 = jnormal(k2a, k2b, ei);
    const float e2 = jnormal(k3a, k3b, ei);
    const float s1 = act + sd * e1;
    const float s2 = act + sd * e2;
    const float dd = (s2 - act) / sd;
    const float lp = -0.5f * (dd * dd) - logf(sd) - 0.9189385332046727f;
    const float attv = 20.0f * jsigmoid(s1);
    out[OUT_SLOG + (long)b * 256 + t * 2 + h]  = ly;
    out[OUT_ACT  + (long)b * 256 + h * 128 + t] = act;
    out[OUT_LOGP + (long)b * 256 + h * 128 + t] = lp;
    att_s[h] = attv;
  }
  __syncthreads();
  const float* xr = X + ((long)b * TT + t) * DD;
  unsigned short* tr = texts_b + (long)r * 320;
  for (int j = tid; j < 320; j += 256){
    unsigned short o = 0;
    if (j < 300) o = f2bf(xr[j] * att_s[j / 150]);
    tr[j] = o;
  }
}

// ---------------- weight conversion to bf16 ----------------
__global__ __launch_bounds__(256) void k_cvt_whh(
    const float* __restrict__ W, unsigned short* __restrict__ O)
{
  const int i = blockIdx.x * 256 + threadIdx.x;   // 3072*1024
  O[i] = f2bf(W[i]);
}

__global__ __launch_bounds__(256) void k_cvt_wih(
    const float* __restrict__ W, unsigned short* __restrict__ O)
{
  const int i = blockIdx.x * 256 + threadIdx.x;   // 3072*320
  const int rw = i / 320, c = i - rw * 320;
  O[i] = (c < DD) ? f2bf(W[(long)rw * DD + c]) : (unsigned short)0;
}

// ---------------- stage-2 persistent: 128 blocks x 512 thr, K-split wave groups ----
// Block (m,n): batch rows [m*64,+64) x cols [n*16,+16) x 3 gates.
// Wave-group 0: hidden chunks 0-7 + texts K[0,192); group 1: hidden 8-15 + texts
// K[192,320). A-tiles: pitch 128B + XOR swizzle (2-way floor; pitch 144+XOR was
// 4-way — R7 bug). Cross-group partial-acc reduce via LDS. Barrier domain =
// same-m 64 blocks only. LDS: W 129792 + 4x8192 A = 162560.
#define NBLK2 128
#define WPITCH 2704   // 1344*2 + 16
#define ABUF 8192     // 64 rows x 128B

__global__ __launch_bounds__(512) void k_stage2(
    const unsigned short* __restrict__ texts_b,
    const unsigned short* __restrict__ Whb,
    const unsigned short* __restrict__ Wib,
    const float* __restrict__ bih, const float* __restrict__ bhh,
    const int* __restrict__ lengths,
    unsigned short* __restrict__ h2b0, unsigned short* __restrict__ h2b1,
    float* __restrict__ last,
    unsigned int* __restrict__ flags)
{
  __shared__ __align__(16) char lds[162560];   // W:129792 | A: 4 x 8192
  unsigned short* Wl = (unsigned short*)lds;
  char* Al = lds + 129792;

  const int tid = threadIdx.x;
  const int bid = blockIdx.x;
  const int m = bid >> 6, n = bid & 63;
  const int e0 = n * 16, mrow = m * 64;
  const int wave = tid >> 6, wg = wave >> 2, wvr = wave & 3;
  const int lane = tid & 63, lo = lane & 15, hi = lane >> 4;
  const int tidg = tid & 255;

  // ---- stage W (48 x 1344 bf16) once ----
  for (int s = tid; s < 48 * 168; s += 512){
    const int row = s / 168, q = s - row * 168;
    const int g = row >> 4, nn = row & 15;
    const long wrow = (long)g * EE + e0 + nn;
    uint4 v;
    if (q < 128) v = *(const uint4*)(Whb + wrow * EE + q * 8);
    else         v = *(const uint4*)(Wib + wrow * 320 + (q - 128) * 8);
    *(uint4*)((char*)Wl + (long)row * WPITCH + q * 16) = v;
  }

  const int e = e0 + lo;
  const float bR = bih[e] + bhh[e];
  const float bZ = bih[EE + e] + bhh[EE + e];
  const float biN = bih[2*EE + e];
  const float bhN = bhh[2*EE + e];
  int li[4]; float hp[4];
#pragma unroll
  for (int j = 0; j < 4; ++j){
    const int brow = wvr * 16 + hi * 4 + j;
    int l = lengths[mrow + brow] - 1; if (l < 0) l += TT;
    li[j] = l; hp[j] = 0.0f;
  }
  __syncthreads();

  using frag = __attribute__((ext_vector_type(8))) short;
  using f32x4 = __attribute__((ext_vector_type(4))) float;

  char* Ag = Al + wg * (2 * ABUF);
  const int arow = wvr * 16 + lo;
  int boff[3];
#pragma unroll
  for (int g = 0; g < 3; ++g) boff[g] = (g * 16 + lo) * WPITCH + hi * 16;

  u32x4 rg[4][2];
  unsigned int* flagp = flags + bid * 16;

  for (int t = 0; t < TT; ++t){
    const unsigned short* hb = (t & 1) ? h2b1 : h2b0;
    unsigned short* ho = (t & 1) ? h2b0 : h2b1;
    const unsigned short* txp = texts_b + (long)t * BB * 320;

    f32x4 aR = {0,0,0,0}, aZ = {0,0,0,0}, aNH = {0,0,0,0}, aNI = {0,0,0,0};

    auto issueT = [&](int c, u32x4* r){
#pragma unroll
      for (int i = 0; i < 2; ++i){
        const int c0 = tidg + i * 256, row = c0 >> 3, kq = c0 & 7;
        r[i] = load_b128_llc(txp + (long)(mrow + row) * 320 + (c - 16) * 64 + kq * 8);
      }
    };
    auto issueH = [&](int ch, u32x4* r){
#pragma unroll
      for (int i = 0; i < 2; ++i){
        const int c0 = tidg + i * 256, row = c0 >> 3, kq = c0 & 7;
        r[i] = load_b128_llc(hb + (long)(mrow + row) * EE + ch * 64 + kq * 8);
      }
    };
    auto writeA = [&](int buf, u32x4* r){
#pragma unroll
      for (int i = 0; i < 2; ++i){
        const int c0 = tidg + i * 256, row = c0 >> 3, kq = c0 & 7;
        *(u32x4*)(Ag + buf * ABUF + row * 128 + ((kq ^ (row & 7)) << 4)) = r[i];
      }
    };
    auto compute = [&](int c, int buf, bool hid){
#pragma unroll
      for (int kf = 0; kf < 2; ++kf){
        frag a = *(const frag*)(Ag + buf * ABUF + arow * 128 +
                                (((kf * 4 + hi) ^ (arow & 7)) << 4));
        frag b0 = *(const frag*)((char*)Wl + boff[0] + c * 128 + kf * 64);
        frag b1 = *(const frag*)((char*)Wl + boff[1] + c * 128 + kf * 64);
        frag b2 = *(const frag*)((char*)Wl + boff[2] + c * 128 + kf * 64);
        aR = __builtin_amdgcn_mfma_f32_16x16x32_bf16(a, b0, aR, 0, 0, 0);
        aZ = __builtin_amdgcn_mfma_f32_16x16x32_bf16(a, b1, aZ, 0, 0, 0);
        if (hid) aNH = __builtin_amdgcn_mfma_f32_16x16x32_bf16(a, b2, aNH, 0, 0, 0);
        else     aNI = __builtin_amdgcn_mfma_f32_16x16x32_bf16(a, b2, aNI, 0, 0, 0);
      }
    };

    // ---- texts phase: group0 chunks 16-18, group1 chunks 19-20 (3 aligned iters) ----
    if (wg == 0){ issueT(16, rg[0]); issueT(17, rg[1]); issueT(18, rg[2]); }
    else        { issueT(19, rg[0]); issueT(20, rg[1]); }
    __syncthreads();
    if (wg == 0){ WAITV(4); } else { WAITV(2); }
    writeA(0, rg[0]);
    __syncthreads();
    compute(wg ? 19 : 16, 0, false);
    __syncthreads();
    if (wg == 0){ WAITV(2); } else { WAITV(0); }
    writeA(1, rg[1]);
    __syncthreads();
    compute(wg ? 20 : 17, 1, false);
    __syncthreads();
    if (wg == 0){ WAITV(0); writeA(0, rg[2]); }
    __syncthreads();
    if (wg == 0) compute(18, 0, false);

    // ---- barrier (same-m domain) + hidden phase (8 chunks per group) ----
    if (t > 0){
      if (tid < 64){
        const unsigned int* fp = flags + ((m << 6) + tid) * 16;
        unsigned v = poll_u32_llc(fp);
        while (v < (unsigned)t){
          __builtin_amdgcn_s_sleep(2);
          v = poll_u32_llc(fp);
        }
      }
      __syncthreads();
      const int chb = wg * 8;
      issueH(chb + 0, rg[0]); issueH(chb + 1, rg[1]);
      issueH(chb + 2, rg[2]); issueH(chb + 3, rg[3]);
#define CHUNKH(i, WN) do{ \
      __syncthreads(); \
      WAITV(WN); \
      writeA((i) & 1, rg[(i) & 3]); \
      if ((i) + 4 < 8) issueH(chb + (i) + 4, rg[(i) & 3]); \
      __syncthreads(); \
      compute(chb + (i), (i) & 1, true); \
    }while(0)
      CHUNKH(0, 6); CHUNKH(1, 6); CHUNKH(2, 6); CHUNKH(3, 6);
      CHUNKH(4, 6); CHUNKH(5, 4); CHUNKH(6, 2); CHUNKH(7, 0);
#undef CHUNKH
    }

    // ---- cross-group reduce (A region reused; 80B stride = 2-way banks) ----
    __syncthreads();
    if (wg == 1){
      char* dst = Al + tidg * 80;
      *(f32x4*)(dst)      = aR;
      *(f32x4*)(dst + 16) = aZ;
      *(f32x4*)(dst + 32) = aNH;
      *(f32x4*)(dst + 48) = aNI;
    }
    __syncthreads();
    if (wg == 0){
      const char* src = Al + tidg * 80;
      const f32x4 pR  = *(const f32x4*)(src);
      const f32x4 pZ  = *(const f32x4*)(src + 16);
      const f32x4 pNH = *(const f32x4*)(src + 32);
      const f32x4 pNI = *(const f32x4*)(src + 48);
#pragma unroll
      for (int j = 0; j < 4; ++j){
        aR[j] += pR[j]; aZ[j] += pZ[j]; aNH[j] += pNH[j]; aNI[j] += pNI[j];
      }
      // ---- GRU gates epilogue (group 0 only) ----
#pragma unroll
      for (int j = 0; j < 4; ++j){
        const int brow = wvr * 16 + hi * 4 + j;
        const float r = jsigmoid(aR[j] + bR);
        const float z = jsigmoid(aZ[j] + bZ);
        const float nn2 = tanhf(aNI[j] + biN + r * (aNH[j] + bhN));
        const float hn = (1.0f - z) * nn2 + z * hp[j];
        hp[j] = hn;
        store_u16_llc(ho + (long)(mrow + brow) * EE + e, (unsigned)f2bf(hn));
        if (t == li[j]) last[(long)(mrow + brow) * EE + e] = hn;
      }
    }

    if (t < TT - 1){
      asm volatile("s_waitcnt vmcnt(0)" ::: "memory");
      __syncthreads();
      if (tid == 0) store_u32_llc(flagp, (unsigned)(t + 1));
    }
  }
}

// ---------------- BatchNorm ----------------
__global__ __launch_bounds__(256) void k_bn_stats(
    const float* __restrict__ last, float* __restrict__ mv)
{
  const int e = blockIdx.x * 256 + threadIdx.x;
  if (e >= EE) return;
  float s = 0.0f;
  for (int b = 0; b < BB; ++b) s += last[(long)b * EE + e];
  const float mean = s / 128.0f;
  float v = 0.0f;
  for (int b = 0; b < BB; ++b){ float d = last[(long)b * EE + e] - mean; v += d * d; }
  mv[e] = mean;
  mv[EE + e] = v / 128.0f;
}

__global__ __launch_bounds__(256) void k_bn_apply(
    const float* __restrict__ last, const float* __restrict__ mv,
    const float* __restrict__ gamma, const float* __restrict__ beta,
    float* __restrict__ out)
{
  const int gid = blockIdx.x * 256 + threadIdx.x;
  const int e = gid & 1023;
  const float xm = last[gid] - mv[e];
  out[gid] = gamma[e] * xm / sqrtf(mv[EE + e] + 1e-5f) + beta[e];
}

// ---------------- launcher ----------------
extern "C" void kernel_launch(void* const* d_in, const int* in_sizes, int n_in,
                              void* d_out, int out_size, void* d_ws, size_t ws_size,
                              hipStream_t stream)
{
  (void)in_sizes; (void)n_in; (void)out_size;
  const float* x     = (const float*)d_in[0];
  const int*   lens  = (const int*)d_in[1];
  const float* Wih_c = (const float*)d_in[3];
  const float* Whh_c = (const float*)d_in[4];
  const float* bih_c = (const float*)d_in[5];
  const float* bhh_c = (const float*)d_in[6];
  const float* Wmu   = (const float*)d_in[7];
  const float* bmu   = (const float*)d_in[8];
  const float* Wlv   = (const float*)d_in[9];
  const float* blv   = (const float*)d_in[10];
  const float* Wih_r = (const float*)d_in[11];
  const float* Whh_r = (const float*)d_in[12];
  const float* bih_r = (const float*)d_in[13];
  const float* bhh_r = (const float*)d_in[14];
  const float* gam   = (const float*)d_in[15];
  const float* bet   = (const float*)d_in[16];
  float* out = (float*)d_out;

  uint32_t nk[4][2];
  for (uint32_t i = 0; i < 4; ++i) tf2x32(0u, 42u, 0u, i, &nk[i][0], &nk[i][1]);

  float* ws = (float*)d_ws;
  size_t off = 0;
  float* U       = ws + off; off += 16384000;  // gi_all then mu_all (aliased)
  float* hx_all  = ws + off; off += 4915200;
  float* lv_all  = ws + off; off += 32768;
  float* Wp      = ws + off; off += 307200;    // packed Whh_c
  float* lastb   = ws + off; off += 131072;
  float* mv      = ws + off; off += 2048;
  float* hex     = ws + off; off += 77824;     // [2][128][304] f32 stage-1 exchange
  unsigned int* flags  = (unsigned int*)(ws + off); off += 2048;  // stage-2: 128*16
  unsigned int* flagsA = (unsigned int*)(ws + off); off += 4096;  // stage-1: 256*16
  unsigned short* texts_b = (unsigned short*)(ws + off); off += 2621440; // 16384x320 bf16
  unsigned short* h2b0    = (unsigned short*)(ws + off); off += 65536;   // 128x1024 bf16
  unsigned short* h2b1    = (unsigned short*)(ws + off); off += 65536;
  unsigned short* Whb     = (unsigned short*)(ws + off); off += 1572864; // 3072x1024 bf16
  unsigned short* Wib     = (unsigned short*)(ws + off); off += 491520;  // 3072x320 bf16
  if (ws_size < off * sizeof(float)) return;

  hipMemsetAsync(flags, 0, 2048 * sizeof(unsigned int), stream);
  hipMemsetAsync(flagsA, 0, 4096 * sizeof(unsigned int), stream);

  // weight prep
  k_cvt_whh<<<dim3(12288), 256, 0, stream>>>(Whh_r, Whb);
  k_cvt_wih<<<dim3(3840), 256, 0, stream>>>(Wih_r, Wib);
  k_pack_whh<<<dim3(300), 256, 0, stream>>>(Whh_c, Wp);

  // stage-1 input projection + persistent jj-split recurrence
  k_gemm_gi<<<dim3(15, 128), 256, 0, stream>>>(x, Wih_c, bih_c, U);
  k_stage1<<<dim3(256), 256, 0, stream>>>(Wp, bhh_c, U, hx_all, hex, flagsA);

  // batched mu / lv / sampling
  k_gemm_mu<<<dim3(16, 128), 256, 0, stream>>>(x, hx_all, Wmu, bmu, U);
  k_lv<<<dim3(4096), 256, 0, stream>>>(x, hx_all, Wlv, blv, lv_all);
  k_sample<<<dim3(16384), 256, 0, stream>>>(x, U, lv_all, texts_b, out,
      nk[0][0], nk[0][1], nk[1][0], nk[1][1],
      nk[2][0], nk[2][1], nk[3][0], nk[3][1]);

  // stage-2 persistent recurrence (K-split wave groups + same-m barrier)
  k_stage2<<<dim3(NBLK2), 512, 0, stream>>>(texts_b, Whb, Wib, bih_r, bhh_r, lens,
                                            h2b0, h2b1, lastb, flags);

  // batchnorm
  k_bn_stats<<<dim3(4), 256, 0, stream>>>(lastb, mv);
  k_bn_apply<<<dim3(512), 256, 0, stream>>>(lastb, mv, gam, bet, out);
}

// Round 10
// 2118.898 us; speedup vs baseline: 3.8648x; 1.0325x over previous
//
#include <hip/hip_runtime.h>
#include <stdint.h>

#define TT 128
#define BB 128
#define DD 300
#define EE 1024
#define GG 900
#define NMU 1000
#define ASP 500

#define OUT_SLOG 131072
#define OUT_ACT  163840
#define OUT_LOGP 196608

typedef unsigned int u32x4 __attribute__((ext_vector_type(4)));

// ---------------- threefry2x32 (JAX, 20 rounds) ----------------
__host__ __device__ static inline uint32_t rotl32(uint32_t x, int r){
  return (x << r) | (x >> (32 - r));
}

__host__ __device__ static inline void tf2x32(uint32_t k0, uint32_t k1,
                                              uint32_t x0, uint32_t x1,
                                              uint32_t* o0, uint32_t* o1){
  uint32_t ks2 = k0 ^ k1 ^ 0x1BD11BDAu;
#define TFR(r) { x0 += x1; x1 = rotl32(x1, r); x1 ^= x0; }
  x0 += k0; x1 += k1;
  TFR(13) TFR(15) TFR(26) TFR(6)
  x0 += k1; x1 += ks2 + 1u;
  TFR(17) TFR(29) TFR(16) TFR(24)
  x0 += ks2; x1 += k0 + 2u;
  TFR(13) TFR(15) TFR(26) TFR(6)
  x0 += k0; x1 += k1 + 3u;
  TFR(17) TFR(29) TFR(16) TFR(24)
  x0 += k1; x1 += ks2 + 4u;
  TFR(13) TFR(15) TFR(26) TFR(6)
  x0 += ks2; x1 += k0 + 5u;
#undef TFR
  *o0 = x0; *o1 = x1;
}

__device__ static inline uint32_t rng32(uint32_t k0, uint32_t k1, uint32_t idx){
  uint32_t a, b;
  tf2x32(k0, k1, 0u, idx, &a, &b);
  return a ^ b;
}

__device__ static inline float u01(uint32_t bits){
  return __uint_as_float((bits >> 9) | 0x3f800000u) - 1.0f;
}

__device__ static inline float jgumbel(uint32_t k0, uint32_t k1, uint32_t idx){
  float u = u01(rng32(k0, k1, idx));
  float l1 = logf(u + 1e-20f);
  return -logf(-l1 + 1e-20f);
}

__device__ static inline float erfinv32(float x){   // XLA ErfInv32 (Giles)
  float w = -log1pf(-x * x);
  float p;
  if (w < 5.0f){
    w = w - 2.5f;
    p = 2.81022636e-08f;
    p = 3.43273939e-07f  + p * w;
    p = -3.5233877e-06f  + p * w;
    p = -4.39150654e-06f + p * w;
    p = 0.00021858087f   + p * w;
    p = -0.00125372503f  + p * w;
    p = -0.00417768164f  + p * w;
    p = 0.246640727f     + p * w;
    p = 1.50140941f      + p * w;
  } else {
    w = sqrtf(w) - 3.0f;
    p = -0.000200214257f;
    p = 0.000100950558f  + p * w;
    p = 0.00134934322f   + p * w;
    p = -0.00367342844f  + p * w;
    p = 0.00573950773f   + p * w;
    p = -0.0076224613f   + p * w;
    p = 0.00943887047f   + p * w;
    p = 1.00167406f      + p * w;
    p = 2.83297682f      + p * w;
  }
  return p * x;
}

__device__ static inline float jnormal(uint32_t k0, uint32_t k1, uint32_t idx){
  float u = u01(rng32(k0, k1, idx));
  const float lo = -0.99999994f;
  float v = u * 2.0f + lo;
  v = fmaxf(lo, v);
  return 1.41421356237f * erfinv32(v);
}

__device__ static inline float jsigmoid(float x){
  return 1.0f / (1.0f + expf(-x));
}

__device__ static inline unsigned short f2bf(float f){   // RNE f32->bf16
  uint32_t u = __float_as_uint(f);
  uint32_t r = (u + 0x7fffu + ((u >> 16) & 1u)) >> 16;
  return (unsigned short)r;
}

// ---- LLC-coherent (cross-XCD) memory ops: sc0 sc1 = bypass L1+L2 ----
__device__ static inline u32x4 load_b128_llc(const void* p){
  u32x4 r;
  asm volatile("global_load_dwordx4 %0, %1, off sc0 sc1"
               : "=v"(r) : "v"(p) : "memory");
  return r;
}
__device__ static inline void store_u16_llc(void* p, unsigned v){
  asm volatile("global_store_short %0, %1, off sc0 sc1"
               :: "v"(p), "v"(v) : "memory");
}
__device__ static inline unsigned poll_u32_llc(const void* p){
  unsigned r;
  asm volatile("global_load_dword %0, %1, off sc0 sc1\n\ts_waitcnt vmcnt(0)"
               : "=v"(r) : "v"(p) : "memory");
  return r;
}
__device__ static inline void store_u32_llc(void* p, unsigned v){
  asm volatile("global_store_dword %0, %1, off sc0 sc1"
               :: "v"(p), "v"(v) : "memory");
}

#define WAITV(N) do{ asm volatile("s_waitcnt vmcnt(" #N ")" ::: "memory"); \
                     __builtin_amdgcn_sched_barrier(0); }while(0)

// ---------------- GEMM1: gi_all[r=(t*BB+b)][900] = x@Wih_c^T + bih ----------------
#define FMA4(ACC, S, B) { ACC.x += (S)*(B).x; ACC.y += (S)*(B).y; \
                          ACC.z += (S)*(B).z; ACC.w += (S)*(B).w; }

__global__ __launch_bounds__(256) void k_gemm_gi(
    const float* __restrict__ X, const float* __restrict__ W,
    const float* __restrict__ bias, float* __restrict__ C)
{
  __shared__ float As[16][132];
  __shared__ float Bs[16][68];
  const int tid = threadIdx.x;
  const int rbase = blockIdx.y * 128;
  const int cbase = blockIdx.x * 64;
  const int tx = tid & 15, ty = tid >> 4;
  const int sr = tid >> 2, sq = tid & 3;
  const int wj = cbase + sr;

  float4 acc[8];
#pragma unroll
  for (int i = 0; i < 8; ++i) acc[i] = (float4){0,0,0,0};

  for (int k0 = 0; k0 < 304; k0 += 16){
    const int k = k0 + sq * 4;
#pragma unroll
    for (int i = 0; i < 2; ++i){
      const int row = sr + i * 64;
      const int rg = rbase + row;
      float4 va = {0,0,0,0};
      if (k < DD) va = *(const float4*)(X + ((long)(rg & 127) * TT + (rg >> 7)) * DD + k);
      As[sq*4+0][row] = va.x; As[sq*4+1][row] = va.y;
      As[sq*4+2][row] = va.z; As[sq*4+3][row] = va.w;
    }
    {
      float4 vb = {0,0,0,0};
      if (k < DD && wj < GG) vb = *(const float4*)(W + (long)wj * DD + k);
      Bs[sq*4+0][sr] = vb.x; Bs[sq*4+1][sr] = vb.y;
      Bs[sq*4+2][sr] = vb.z; Bs[sq*4+3][sr] = vb.w;
    }
    __syncthreads();
#pragma unroll
    for (int kk = 0; kk < 16; ++kk){
      const float4 b  = *(const float4*)&Bs[kk][tx * 4];
      const float4 a0 = *(const float4*)&As[kk][ty * 8];
      const float4 a1 = *(const float4*)&As[kk][ty * 8 + 4];
      FMA4(acc[0], a0.x, b); FMA4(acc[1], a0.y, b);
      FMA4(acc[2], a0.z, b); FMA4(acc[3], a0.w, b);
      FMA4(acc[4], a1.x, b); FMA4(acc[5], a1.y, b);
      FMA4(acc[6], a1.z, b); FMA4(acc[7], a1.w, b);
    }
    __syncthreads();
  }
  const int ci = cbase + tx * 4;
  float bv[4];
#pragma unroll
  for (int j = 0; j < 4; ++j) bv[j] = (ci + j < GG) ? bias[ci + j] : 0.0f;
#pragma unroll
  for (int i = 0; i < 8; ++i){
    const int r = rbase + ty * 8 + i;
    float vals[4] = {acc[i].x + bv[0], acc[i].y + bv[1],
                     acc[i].z + bv[2], acc[i].w + bv[3]};
    float* crow = C + (long)r * GG;
    if (ci + 3 < GG){
      float4 st = {vals[0], vals[1], vals[2], vals[3]};
      *(float4*)(crow + ci) = st;
    } else {
#pragma unroll
      for (int j = 0; j < 4; ++j) if (ci + j < GG) crow[ci + j] = vals[j];
    }
  }
}

// ---------------- GEMM-mu: 128x64 tile, 8x4 per thread ----------------
__global__ __launch_bounds__(256) void k_gemm_mu(
    const float* __restrict__ X, const float* __restrict__ HX,
    const float* __restrict__ W, const float* __restrict__ bias,
    float* __restrict__ C)
{
  __shared__ float As[16][132];
  __shared__ float Bs[16][68];
  const int tid = threadIdx.x;
  const int rbase = blockIdx.y * 128;
  const int cbase = blockIdx.x * 64;
  const int tx = tid & 15, ty = tid >> 4;
  const int sr = tid >> 2, sq = tid & 3;
  const int wj = cbase + sr;

  float4 acc[8];
#pragma unroll
  for (int i = 0; i < 8; ++i) acc[i] = (float4){0,0,0,0};

  for (int k0 = 0; k0 < 608; k0 += 16){
    const int k = k0 + sq * 4;
#pragma unroll
    for (int i = 0; i < 2; ++i){
      const int row = sr + i * 64;
      const int rg = rbase + row;
      float4 va = {0,0,0,0};
      if (k < 300)      va = *(const float4*)(X + ((long)(rg & 127) * TT + (rg >> 7)) * DD + k);
      else if (k < 600) va = *(const float4*)(HX + (long)rg * DD + (k - 300));
      va.x = fmaxf(va.x, 0.f); va.y = fmaxf(va.y, 0.f);
      va.z = fmaxf(va.z, 0.f); va.w = fmaxf(va.w, 0.f);
      As[sq*4+0][row] = va.x; As[sq*4+1][row] = va.y;
      As[sq*4+2][row] = va.z; As[sq*4+3][row] = va.w;
    }
    {
      float4 vb = {0,0,0,0};
      if (k < 600 && wj < NMU) vb = *(const float4*)(W + (long)wj * 600 + k);
      Bs[sq*4+0][sr] = vb.x; Bs[sq*4+1][sr] = vb.y;
      Bs[sq*4+2][sr] = vb.z; Bs[sq*4+3][sr] = vb.w;
    }
    __syncthreads();
#pragma unroll
    for (int kk = 0; kk < 16; ++kk){
      const float4 b  = *(const float4*)&Bs[kk][tx * 4];
      const float4 a0 = *(const float4*)&As[kk][ty * 8];
      const float4 a1 = *(const float4*)&As[kk][ty * 8 + 4];
      FMA4(acc[0], a0.x, b); FMA4(acc[1], a0.y, b);
      FMA4(acc[2], a0.z, b); FMA4(acc[3], a0.w, b);
      FMA4(acc[4], a1.x, b); FMA4(acc[5], a1.y, b);
      FMA4(acc[6], a1.z, b); FMA4(acc[7], a1.w, b);
    }
    __syncthreads();
  }
  const int ci = cbase + tx * 4;
  float bv[4];
#pragma unroll
  for (int j = 0; j < 4; ++j) bv[j] = (ci + j < NMU) ? bias[ci + j] : 0.0f;
#pragma unroll
  for (int i = 0; i < 8; ++i){
    const int r = rbase + ty * 8 + i;
    float vals[4] = {acc[i].x + bv[0], acc[i].y + bv[1],
                     acc[i].z + bv[2], acc[i].w + bv[3]};
    float* crow = C + (long)r * NMU;
    if (ci + 3 < NMU){
      float4 st = {vals[0], vals[1], vals[2], vals[3]};
      *(float4*)(crow + ci) = st;
    } else {
#pragma unroll
      for (int j = 0; j < 4; ++j) if (ci + j < NMU) crow[ci + j] = vals[j];
    }
  }
}

// ---------------- lv (pre-softplus), wave-per-row ----------------
__global__ __launch_bounds__(256) void k_lv(
    const float* __restrict__ X, const float* __restrict__ HX,
    const float* __restrict__ Wlv, const float* __restrict__ blv,
    float* __restrict__ LV)
{
  const int r = blockIdx.x * 4 + (threadIdx.x >> 6);   // 16384 rows
  const int lane = threadIdx.x & 63;
  const float* xr = X + ((long)(r & 127) * TT + (r >> 7)) * DD;
  const float* hr = HX + (long)r * DD;
  float a0 = 0.0f, a1 = 0.0f;
  for (int k = lane; k < DD; k += 64){
    float v = fmaxf(xr[k], 0.0f);
    a0 += v * Wlv[k];       a1 += v * Wlv[600 + k];
    float w = fmaxf(hr[k], 0.0f);
    a0 += w * Wlv[300 + k]; a1 += w * Wlv[900 + k];
  }
#pragma unroll
  for (int off = 32; off > 0; off >>= 1){
    a0 += __shfl_down(a0, off);
    a1 += __shfl_down(a1, off);
  }
  if (lane == 0){
    LV[(long)r * 2 + 0] = a0 + blv[0];
    LV[(long)r * 2 + 1] = a1 + blv[1];
  }
}

// ---------------- Whh_c pack: Wp[kq][1024 j][4 c] = Whh_c[j][4kq+c] ----------------
__global__ __launch_bounds__(256) void k_pack_whh(
    const float* __restrict__ W, float* __restrict__ Wp)
{
  const int i = blockIdx.x * 256 + threadIdx.x;   // 75*1024
  const int kq = i >> 10, j = i & 1023;
  float4 v = {0,0,0,0};
  if (kq < 75 && j < GG){
    const float* s = W + (long)j * DD + kq * 4;
    v.x = s[0]; v.y = s[1]; v.z = s[2]; v.w = s[3];
  }
  *(float4*)(Wp + (long)i * 4) = v;
}

// ---------------- stage-1: 256 blocks = 64 batch-pairs x 4 jj-slices ----------------
#define S1PAD 304

__global__ __launch_bounds__(256) void k_stage1(
    const float* __restrict__ Wp, const float* __restrict__ bhh,
    const float* __restrict__ gi_all, float* __restrict__ hx_all,
    float* __restrict__ hex, unsigned int* __restrict__ flagsA)
{
  __shared__ __align__(16) float hs[2][S1PAD];
  __shared__ float ghs[2][240];
  const int tid = threadIdx.x;
  const int bid = blockIdx.x;
  const int bp = bid >> 2, js = bid & 3;
  const int b0 = bp * 2;
  const int jj0 = js * 75;

  const bool mact = tid < 225;                        // matvec thread
  const int mg = tid / 75, mj = tid - mg * 75;
  const int jcol = mg * 300 + jj0 + mj;               // flat j in [0,900)
  const float* wbase = Wp + (long)jcol * 4;

  const bool gact = tid < 150;                        // gate thread
  const int grow = tid / 75, gj = tid - grow * 75;
  const int gjj = jj0 + gj;
  float bhr = 0.f, bhz = 0.f, bhn = 0.f;
  if (gact){ bhr = bhh[gjj]; bhz = bhh[DD + gjj]; bhn = bhh[2*DD + gjj]; }

  // refresh indices: 152 threads, one float4 each (2 rows x 76)
  const int rr_ = tid / 76, rc_ = tid - rr_ * 76;

  for (int i = tid; i < 2 * S1PAD; i += 256) ((float*)hs)[i] = 0.f;
  __syncthreads();

  unsigned int* myflag = flagsA + bid * 16;

  for (int t = 0; t < TT; ++t){
    float gir = 0.f, giz = 0.f, gin = 0.f;
    if (gact){
      const float* gp = gi_all + ((long)t * BB + b0 + grow) * GG;
      gir = gp[gjj]; giz = gp[DD + gjj]; gin = gp[2*DD + gjj];
    }

    if (mact){
      float4 a0 = {0,0,0,0}, a1 = {0,0,0,0};
#pragma unroll 5
      for (int kq = 0; kq < 75; ++kq){
        const float4 w  = *(const float4*)(wbase + (long)kq * 4096);
        const float4 h0 = *(const float4*)&hs[0][kq * 4];
        const float4 h1 = *(const float4*)&hs[1][kq * 4];
        a0.x = fmaf(w.x, h0.x, a0.x); a0.y = fmaf(w.y, h0.y, a0.y);
        a0.z = fmaf(w.z, h0.z, a0.z); a0.w = fmaf(w.w, h0.w, a0.w);
        a1.x = fmaf(w.x, h1.x, a1.x); a1.y = fmaf(w.y, h1.y, a1.y);
        a1.z = fmaf(w.z, h1.z, a1.z); a1.w = fmaf(w.w, h1.w, a1.w);
      }
      ghs[0][mg * 80 + mj] = (a0.x + a0.y) + (a0.z + a0.w);
      ghs[1][mg * 80 + mj] = (a1.x + a1.y) + (a1.z + a1.w);
    }
    __syncthreads();

    const int par = t & 1;
    if (gact){
      const float r = jsigmoid(gir + ghs[grow][gj] + bhr);
      const float z = jsigmoid(giz + ghs[grow][80 + gj] + bhz);
      const float n = tanhf(gin + r * (ghs[grow][160 + gj] + bhn));
      const float hn = (1.0f - z) * n + z * hs[grow][gjj];
      hx_all[((long)t * BB + b0 + grow) * DD + gjj] = hn;
      if (t < TT - 1)
        store_u32_llc(hex + ((long)par * BB + b0 + grow) * S1PAD + gjj,
                      __float_as_uint(hn));
    }

    if (t < TT - 1){
      asm volatile("s_waitcnt vmcnt(0)" ::: "memory");
      __syncthreads();
      if (tid == 0) store_u32_llc(myflag, (unsigned)(t + 1));
      if (tid < 4){
        const unsigned int* fp = flagsA + (bp * 4 + tid) * 16;
        unsigned v = poll_u32_llc(fp);
        while (v < (unsigned)(t + 1)){
          __builtin_amdgcn_s_sleep(1);
          v = poll_u32_llc(fp);
        }
      }
      __syncthreads();
      // vectorized refresh: 152 float4 LLC loads, ONE latency round-trip
      u32x4 rv = (u32x4){0,0,0,0};
      if (tid < 152)
        rv = load_b128_llc(hex + (long)par * BB * S1PAD
                               + (long)(b0 + rr_) * S1PAD + rc_ * 4);
      WAITV(0);
      if (tid < 152) *(u32x4*)&hs[rr_][rc_ * 4] = rv;
      __syncthreads();
    }
  }
}

// ---------------- sampling ----------------
__global__ __launch_bounds__(256) void k_sample(
    const float* __restrict__ X, const float* __restrict__ mu_all,
    const float* __restrict__ lv_all, unsigned short* __restrict__ texts_b,
    float* __restrict__ out,
    const uint32_t k0a, const uint32_t k0b, const uint32_t k1a, const uint32_t k1b,
    const uint32_t k2a, const uint32_t k2b, const uint32_t k3a, const uint32_t k3b)
{
  const int r = blockIdx.x;            // t*128 + b
  const int t = r >> 7, b = r & 127;
  const int tid = threadIdx.x;
  const int h = tid >> 7, lane = tid & 127;
  __shared__ float redf[256];
  __shared__ int   redi[256];
  __shared__ float yw[2], lyw[2], att_s[2];

  const uint32_t rowbase = (uint32_t)((t * 256 + b * 2 + h) * 500);
  float zv[4], ev[4];
  float lmax = -3.0e38f;
#pragma unroll
  for (int s = 0; s < 4; ++s){
    const int a = lane + s * 128;
    float z = -3.0e38f;
    if (a < ASP){
      float g = jgumbel(k0a, k0b, rowbase + (uint32_t)a);
      float m = mu_all[(long)r * NMU + h * ASP + a];
      z = (m + g) / 0.8f;
    }
    zv[s] = z;
    lmax = fmaxf(lmax, z);
  }
  redf[tid] = lmax;
  __syncthreads();
  for (int off = 64; off > 0; off >>= 1){
    if (lane < off) redf[tid] = fmaxf(redf[tid], redf[tid + off]);
    __syncthreads();
  }
  const float mx = redf[h << 7];
  __syncthreads();
  float lsum = 0.0f;
#pragma unroll
  for (int s = 0; s < 4; ++s){
    const int a = lane + s * 128;
    float e = 0.0f;
    if (a < ASP) e = expf(zv[s] - mx);
    ev[s] = e;
    lsum += e;
  }
  redf[tid] = lsum;
  __syncthreads();
  for (int off = 64; off > 0; off >>= 1){
    if (lane < off) redf[tid] += redf[tid + off];
    __syncthreads();
  }
  const float S = redf[h << 7];
  __syncthreads();
  float bestv = -3.0e38f;
  int besti = 0x7fffffff;
#pragma unroll
  for (int s = 0; s < 4; ++s){
    const int a = lane + s * 128;
    if (a < ASP){
      float y = ev[s] / S;
      float ly = logf(y);
      float gc = jgumbel(k1a, k1b, rowbase + (uint32_t)a);
      float val = ly + gc;
      if (val > bestv){ bestv = val; besti = a; }
    }
  }
  redf[tid] = bestv; redi[tid] = besti;
  __syncthreads();
  for (int off = 64; off > 0; off >>= 1){
    if (lane < off){
      float v2 = redf[tid + off]; int i2 = redi[tid + off];
      if (v2 > redf[tid] || (v2 == redf[tid] && i2 < redi[tid])){
        redf[tid] = v2; redi[tid] = i2;
      }
    }
    __syncthreads();
  }
  const int ind = redi[h << 7];
#pragma unroll
  for (int s = 0; s < 4; ++s){
    const int a = lane + s * 128;
    if (a == ind){
      float y = ev[s] / S;
      yw[h] = y;
      lyw[h] = logf(y);
    }
  }
  __syncthreads();
  if (lane == 0){
    const float yv = yw[h];
    const float ly = lyw[h];
    const float yh = (1.0f - yv) + yv;
    const float act = ((float)ind * yh) / 500.0f;
    const float lvr = lv_all[(long)r * 2 + h];
    const float lv = fmaxf(lvr, 0.0f) + log1pf(expf(-fabsf(lvr)));
    const float sd = expf(0.5f * lv);
    const uint32_t ei = (uint32_t)(r * 2 + h);
    const float e1 = jnormal(k2a, k2b, ei);
    const float e2 = jnormal(k3a, k3b, ei);
    const float s1 = act + sd * e1;
    const float s2 = act + sd * e2;
    const float dd = (s2 - act) / sd;
    const float lp = -0.5f * (dd * dd) - logf(sd) - 0.9189385332046727f;
    const float attv = 20.0f * jsigmoid(s1);
    out[OUT_SLOG + (long)b * 256 + t * 2 + h]  = ly;
    out[OUT_ACT  + (long)b * 256 + h * 128 + t] = act;
    out[OUT_LOGP + (long)b * 256 + h * 128 + t] = lp;
    att_s[h] = attv;
  }
  __syncthreads();
  const float* xr = X + ((long)b * TT + t) * DD;
  unsigned short* tr = texts_b + (long)r * 320;
  for (int j = tid; j < 320; j += 256){
    unsigned short o = 0;
    if (j < 300) o = f2bf(xr[j] * att_s[j / 150]);
    tr[j] = o;
  }
}

// ---------------- weight conversion to bf16 ----------------
__global__ __launch_bounds__(256) void k_cvt_whh(
    const float* __restrict__ W, unsigned short* __restrict__ O)
{
  const int i = blockIdx.x * 256 + threadIdx.x;   // 3072*1024
  O[i] = f2bf(W[i]);
}

__global__ __launch_bounds__(256) void k_cvt_wih(
    const float* __restrict__ W, unsigned short* __restrict__ O)
{
  const int i = blockIdx.x * 256 + threadIdx.x;   // 3072*320
  const int rw = i / 320, c = i - rw * 320;
  O[i] = (c < DD) ? f2bf(W[(long)rw * DD + c]) : (unsigned short)0;
}

// ---------------- stage-2 persistent: 128 blocks x 512 thr ----------------
// Block (m,n): batch rows [m*64,+64) x cols [n*16,+16) x 3 gates.
// Per-WAVE A-staging: each wave loads its own 16 A-rows into a private 2KB
// LDS buffer (cross-lane only within the wave -> in-order LDS pipe +
// lgkmcnt, NO __syncthreads in the chunk loops). Wave-group 0: hidden K
// [0,512) + texts K [0,192); group 1: hidden [512,1024) + texts [192,320).
// Hidden loads issued 8-deep with counted vmcnt. XOR swizzle, 128B pitch.
// LDS: W 129792 | wave bufs 8x2048 (reduce region overlaps, sync-fenced).
#define NBLK2 128
#define WPITCH 2704   // 1344*2 + 16

__global__ __launch_bounds__(512) void k_stage2(
    const unsigned short* __restrict__ texts_b,
    const unsigned short* __restrict__ Whb,
    const unsigned short* __restrict__ Wib,
    const float* __restrict__ bih, const float* __restrict__ bhh,
    const int* __restrict__ lengths,
    unsigned short* __restrict__ h2b0, unsigned short* __restrict__ h2b1,
    float* __restrict__ last,
    unsigned int* __restrict__ flags)
{
  __shared__ __align__(16) char lds[150272];   // W:129792 | A/reduce: 20480
  unsigned short* Wl = (unsigned short*)lds;
  char* Al = lds + 129792;

  const int tid = threadIdx.x;
  const int bid = blockIdx.x;
  const int m = bid >> 6, n = bid & 63;
  const int e0 = n * 16, mrow = m * 64;
  const int wave = tid >> 6, wg = wave >> 2, wvr = wave & 3;
  const int lane = tid & 63, lo = lane & 15, hi = lane >> 4;
  const int tidg = tid & 255;

  // ---- stage W (48 x 1344 bf16) once ----
  for (int s = tid; s < 48 * 168; s += 512){
    const int row = s / 168, q = s - row * 168;
    const int g = row >> 4, nn = row & 15;
    const long wrow = (long)g * EE + e0 + nn;
    uint4 v;
    if (q < 128) v = *(const uint4*)(Whb + wrow * EE + q * 8);
    else         v = *(const uint4*)(Wib + wrow * 320 + (q - 128) * 8);
    *(uint4*)((char*)Wl + (long)row * WPITCH + q * 16) = v;
  }

  const int e = e0 + lo;
  const float bR = bih[e] + bhh[e];
  const float bZ = bih[EE + e] + bhh[EE + e];
  const float biN = bih[2*EE + e];
  const float bhN = bhh[2*EE + e];
  int li[4]; float hp[4];
#pragma unroll
  for (int j = 0; j < 4; ++j){
    const int brow = wvr * 16 + hi * 4 + j;
    int l = lengths[mrow + brow] - 1; if (l < 0) l += TT;
    li[j] = l; hp[j] = 0.0f;
  }
  __syncthreads();

  using frag = __attribute__((ext_vector_type(8))) short;
  using f32x4 = __attribute__((ext_vector_type(4))) float;

  // per-wave A buffer: 16 rows x 128B, XOR-swizzled
  char* Aw = Al + wave * 2048;
  const int lrow = lane >> 2, lkq0 = lane & 3, lkq1 = (lane & 3) + 4;
  const int woff0 = lrow * 128 + ((lkq0 ^ (lrow & 7)) << 4);
  const int woff1 = lrow * 128 + ((lkq1 ^ (lrow & 7)) << 4);
  const int growA = mrow + wvr * 16 + lrow;      // global A row this lane loads
  const int roff0 = lo * 128 + (((0 + hi) ^ (lo & 7)) << 4);   // kf=0 read
  const int roff1 = lo * 128 + (((4 + hi) ^ (lo & 7)) << 4);   // kf=1 read
  int boff[3];
#pragma unroll
  for (int g = 0; g < 3; ++g) boff[g] = (g * 16 + lo) * WPITCH + hi * 16;

  unsigned int* flagp = flags + bid * 16;

  for (int t = 0; t < TT; ++t){
    const unsigned short* hb = (t & 1) ? h2b1 : h2b0;
    unsigned short* ho = (t & 1) ? h2b0 : h2b1;
    const unsigned short* txp = texts_b + (long)t * BB * 320;

    f32x4 aR = {0,0,0,0}, aZ = {0,0,0,0}, aNH = {0,0,0,0}, aNI = {0,0,0,0};

    // per-wave chunk: stage 2 b128 into own buffer, lgkm-fence, read frags, MFMA
    auto chunkA = [&](int cc, u32x4 r0, u32x4 r1, bool hid){
      asm volatile("" ::: "memory");
      *(u32x4*)(Aw + woff0) = r0;
      *(u32x4*)(Aw + woff1) = r1;
      asm volatile("s_waitcnt lgkmcnt(0)" ::: "memory");
      __builtin_amdgcn_sched_barrier(0);
      frag a0 = *(const frag*)(Aw + roff0);
      frag a1 = *(const frag*)(Aw + roff1);
      asm volatile("" ::: "memory");
      const char* wb = (const char*)Wl + cc * 128;
      frag b00 = *(const frag*)(wb + boff[0]);
      frag b10 = *(const frag*)(wb + boff[1]);
      frag b20 = *(const frag*)(wb + boff[2]);
      frag b01 = *(const frag*)(wb + boff[0] + 64);
      frag b11 = *(const frag*)(wb + boff[1] + 64);
      frag b21 = *(const frag*)(wb + boff[2] + 64);
      aR = __builtin_amdgcn_mfma_f32_16x16x32_bf16(a0, b00, aR, 0, 0, 0);
      aZ = __builtin_amdgcn_mfma_f32_16x16x32_bf16(a0, b10, aZ, 0, 0, 0);
      if (hid) aNH = __builtin_amdgcn_mfma_f32_16x16x32_bf16(a0, b20, aNH, 0, 0, 0);
      else     aNI = __builtin_amdgcn_mfma_f32_16x16x32_bf16(a0, b20, aNI, 0, 0, 0);
      aR = __builtin_amdgcn_mfma_f32_16x16x32_bf16(a1, b01, aR, 0, 0, 0);
      aZ = __builtin_amdgcn_mfma_f32_16x16x32_bf16(a1, b11, aZ, 0, 0, 0);
      if (hid) aNH = __builtin_amdgcn_mfma_f32_16x16x32_bf16(a1, b21, aNH, 0, 0, 0);
      else     aNI = __builtin_amdgcn_mfma_f32_16x16x32_bf16(a1, b21, aNI, 0, 0, 0);
    };

    // ---- texts phase (per-wave, barrier-free) ----
    {
      const unsigned short* tp = txp + (long)growA * 320 + (wg ? 192 : 0);
      u32x4 t0a, t0b, t1a, t1b, t2a = {0,0,0,0}, t2b = {0,0,0,0};
      t0a = load_b128_llc(tp + lkq0 * 8);        t0b = load_b128_llc(tp + lkq1 * 8);
      t1a = load_b128_llc(tp + 64 + lkq0 * 8);   t1b = load_b128_llc(tp + 64 + lkq1 * 8);
      if (wg == 0){
        t2a = load_b128_llc(tp + 128 + lkq0 * 8);
        t2b = load_b128_llc(tp + 128 + lkq1 * 8);
        WAITV(4); chunkA(16, t0a, t0b, false);
        WAITV(2); chunkA(17, t1a, t1b, false);
        WAITV(0); chunkA(18, t2a, t2b, false);
      } else {
        WAITV(2); chunkA(19, t0a, t0b, false);
        WAITV(0); chunkA(20, t1a, t1b, false);
      }
    }

    // ---- barrier (same-m domain) + hidden phase (8 chunks, 8-deep issue) ----
    if (t > 0){
      if (tid < 64){
        const unsigned int* fp = flags + ((m << 6) + tid) * 16;
        unsigned v = poll_u32_llc(fp);
        while (v < (unsigned)t){
          __builtin_amdgcn_s_sleep(2);
          v = poll_u32_llc(fp);
        }
      }
      __syncthreads();

      const unsigned short* hpK = hb + (long)growA * EE + (wg << 9);
      u32x4 h0a = load_b128_llc(hpK +   0 + lkq0*8), h0b = load_b128_llc(hpK +   0 + lkq1*8);
      u32x4 h1a = load_b128_llc(hpK +  64 + lkq0*8), h1b = load_b128_llc(hpK +  64 + lkq1*8);
      u32x4 h2a = load_b128_llc(hpK + 128 + lkq0*8), h2b_ = load_b128_llc(hpK + 128 + lkq1*8);
      u32x4 h3a = load_b128_llc(hpK + 192 + lkq0*8), h3b = load_b128_llc(hpK + 192 + lkq1*8);
      u32x4 h4a = load_b128_llc(hpK + 256 + lkq0*8), h4b = load_b128_llc(hpK + 256 + lkq1*8);
      u32x4 h5a = load_b128_llc(hpK + 320 + lkq0*8), h5b = load_b128_llc(hpK + 320 + lkq1*8);
      u32x4 h6a = load_b128_llc(hpK + 384 + lkq0*8), h6b = load_b128_llc(hpK + 384 + lkq1*8);
      u32x4 h7a = load_b128_llc(hpK + 448 + lkq0*8), h7b = load_b128_llc(hpK + 448 + lkq1*8);
      const int cb = wg * 8;
      WAITV(14); chunkA(cb + 0, h0a, h0b, true);
      WAITV(12); chunkA(cb + 1, h1a, h1b, true);
      WAITV(10); chunkA(cb + 2, h2a, h2b_, true);
      WAITV(8);  chunkA(cb + 3, h3a, h3b, true);
      WAITV(6);  chunkA(cb + 4, h4a, h4b, true);
      WAITV(4);  chunkA(cb + 5, h5a, h5b, true);
      WAITV(2);  chunkA(cb + 6, h6a, h6b, true);
      WAITV(0);  chunkA(cb + 7, h7a, h7b, true);
    }

    // ---- cross-group reduce (Al reused; fenced by barriers) ----
    __syncthreads();
    if (wg == 1){
      char* dst = Al + tidg * 80;
      *(f32x4*)(dst)      = aR;
      *(f32x4*)(dst + 16) = aZ;
      *(f32x4*)(dst + 32) = aNH;
      *(f32x4*)(dst + 48) = aNI;
    }
    __syncthreads();
    if (wg == 0){
      const char* src = Al + tidg * 80;
      const f32x4 pR  = *(const f32x4*)(src);
      const f32x4 pZ  = *(const f32x4*)(src + 16);
      const f32x4 pNH = *(const f32x4*)(src + 32);
      const f32x4 pNI = *(const f32x4*)(src + 48);
#pragma unroll
      for (int j = 0; j < 4; ++j){
        aR[j] += pR[j]; aZ[j] += pZ[j]; aNH[j] += pNH[j]; aNI[j] += pNI[j];
      }
      // GRU gates epilogue (group 0 only)
#pragma unroll
      for (int j = 0; j < 4; ++j){
        const int brow = wvr * 16 + hi * 4 + j;
        const float r = jsigmoid(aR[j] + bR);
        const float z = jsigmoid(aZ[j] + bZ);
        const float nn2 = tanhf(aNI[j] + biN + r * (aNH[j] + bhN));
        const float hn = (1.0f - z) * nn2 + z * hp[j];
        hp[j] = hn;
        store_u16_llc(ho + (long)(mrow + brow) * EE + e, (unsigned)f2bf(hn));
        if (t == li[j]) last[(long)(mrow + brow) * EE + e] = hn;
      }
    }

    if (t < TT - 1){
      asm volatile("s_waitcnt vmcnt(0)" ::: "memory");
      __syncthreads();
      if (tid == 0) store_u32_llc(flagp, (unsigned)(t + 1));
    }
  }
}

// ---------------- BatchNorm ----------------
__global__ __launch_bounds__(256) void k_bn_stats(
    const float* __restrict__ last, float* __restrict__ mv)
{
  const int e = blockIdx.x * 256 + threadIdx.x;
  if (e >= EE) return;
  float s = 0.0f;
  for (int b = 0; b < BB; ++b) s += last[(long)b * EE + e];
  const float mean = s / 128.0f;
  float v = 0.0f;
  for (int b = 0; b < BB; ++b){ float d = last[(long)b * EE + e] - mean; v += d * d; }
  mv[e] = mean;
  mv[EE + e] = v / 128.0f;
}

__global__ __launch_bounds__(256) void k_bn_apply(
    const float* __restrict__ last, const float* __restrict__ mv,
    const float* __restrict__ gamma, const float* __restrict__ beta,
    float* __restrict__ out)
{
  const int gid = blockIdx.x * 256 + threadIdx.x;
  const int e = gid & 1023;
  const float xm = last[gid] - mv[e];
  out[gid] = gamma[e] * xm / sqrtf(mv[EE + e] + 1e-5f) + beta[e];
}

// ---------------- launcher ----------------
extern "C" void kernel_launch(void* const* d_in, const int* in_sizes, int n_in,
                              void* d_out, int out_size, void* d_ws, size_t ws_size,
                              hipStream_t stream)
{
  (void)in_sizes; (void)n_in; (void)out_size;
  const float* x     = (const float*)d_in[0];
  const int*   lens  = (const int*)d_in[1];
  const float* Wih_c = (const float*)d_in[3];
  const float* Whh_c = (const float*)d_in[4];
  const float* bih_c = (const float*)d_in[5];
  const float* bhh_c = (const float*)d_in[6];
  const float* Wmu   = (const float*)d_in[7];
  const float* bmu   = (const float*)d_in[8];
  const float* Wlv   = (const float*)d_in[9];
  const float* blv   = (const float*)d_in[10];
  const float* Wih_r = (const float*)d_in[11];
  const float* Whh_r = (const float*)d_in[12];
  const float* bih_r = (const float*)d_in[13];
  const float* bhh_r = (const float*)d_in[14];
  const float* gam   = (const float*)d_in[15];
  const float* bet   = (const float*)d_in[16];
  float* out = (float*)d_out;

  uint32_t nk[4][2];
  for (uint32_t i = 0; i < 4; ++i) tf2x32(0u, 42u, 0u, i, &nk[i][0], &nk[i][1]);

  float* ws = (float*)d_ws;
  size_t off = 0;
  float* U       = ws + off; off += 16384000;  // gi_all then mu_all (aliased)
  float* hx_all  = ws + off; off += 4915200;
  float* lv_all  = ws + off; off += 32768;
  float* Wp      = ws + off; off += 307200;    // packed Whh_c
  float* lastb   = ws + off; off += 131072;
  float* mv      = ws + off; off += 2048;
  float* hex     = ws + off; off += 77824;     // [2][128][304] f32 stage-1 exchange
  unsigned int* flags  = (unsigned int*)(ws + off); off += 2048;  // stage-2: 128*16
  unsigned int* flagsA = (unsigned int*)(ws + off); off += 4096;  // stage-1: 256*16
  unsigned short* texts_b = (unsigned short*)(ws + off); off += 2621440; // 16384x320 bf16
  unsigned short* h2b0    = (unsigned short*)(ws + off); off += 65536;   // 128x1024 bf16
  unsigned short* h2b1    = (unsigned short*)(ws + off); off += 65536;
  unsigned short* Whb     = (unsigned short*)(ws + off); off += 1572864; // 3072x1024 bf16
  unsigned short* Wib     = (unsigned short*)(ws + off); off += 491520;  // 3072x320 bf16
  if (ws_size < off * sizeof(float)) return;

  hipMemsetAsync(flags, 0, 2048 * sizeof(unsigned int), stream);
  hipMemsetAsync(flagsA, 0, 4096 * sizeof(unsigned int), stream);

  // weight prep
  k_cvt_whh<<<dim3(12288), 256, 0, stream>>>(Whh_r, Whb);
  k_cvt_wih<<<dim3(3840), 256, 0, stream>>>(Wih_r, Wib);
  k_pack_whh<<<dim3(300), 256, 0, stream>>>(Whh_c, Wp);

  // stage-1 input projection + persistent jj-split recurrence
  k_gemm_gi<<<dim3(15, 128), 256, 0, stream>>>(x, Wih_c, bih_c, U);
  k_stage1<<<dim3(256), 256, 0, stream>>>(Wp, bhh_c, U, hx_all, hex, flagsA);

  // batched mu / lv / sampling
  k_gemm_mu<<<dim3(16, 128), 256, 0, stream>>>(x, hx_all, Wmu, bmu, U);
  k_lv<<<dim3(4096), 256, 0, stream>>>(x, hx_all, Wlv, blv, lv_all);
  k_sample<<<dim3(16384), 256, 0, stream>>>(x, U, lv_all, texts_b, out,
      nk[0][0], nk[0][1], nk[1][0], nk[1][1],
      nk[2][0], nk[2][1], nk[3][0], nk[3][1]);

  // stage-2 persistent recurrence (per-wave staging, barrier-free chunks)
  k_stage2<<<dim3(NBLK2), 512, 0, stream>>>(texts_b, Whb, Wib, bih_r, bhh_r, lens,
                                            h2b0, h2b1, lastb, flags);

  // batchnorm
  k_bn_stats<<<dim3(4), 256, 0, stream>>>(lastb, mv);
  k_bn_apply<<<dim3(512), 256, 0, stream>>>(lastb, mv, gam, bet, out);
}

// Round 11
// 2046.854 us; speedup vs baseline: 4.0008x; 1.0352x over previous
//
#include <hip/hip_runtime.h>
#include <stdint.h>

#define TT 128
#define BB 128
#define DD 300
#define EE 1024
#define GG 900
#define NMU 1000
#define ASP 500

#define OUT_SLOG 131072
#define OUT_ACT  163840
#define OUT_LOGP 196608

typedef unsigned int u32x4 __attribute__((ext_vector_type(4)));

// ---------------- threefry2x32 (JAX, 20 rounds) ----------------
__host__ __device__ static inline uint32_t rotl32(uint32_t x, int r){
  return (x << r) | (x >> (32 - r));
}

__host__ __device__ static inline void tf2x32(uint32_t k0, uint32_t k1,
                                              uint32_t x0, uint32_t x1,
                                              uint32_t* o0, uint32_t* o1){
  uint32_t ks2 = k0 ^ k1 ^ 0x1BD11BDAu;
#define TFR(r) { x0 += x1; x1 = rotl32(x1, r); x1 ^= x0; }
  x0 += k0; x1 += k1;
  TFR(13) TFR(15) TFR(26) TFR(6)
  x0 += k1; x1 += ks2 + 1u;
  TFR(17) TFR(29) TFR(16) TFR(24)
  x0 += ks2; x1 += k0 + 2u;
  TFR(13) TFR(15) TFR(26) TFR(6)
  x0 += k0; x1 += k1 + 3u;
  TFR(17) TFR(29) TFR(16) TFR(24)
  x0 += k1; x1 += ks2 + 4u;
  TFR(13) TFR(15) TFR(26) TFR(6)
  x0 += ks2; x1 += k0 + 5u;
#undef TFR
  *o0 = x0; *o1 = x1;
}

__device__ static inline uint32_t rng32(uint32_t k0, uint32_t k1, uint32_t idx){
  uint32_t a, b;
  tf2x32(k0, k1, 0u, idx, &a, &b);
  return a ^ b;
}

__device__ static inline float u01(uint32_t bits){
  return __uint_as_float((bits >> 9) | 0x3f800000u) - 1.0f;
}

__device__ static inline float jgumbel(uint32_t k0, uint32_t k1, uint32_t idx){
  float u = u01(rng32(k0, k1, idx));
  float l1 = logf(u + 1e-20f);
  return -logf(-l1 + 1e-20f);
}

__device__ static inline float erfinv32(float x){   // XLA ErfInv32 (Giles)
  float w = -log1pf(-x * x);
  float p;
  if (w < 5.0f){
    w = w - 2.5f;
    p = 2.81022636e-08f;
    p = 3.43273939e-07f  + p * w;
    p = -3.5233877e-06f  + p * w;
    p = -4.39150654e-06f + p * w;
    p = 0.00021858087f   + p * w;
    p = -0.00125372503f  + p * w;
    p = -0.00417768164f  + p * w;
    p = 0.246640727f     + p * w;
    p = 1.50140941f      + p * w;
  } else {
    w = sqrtf(w) - 3.0f;
    p = -0.000200214257f;
    p = 0.000100950558f  + p * w;
    p = 0.00134934322f   + p * w;
    p = -0.00367342844f  + p * w;
    p = 0.00573950773f   + p * w;
    p = -0.0076224613f   + p * w;
    p = 0.00943887047f   + p * w;
    p = 1.00167406f      + p * w;
    p = 2.83297682f      + p * w;
  }
  return p * x;
}

__device__ static inline float jnormal(uint32_t k0, uint32_t k1, uint32_t idx){
  float u = u01(rng32(k0, k1, idx));
  const float lo = -0.99999994f;
  float v = u * 2.0f + lo;
  v = fmaxf(lo, v);
  return 1.41421356237f * erfinv32(v);
}

__device__ static inline float jsigmoid(float x){
  return 1.0f / (1.0f + expf(-x));
}

__device__ static inline unsigned short f2bf(float f){   // RNE f32->bf16
  uint32_t u = __float_as_uint(f);
  uint32_t r = (u + 0x7fffu + ((u >> 16) & 1u)) >> 16;
  return (unsigned short)r;
}

// ---- LLC-coherent (cross-XCD) memory ops: sc0 sc1 = bypass L1+L2 ----
__device__ static inline u32x4 load_b128_llc(const void* p){
  u32x4 r;
  asm volatile("global_load_dwordx4 %0, %1, off sc0 sc1"
               : "=v"(r) : "v"(p) : "memory");
  return r;
}
__device__ static inline void store_u16_llc(void* p, unsigned v){
  asm volatile("global_store_short %0, %1, off sc0 sc1"
               :: "v"(p), "v"(v) : "memory");
}
__device__ static inline unsigned poll_u32_llc(const void* p){
  unsigned r;
  asm volatile("global_load_dword %0, %1, off sc0 sc1\n\ts_waitcnt vmcnt(0)"
               : "=v"(r) : "v"(p) : "memory");
  return r;
}
__device__ static inline void store_u32_llc(void* p, unsigned v){
  asm volatile("global_store_dword %0, %1, off sc0 sc1"
               :: "v"(p), "v"(v) : "memory");
}

#define WAITV(N) do{ asm volatile("s_waitcnt vmcnt(" #N ")" ::: "memory"); \
                     __builtin_amdgcn_sched_barrier(0); }while(0)

// ---------------- GEMM1: gi_all[r=(t*BB+b)][900] = x@Wih_c^T + bih ----------------
#define FMA4(ACC, S, B) { ACC.x += (S)*(B).x; ACC.y += (S)*(B).y; \
                          ACC.z += (S)*(B).z; ACC.w += (S)*(B).w; }

__global__ __launch_bounds__(256) void k_gemm_gi(
    const float* __restrict__ X, const float* __restrict__ W,
    const float* __restrict__ bias, float* __restrict__ C)
{
  __shared__ float As[16][132];
  __shared__ float Bs[16][68];
  const int tid = threadIdx.x;
  const int rbase = blockIdx.y * 128;
  const int cbase = blockIdx.x * 64;
  const int tx = tid & 15, ty = tid >> 4;
  const int sr = tid >> 2, sq = tid & 3;
  const int wj = cbase + sr;

  float4 acc[8];
#pragma unroll
  for (int i = 0; i < 8; ++i) acc[i] = (float4){0,0,0,0};

  for (int k0 = 0; k0 < 304; k0 += 16){
    const int k = k0 + sq * 4;
#pragma unroll
    for (int i = 0; i < 2; ++i){
      const int row = sr + i * 64;
      const int rg = rbase + row;
      float4 va = {0,0,0,0};
      if (k < DD) va = *(const float4*)(X + ((long)(rg & 127) * TT + (rg >> 7)) * DD + k);
      As[sq*4+0][row] = va.x; As[sq*4+1][row] = va.y;
      As[sq*4+2][row] = va.z; As[sq*4+3][row] = va.w;
    }
    {
      float4 vb = {0,0,0,0};
      if (k < DD && wj < GG) vb = *(const float4*)(W + (long)wj * DD + k);
      Bs[sq*4+0][sr] = vb.x; Bs[sq*4+1][sr] = vb.y;
      Bs[sq*4+2][sr] = vb.z; Bs[sq*4+3][sr] = vb.w;
    }
    __syncthreads();
#pragma unroll
    for (int kk = 0; kk < 16; ++kk){
      const float4 b  = *(const float4*)&Bs[kk][tx * 4];
      const float4 a0 = *(const float4*)&As[kk][ty * 8];
      const float4 a1 = *(const float4*)&As[kk][ty * 8 + 4];
      FMA4(acc[0], a0.x, b); FMA4(acc[1], a0.y, b);
      FMA4(acc[2], a0.z, b); FMA4(acc[3], a0.w, b);
      FMA4(acc[4], a1.x, b); FMA4(acc[5], a1.y, b);
      FMA4(acc[6], a1.z, b); FMA4(acc[7], a1.w, b);
    }
    __syncthreads();
  }
  const int ci = cbase + tx * 4;
  float bv[4];
#pragma unroll
  for (int j = 0; j < 4; ++j) bv[j] = (ci + j < GG) ? bias[ci + j] : 0.0f;
#pragma unroll
  for (int i = 0; i < 8; ++i){
    const int r = rbase + ty * 8 + i;
    float vals[4] = {acc[i].x + bv[0], acc[i].y + bv[1],
                     acc[i].z + bv[2], acc[i].w + bv[3]};
    float* crow = C + (long)r * GG;
    if (ci + 3 < GG){
      float4 st = {vals[0], vals[1], vals[2], vals[3]};
      *(float4*)(crow + ci) = st;
    } else {
#pragma unroll
      for (int j = 0; j < 4; ++j) if (ci + j < GG) crow[ci + j] = vals[j];
    }
  }
}

// ---------------- GEMM-mu: 128x64 tile, 8x4 per thread ----------------
__global__ __launch_bounds__(256) void k_gemm_mu(
    const float* __restrict__ X, const float* __restrict__ HX,
    const float* __restrict__ W, const float* __restrict__ bias,
    float* __restrict__ C)
{
  __shared__ float As[16][132];
  __shared__ float Bs[16][68];
  const int tid = threadIdx.x;
  const int rbase = blockIdx.y * 128;
  const int cbase = blockIdx.x * 64;
  const int tx = tid & 15, ty = tid >> 4;
  const int sr = tid >> 2, sq = tid & 3;
  const int wj = cbase + sr;

  float4 acc[8];
#pragma unroll
  for (int i = 0; i < 8; ++i) acc[i] = (float4){0,0,0,0};

  for (int k0 = 0; k0 < 608; k0 += 16){
    const int k = k0 + sq * 4;
#pragma unroll
    for (int i = 0; i < 2; ++i){
      const int row = sr + i * 64;
      const int rg = rbase + row;
      float4 va = {0,0,0,0};
      if (k < 300)      va = *(const float4*)(X + ((long)(rg & 127) * TT + (rg >> 7)) * DD + k);
      else if (k < 600) va = *(const float4*)(HX + (long)rg * DD + (k - 300));
      va.x = fmaxf(va.x, 0.f); va.y = fmaxf(va.y, 0.f);
      va.z = fmaxf(va.z, 0.f); va.w = fmaxf(va.w, 0.f);
      As[sq*4+0][row] = va.x; As[sq*4+1][row] = va.y;
      As[sq*4+2][row] = va.z; As[sq*4+3][row] = va.w;
    }
    {
      float4 vb = {0,0,0,0};
      if (k < 600 && wj < NMU) vb = *(const float4*)(W + (long)wj * 600 + k);
      Bs[sq*4+0][sr] = vb.x; Bs[sq*4+1][sr] = vb.y;
      Bs[sq*4+2][sr] = vb.z; Bs[sq*4+3][sr] = vb.w;
    }
    __syncthreads();
#pragma unroll
    for (int kk = 0; kk < 16; ++kk){
      const float4 b  = *(const float4*)&Bs[kk][tx * 4];
      const float4 a0 = *(const float4*)&As[kk][ty * 8];
      const float4 a1 = *(const float4*)&As[kk][ty * 8 + 4];
      FMA4(acc[0], a0.x, b); FMA4(acc[1], a0.y, b);
      FMA4(acc[2], a0.z, b); FMA4(acc[3], a0.w, b);
      FMA4(acc[4], a1.x, b); FMA4(acc[5], a1.y, b);
      FMA4(acc[6], a1.z, b); FMA4(acc[7], a1.w, b);
    }
    __syncthreads();
  }
  const int ci = cbase + tx * 4;
  float bv[4];
#pragma unroll
  for (int j = 0; j < 4; ++j) bv[j] = (ci + j < NMU) ? bias[ci + j] : 0.0f;
#pragma unroll
  for (int i = 0; i < 8; ++i){
    const int r = rbase + ty * 8 + i;
    float vals[4] = {acc[i].x + bv[0], acc[i].y + bv[1],
                     acc[i].z + bv[2], acc[i].w + bv[3]};
    float* crow = C + (long)r * NMU;
    if (ci + 3 < NMU){
      float4 st = {vals[0], vals[1], vals[2], vals[3]};
      *(float4*)(crow + ci) = st;
    } else {
#pragma unroll
      for (int j = 0; j < 4; ++j) if (ci + j < NMU) crow[ci + j] = vals[j];
    }
  }
}

// ---------------- lv (pre-softplus), wave-per-row ----------------
__global__ __launch_bounds__(256) void k_lv(
    const float* __restrict__ X, const float* __restrict__ HX,
    const float* __restrict__ Wlv, const float* __restrict__ blv,
    float* __restrict__ LV)
{
  const int r = blockIdx.x * 4 + (threadIdx.x >> 6);   // 16384 rows
  const int lane = threadIdx.x & 63;
  const float* xr = X + ((long)(r & 127) * TT + (r >> 7)) * DD;
  const float* hr = HX + (long)r * DD;
  float a0 = 0.0f, a1 = 0.0f;
  for (int k = lane; k < DD; k += 64){
    float v = fmaxf(xr[k], 0.0f);
    a0 += v * Wlv[k];       a1 += v * Wlv[600 + k];
    float w = fmaxf(hr[k], 0.0f);
    a0 += w * Wlv[300 + k]; a1 += w * Wlv[900 + k];
  }
#pragma unroll
  for (int off = 32; off > 0; off >>= 1){
    a0 += __shfl_down(a0, off);
    a1 += __shfl_down(a1, off);
  }
  if (lane == 0){
    LV[(long)r * 2 + 0] = a0 + blv[0];
    LV[(long)r * 2 + 1] = a1 + blv[1];
  }
}

// ---------------- Whh_c pack: Wp[kq][1024 j][4 c] = Whh_c[j][4kq+c] ----------------
__global__ __launch_bounds__(256) void k_pack_whh(
    const float* __restrict__ W, float* __restrict__ Wp)
{
  const int i = blockIdx.x * 256 + threadIdx.x;   // 75*1024
  const int kq = i >> 10, j = i & 1023;
  float4 v = {0,0,0,0};
  if (kq < 75 && j < GG){
    const float* s = W + (long)j * DD + kq * 4;
    v.x = s[0]; v.y = s[1]; v.z = s[2]; v.w = s[3];
  }
  *(float4*)(Wp + (long)i * 4) = v;
}

// ---------------- stage-1: 256 blocks = 32 batch-quads x 8 jj-slices ----------------
// Block (bq, js): batch rows [bq*4, +4) x hidden slice [jj0, jj0+wid), all 3
// gates, W slice (<=114 cols x 300 x f32 = 136.8KB) LDS-RESIDENT (was 270KB/step
// streamed from L2 = 2.2us/step, the R10 wall). h exchanged in the 8-block
// cluster via LLC with parity double-buffer + per-block flag (same protocol).
// Accumulation order per output unchanged -> bit-identical results.
#define S1PAD 304

__global__ __launch_bounds__(256) void k_stage1(
    const float* __restrict__ Wp, const float* __restrict__ bhh,
    const float* __restrict__ gi_all, float* __restrict__ hx_all,
    float* __restrict__ hex, unsigned int* __restrict__ flagsA)
{
  __shared__ __align__(16) float LW[75 * 114 * 4];   // [kq][lc][4] = 136.8KB
  __shared__ __align__(16) float hs[4][S1PAD];
  __shared__ float ghs[4][116];
  const int tid = threadIdx.x;
  const int bid = blockIdx.x;
  const int bq = bid >> 3, js = bid & 7;
  const int b0 = bq * 4;
  const int wid = (js < 4) ? 38 : 37;
  const int jj0 = (js < 4) ? js * 38 : 152 + (js - 4) * 37;
  const int NC = 3 * wid;                     // 114 or 111

  // ---- stage W slice into LDS once ----
  for (int s = tid; s < 75 * NC; s += 256){
    const int kq = s / NC, lc = s - kq * NC;
    const int gate = lc / wid, col = lc - gate * wid;
    const int jcol = gate * 300 + jj0 + col;
    *(float4*)&LW[(kq * 114 + lc) * 4] =
        *(const float4*)(Wp + ((long)kq * 1024 + jcol) * 4);
  }

  // matvec thread: gc = lc, rp = row-pair
  const int gc = tid >> 1, rp = tid & 1;
  const bool mact = (gc < NC);

  // gates thread: (row, col)
  const bool gact = tid < 4 * wid;
  const int grow = gact ? (tid / wid) : 0;
  const int gcol = gact ? (tid - grow * wid) : 0;
  const int gjj = jj0 + gcol;
  float bhr = 0.f, bhz = 0.f, bhn = 0.f;
  if (gact){ bhr = bhh[gjj]; bhz = bhh[DD + gjj]; bhn = bhh[2*DD + gjj]; }

  for (int i = tid; i < 4 * S1PAD; i += 256) ((float*)hs)[i] = 0.f;
  __syncthreads();

  unsigned int* myflag = flagsA + bid * 16;

  for (int t = 0; t < TT; ++t){
    // gi prefetch (independent of h)
    float gir = 0.f, giz = 0.f, gin = 0.f;
    if (gact){
      const float* gp = gi_all + ((long)t * BB + b0 + grow) * GG;
      gir = gp[gjj]; giz = gp[DD + gjj]; gin = gp[2*DD + gjj];
    }

    // matvec: thread (gc, rp) computes rows {2rp, 2rp+1} for its (gate,col)
    if (mact){
      const int r0 = rp * 2, r1 = rp * 2 + 1;
      float4 a0 = {0,0,0,0}, a1 = {0,0,0,0};
#pragma unroll 5
      for (int kq = 0; kq < 75; ++kq){
        const float4 w  = *(const float4*)&LW[(kq * 114 + gc) * 4];
        const float4 h0 = *(const float4*)&hs[r0][kq * 4];
        const float4 h1 = *(const float4*)&hs[r1][kq * 4];
        a0.x = fmaf(w.x, h0.x, a0.x); a0.y = fmaf(w.y, h0.y, a0.y);
        a0.z = fmaf(w.z, h0.z, a0.z); a0.w = fmaf(w.w, h0.w, a0.w);
        a1.x = fmaf(w.x, h1.x, a1.x); a1.y = fmaf(w.y, h1.y, a1.y);
        a1.z = fmaf(w.z, h1.z, a1.z); a1.w = fmaf(w.w, h1.w, a1.w);
      }
      ghs[r0][gc] = (a0.x + a0.y) + (a0.z + a0.w);
      ghs[r1][gc] = (a1.x + a1.y) + (a1.z + a1.w);
    }
    __syncthreads();

    // gates + h update + exchange store (own slice)
    const int par = t & 1;
    if (gact){
      const float r = jsigmoid(gir + ghs[grow][gcol] + bhr);
      const float z = jsigmoid(giz + ghs[grow][wid + gcol] + bhz);
      const float n = tanhf(gin + r * (ghs[grow][2*wid + gcol] + bhn));
      const float hn = (1.0f - z) * n + z * hs[grow][gjj];
      hx_all[((long)t * BB + b0 + grow) * DD + gjj] = hn;
      if (t < TT - 1)
        store_u32_llc(hex + ((long)par * BB + b0 + grow) * S1PAD + gjj,
                      __float_as_uint(hn));
    }

    if (t < TT - 1){
      asm volatile("s_waitcnt vmcnt(0)" ::: "memory");
      __syncthreads();
      if (tid == 0) store_u32_llc(myflag, (unsigned)(t + 1));
      if (tid < 8){
        const unsigned int* fp = flagsA + (bq * 8 + tid) * 16;
        unsigned v = poll_u32_llc(fp);
        while (v < (unsigned)(t + 1)){
          __builtin_amdgcn_s_sleep(1);
          v = poll_u32_llc(fp);
        }
      }
      __syncthreads();
      // vectorized refresh: 304 float4 LLC loads (4 rows x 76), one round trip
      {
        const float* src = hex + (long)par * BB * S1PAD + (long)b0 * S1PAD;
        const int t0 = tid, t1 = tid + 256;
        const int r0 = t0 / 76, c0 = t0 - r0 * 76;
        u32x4 v0 = load_b128_llc(src + (long)r0 * S1PAD + c0 * 4);
        u32x4 v1 = (u32x4){0,0,0,0};
        int r1 = 0, c1 = 0;
        if (t1 < 304){
          r1 = t1 / 76; c1 = t1 - r1 * 76;
          v1 = load_b128_llc(src + (long)r1 * S1PAD + c1 * 4);
        }
        WAITV(0);
        *(u32x4*)&hs[r0][c0 * 4] = v0;
        if (t1 < 304) *(u32x4*)&hs[r1][c1 * 4] = v1;
      }
      __syncthreads();
    }
  }
}

// ---------------- sampling ----------------
__global__ __launch_bounds__(256) void k_sample(
    const float* __restrict__ X, const float* __restrict__ mu_all,
    const float* __restrict__ lv_all, unsigned short* __restrict__ texts_b,
    float* __restrict__ out,
    const uint32_t k0a, const uint32_t k0b, const uint32_t k1a, const uint32_t k1b,
    const uint32_t k2a, const uint32_t k2b, const uint32_t k3a, const uint32_t k3b)
{
  const int r = blockIdx.x;            // t*128 + b
  const int t = r >> 7, b = r & 127;
  const int tid = threadIdx.x;
  const int h = tid >> 7, lane = tid & 127;
  __shared__ float redf[256];
  __shared__ int   redi[256];
  __shared__ float yw[2], lyw[2], att_s[2];

  const uint32_t rowbase = (uint32_t)((t * 256 + b * 2 + h) * 500);
  float zv[4], ev[4];
  float lmax = -3.0e38f;
#pragma unroll
  for (int s = 0; s < 4; ++s){
    const int a = lane + s * 128;
    float z = -3.0e38f;
    if (a < ASP){
      float g = jgumbel(k0a, k0b, rowbase + (uint32_t)a);
      float m = mu_all[(long)r * NMU + h * ASP + a];
      z = (m + g) / 0.8f;
    }
    zv[s] = z;
    lmax = fmaxf(lmax, z);
  }
  redf[tid] = lmax;
  __syncthreads();
  for (int off = 64; off > 0; off >>= 1){
    if (lane < off) redf[tid] = fmaxf(redf[tid], redf[tid + off]);
    __syncthreads();
  }
  const float mx = redf[h << 7];
  __syncthreads();
  float lsum = 0.0f;
#pragma unroll
  for (int s = 0; s < 4; ++s){
    const int a = lane + s * 128;
    float e = 0.0f;
    if (a < ASP) e = expf(zv[s] - mx);
    ev[s] = e;
    lsum += e;
  }
  redf[tid] = lsum;
  __syncthreads();
  for (int off = 64; off > 0; off >>= 1){
    if (lane < off) redf[tid] += redf[tid + off];
    __syncthreads();
  }
  const float S = redf[h << 7];
  __syncthreads();
  float bestv = -3.0e38f;
  int besti = 0x7fffffff;
#pragma unroll
  for (int s = 0; s < 4; ++s){
    const int a = lane + s * 128;
    if (a < ASP){
      float y = ev[s] / S;
      float ly = logf(y);
      float gc = jgumbel(k1a, k1b, rowbase + (uint32_t)a);
      float val = ly + gc;
      if (val > bestv){ bestv = val; besti = a; }
    }
  }
  redf[tid] = bestv; redi[tid] = besti;
  __syncthreads();
  for (int off = 64; off > 0; off >>= 1){
    if (lane < off){
      float v2 = redf[tid + off]; int i2 = redi[tid + off];
      if (v2 > redf[tid] || (v2 == redf[tid] && i2 < redi[tid])){
        redf[tid] = v2; redi[tid] = i2;
      }
    }
    __syncthreads();
  }
  const int ind = redi[h << 7];
#pragma unroll
  for (int s = 0; s < 4; ++s){
    const int a = lane + s * 128;
    if (a == ind){
      float y = ev[s] / S;
      yw[h] = y;
      lyw[h] = logf(y);
    }
  }
  __syncthreads();
  if (lane == 0){
    const float yv = yw[h];
    const float ly = lyw[h];
    const float yh = (1.0f - yv) + yv;
    const float act = ((float)ind * yh) / 500.0f;
    const float lvr = lv_all[(long)r * 2 + h];
    const float lv = fmaxf(lvr, 0.0f) + log1pf(expf(-fabsf(lvr)));
    const float sd = expf(0.5f * lv);
    const uint32_t ei = (uint32_t)(r * 2 + h);
    const float e1 = jnormal(k2a, k2b, ei);
    const float e2 = jnormal(k3a, k3b, ei);
    const float s1 = act + sd * e1;
    const float s2 = act + sd * e2;
    const float dd = (s2 - act) / sd;
    const float lp = -0.5f * (dd * dd) - logf(sd) - 0.9189385332046727f;
    const float attv = 20.0f * jsigmoid(s1);
    out[OUT_SLOG + (long)b * 256 + t * 2 + h]  = ly;
    out[OUT_ACT  + (long)b * 256 + h * 128 + t] = act;
    out[OUT_LOGP + (long)b * 256 + h * 128 + t] = lp;
    att_s[h] = attv;
  }
  __syncthreads();
  const float* xr = X + ((long)b * TT + t) * DD;
  unsigned short* tr = texts_b + (long)r * 320;
  for (int j = tid; j < 320; j += 256){
    unsigned short o = 0;
    if (j < 300) o = f2bf(xr[j] * att_s[j / 150]);
    tr[j] = o;
  }
}

// ---------------- weight conversion to bf16 ----------------
__global__ __launch_bounds__(256) void k_cvt_whh(
    const float* __restrict__ W, unsigned short* __restrict__ O)
{
  const int i = blockIdx.x * 256 + threadIdx.x;   // 3072*1024
  O[i] = f2bf(W[i]);
}

__global__ __launch_bounds__(256) void k_cvt_wih(
    const float* __restrict__ W, unsigned short* __restrict__ O)
{
  const int i = blockIdx.x * 256 + threadIdx.x;   // 3072*320
  const int rw = i / 320, c = i - rw * 320;
  O[i] = (c < DD) ? f2bf(W[(long)rw * DD + c]) : (unsigned short)0;
}

// ---------------- stage-2 persistent: 128 blocks x 512 thr ----------------
#define NBLK2 128
#define WPITCH 2704   // 1344*2 + 16

__global__ __launch_bounds__(512) void k_stage2(
    const unsigned short* __restrict__ texts_b,
    const unsigned short* __restrict__ Whb,
    const unsigned short* __restrict__ Wib,
    const float* __restrict__ bih, const float* __restrict__ bhh,
    const int* __restrict__ lengths,
    unsigned short* __restrict__ h2b0, unsigned short* __restrict__ h2b1,
    float* __restrict__ last,
    unsigned int* __restrict__ flags)
{
  __shared__ __align__(16) char lds[150272];   // W:129792 | A/reduce: 20480
  unsigned short* Wl = (unsigned short*)lds;
  char* Al = lds + 129792;

  const int tid = threadIdx.x;
  const int bid = blockIdx.x;
  const int m = bid >> 6, n = bid & 63;
  const int e0 = n * 16, mrow = m * 64;
  const int wave = tid >> 6, wg = wave >> 2, wvr = wave & 3;
  const int lane = tid & 63, lo = lane & 15, hi = lane >> 4;
  const int tidg = tid & 255;

  // ---- stage W (48 x 1344 bf16) once ----
  for (int s = tid; s < 48 * 168; s += 512){
    const int row = s / 168, q = s - row * 168;
    const int g = row >> 4, nn = row & 15;
    const long wrow = (long)g * EE + e0 + nn;
    uint4 v;
    if (q < 128) v = *(const uint4*)(Whb + wrow * EE + q * 8);
    else         v = *(const uint4*)(Wib + wrow * 320 + (q - 128) * 8);
    *(uint4*)((char*)Wl + (long)row * WPITCH + q * 16) = v;
  }

  const int e = e0 + lo;
  const float bR = bih[e] + bhh[e];
  const float bZ = bih[EE + e] + bhh[EE + e];
  const float biN = bih[2*EE + e];
  const float bhN = bhh[2*EE + e];
  int li[4]; float hp[4];
#pragma unroll
  for (int j = 0; j < 4; ++j){
    const int brow = wvr * 16 + hi * 4 + j;
    int l = lengths[mrow + brow] - 1; if (l < 0) l += TT;
    li[j] = l; hp[j] = 0.0f;
  }
  __syncthreads();

  using frag = __attribute__((ext_vector_type(8))) short;
  using f32x4 = __attribute__((ext_vector_type(4))) float;

  // per-wave A buffer: 16 rows x 128B, XOR-swizzled
  char* Aw = Al + wave * 2048;
  const int lrow = lane >> 2, lkq0 = lane & 3, lkq1 = (lane & 3) + 4;
  const int woff0 = lrow * 128 + ((lkq0 ^ (lrow & 7)) << 4);
  const int woff1 = lrow * 128 + ((lkq1 ^ (lrow & 7)) << 4);
  const int growA = mrow + wvr * 16 + lrow;      // global A row this lane loads
  const int roff0 = lo * 128 + (((0 + hi) ^ (lo & 7)) << 4);   // kf=0 read
  const int roff1 = lo * 128 + (((4 + hi) ^ (lo & 7)) << 4);   // kf=1 read
  int boff[3];
#pragma unroll
  for (int g = 0; g < 3; ++g) boff[g] = (g * 16 + lo) * WPITCH + hi * 16;

  unsigned int* flagp = flags + bid * 16;

  for (int t = 0; t < TT; ++t){
    const unsigned short* hb = (t & 1) ? h2b1 : h2b0;
    unsigned short* ho = (t & 1) ? h2b0 : h2b1;
    const unsigned short* txp = texts_b + (long)t * BB * 320;

    f32x4 aR = {0,0,0,0}, aZ = {0,0,0,0}, aNH = {0,0,0,0}, aNI = {0,0,0,0};

    auto chunkA = [&](int cc, u32x4 r0, u32x4 r1, bool hid){
      asm volatile("" ::: "memory");
      *(u32x4*)(Aw + woff0) = r0;
      *(u32x4*)(Aw + woff1) = r1;
      asm volatile("s_waitcnt lgkmcnt(0)" ::: "memory");
      __builtin_amdgcn_sched_barrier(0);
      frag a0 = *(const frag*)(Aw + roff0);
      frag a1 = *(const frag*)(Aw + roff1);
      asm volatile("" ::: "memory");
      const char* wb = (const char*)Wl + cc * 128;
      frag b00 = *(const frag*)(wb + boff[0]);
      frag b10 = *(const frag*)(wb + boff[1]);
      frag b20 = *(const frag*)(wb + boff[2]);
      frag b01 = *(const frag*)(wb + boff[0] + 64);
      frag b11 = *(const frag*)(wb + boff[1] + 64);
      frag b21 = *(const frag*)(wb + boff[2] + 64);
      aR = __builtin_amdgcn_mfma_f32_16x16x32_bf16(a0, b00, aR, 0, 0, 0);
      aZ = __builtin_amdgcn_mfma_f32_16x16x32_bf16(a0, b10, aZ, 0, 0, 0);
      if (hid) aNH = __builtin_amdgcn_mfma_f32_16x16x32_bf16(a0, b20, aNH, 0, 0, 0);
      else     aNI = __builtin_amdgcn_mfma_f32_16x16x32_bf16(a0, b20, aNI, 0, 0, 0);
      aR = __builtin_amdgcn_mfma_f32_16x16x32_bf16(a1, b01, aR, 0, 0, 0);
      aZ = __builtin_amdgcn_mfma_f32_16x16x32_bf16(a1, b11, aZ, 0, 0, 0);
      if (hid) aNH = __builtin_amdgcn_mfma_f32_16x16x32_bf16(a1, b21, aNH, 0, 0, 0);
      else     aNI = __builtin_amdgcn_mfma_f32_16x16x32_bf16(a1, b21, aNI, 0, 0, 0);
    };

    // ---- texts phase (per-wave, barrier-free) ----
    {
      const unsigned short* tp = txp + (long)growA * 320 + (wg ? 192 : 0);
      u32x4 t0a, t0b, t1a, t1b, t2a = {0,0,0,0}, t2b = {0,0,0,0};
      t0a = load_b128_llc(tp + lkq0 * 8);        t0b = load_b128_llc(tp + lkq1 * 8);
      t1a = load_b128_llc(tp + 64 + lkq0 * 8);   t1b = load_b128_llc(tp + 64 + lkq1 * 8);
      if (wg == 0){
        t2a = load_b128_llc(tp + 128 + lkq0 * 8);
        t2b = load_b128_llc(tp + 128 + lkq1 * 8);
        WAITV(4); chunkA(16, t0a, t0b, false);
        WAITV(2); chunkA(17, t1a, t1b, false);
        WAITV(0); chunkA(18, t2a, t2b, false);
      } else {
        WAITV(2); chunkA(19, t0a, t0b, false);
        WAITV(0); chunkA(20, t1a, t1b, false);
      }
    }

    // ---- barrier (same-m domain) + hidden phase (8 chunks, 8-deep issue) ----
    if (t > 0){
      if (tid < 64){
        const unsigned int* fp = flags + ((m << 6) + tid) * 16;
        unsigned v = poll_u32_llc(fp);
        while (v < (unsigned)t){
          __builtin_amdgcn_s_sleep(2);
          v = poll_u32_llc(fp);
        }
      }
      __syncthreads();

      const unsigned short* hpK = hb + (long)growA * EE + (wg << 9);
      u32x4 h0a = load_b128_llc(hpK +   0 + lkq0*8), h0b = load_b128_llc(hpK +   0 + lkq1*8);
      u32x4 h1a = load_b128_llc(hpK +  64 + lkq0*8), h1b = load_b128_llc(hpK +  64 + lkq1*8);
      u32x4 h2a = load_b128_llc(hpK + 128 + lkq0*8), h2b_ = load_b128_llc(hpK + 128 + lkq1*8);
      u32x4 h3a = load_b128_llc(hpK + 192 + lkq0*8), h3b = load_b128_llc(hpK + 192 + lkq1*8);
      u32x4 h4a = load_b128_llc(hpK + 256 + lkq0*8), h4b = load_b128_llc(hpK + 256 + lkq1*8);
      u32x4 h5a = load_b128_llc(hpK + 320 + lkq0*8), h5b = load_b128_llc(hpK + 320 + lkq1*8);
      u32x4 h6a = load_b128_llc(hpK + 384 + lkq0*8), h6b = load_b128_llc(hpK + 384 + lkq1*8);
      u32x4 h7a = load_b128_llc(hpK + 448 + lkq0*8), h7b = load_b128_llc(hpK + 448 + lkq1*8);
      const int cb = wg * 8;
      WAITV(14); chunkA(cb + 0, h0a, h0b, true);
      WAITV(12); chunkA(cb + 1, h1a, h1b, true);
      WAITV(10); chunkA(cb + 2, h2a, h2b_, true);
      WAITV(8);  chunkA(cb + 3, h3a, h3b, true);
      WAITV(6);  chunkA(cb + 4, h4a, h4b, true);
      WAITV(4);  chunkA(cb + 5, h5a, h5b, true);
      WAITV(2);  chunkA(cb + 6, h6a, h6b, true);
      WAITV(0);  chunkA(cb + 7, h7a, h7b, true);
    }

    // ---- cross-group reduce (Al reused; fenced by barriers) ----
    __syncthreads();
    if (wg == 1){
      char* dst = Al + tidg * 80;
      *(f32x4*)(dst)      = aR;
      *(f32x4*)(dst + 16) = aZ;
      *(f32x4*)(dst + 32) = aNH;
      *(f32x4*)(dst + 48) = aNI;
    }
    __syncthreads();
    if (wg == 0){
      const char* src = Al + tidg * 80;
      const f32x4 pR  = *(const f32x4*)(src);
      const f32x4 pZ  = *(const f32x4*)(src + 16);
      const f32x4 pNH = *(const f32x4*)(src + 32);
      const f32x4 pNI = *(const f32x4*)(src + 48);
#pragma unroll
      for (int j = 0; j < 4; ++j){
        aR[j] += pR[j]; aZ[j] += pZ[j]; aNH[j] += pNH[j]; aNI[j] += pNI[j];
      }
      // GRU gates epilogue (group 0 only)
#pragma unroll
      for (int j = 0; j < 4; ++j){
        const int brow = wvr * 16 + hi * 4 + j;
        const float r = jsigmoid(aR[j] + bR);
        const float z = jsigmoid(aZ[j] + bZ);
        const float nn2 = tanhf(aNI[j] + biN + r * (aNH[j] + bhN));
        const float hn = (1.0f - z) * nn2 + z * hp[j];
        hp[j] = hn;
        store_u16_llc(ho + (long)(mrow + brow) * EE + e, (unsigned)f2bf(hn));
        if (t == li[j]) last[(long)(mrow + brow) * EE + e] = hn;
      }
    }

    if (t < TT - 1){
      asm volatile("s_waitcnt vmcnt(0)" ::: "memory");
      __syncthreads();
      if (tid == 0) store_u32_llc(flagp, (unsigned)(t + 1));
    }
  }
}

// ---------------- BatchNorm ----------------
__global__ __launch_bounds__(256) void k_bn_stats(
    const float* __restrict__ last, float* __restrict__ mv)
{
  const int e = blockIdx.x * 256 + threadIdx.x;
  if (e >= EE) return;
  float s = 0.0f;
  for (int b = 0; b < BB; ++b) s += last[(long)b * EE + e];
  const float mean = s / 128.0f;
  float v = 0.0f;
  for (int b = 0; b < BB; ++b){ float d = last[(long)b * EE + e] - mean; v += d * d; }
  mv[e] = mean;
  mv[EE + e] = v / 128.0f;
}

__global__ __launch_bounds__(256) void k_bn_apply(
    const float* __restrict__ last, const float* __restrict__ mv,
    const float* __restrict__ gamma, const float* __restrict__ beta,
    float* __restrict__ out)
{
  const int gid = blockIdx.x * 256 + threadIdx.x;
  const int e = gid & 1023;
  const float xm = last[gid] - mv[e];
  out[gid] = gamma[e] * xm / sqrtf(mv[EE + e] + 1e-5f) + beta[e];
}

// ---------------- launcher ----------------
extern "C" void kernel_launch(void* const* d_in, const int* in_sizes, int n_in,
                              void* d_out, int out_size, void* d_ws, size_t ws_size,
                              hipStream_t stream)
{
  (void)in_sizes; (void)n_in; (void)out_size;
  const float* x     = (const float*)d_in[0];
  const int*   lens  = (const int*)d_in[1];
  const float* Wih_c = (const float*)d_in[3];
  const float* Whh_c = (const float*)d_in[4];
  const float* bih_c = (const float*)d_in[5];
  const float* bhh_c = (const float*)d_in[6];
  const float* Wmu   = (const float*)d_in[7];
  const float* bmu   = (const float*)d_in[8];
  const float* Wlv   = (const float*)d_in[9];
  const float* blv   = (const float*)d_in[10];
  const float* Wih_r = (const float*)d_in[11];
  const float* Whh_r = (const float*)d_in[12];
  const float* bih_r = (const float*)d_in[13];
  const float* bhh_r = (const float*)d_in[14];
  const float* gam   = (const float*)d_in[15];
  const float* bet   = (const float*)d_in[16];
  float* out = (float*)d_out;

  uint32_t nk[4][2];
  for (uint32_t i = 0; i < 4; ++i) tf2x32(0u, 42u, 0u, i, &nk[i][0], &nk[i][1]);

  float* ws = (float*)d_ws;
  size_t off = 0;
  float* U       = ws + off; off += 16384000;  // gi_all then mu_all (aliased)
  float* hx_all  = ws + off; off += 4915200;
  float* lv_all  = ws + off; off += 32768;
  float* Wp      = ws + off; off += 307200;    // packed Whh_c
  float* lastb   = ws + off; off += 131072;
  float* mv      = ws + off; off += 2048;
  float* hex     = ws + off; off += 77824;     // [2][128][304] f32 stage-1 exchange
  unsigned int* flags  = (unsigned int*)(ws + off); off += 2048;  // stage-2: 128*16
  unsigned int* flagsA = (unsigned int*)(ws + off); off += 4096;  // stage-1: 256*16
  unsigned short* texts_b = (unsigned short*)(ws + off); off += 2621440; // 16384x320 bf16
  unsigned short* h2b0    = (unsigned short*)(ws + off); off += 65536;   // 128x1024 bf16
  unsigned short* h2b1    = (unsigned short*)(ws + off); off += 65536;
  unsigned short* Whb     = (unsigned short*)(ws + off); off += 1572864; // 3072x1024 bf16
  unsigned short* Wib     = (unsigned short*)(ws + off); off += 491520;  // 3072x320 bf16
  if (ws_size < off * sizeof(float)) return;

  hipMemsetAsync(flags, 0, 2048 * sizeof(unsigned int), stream);
  hipMemsetAsync(flagsA, 0, 4096 * sizeof(unsigned int), stream);

  // weight prep
  k_cvt_whh<<<dim3(12288), 256, 0, stream>>>(Whh_r, Whb);
  k_cvt_wih<<<dim3(3840), 256, 0, stream>>>(Wih_r, Wib);
  k_pack_whh<<<dim3(300), 256, 0, stream>>>(Whh_c, Wp);

  // stage-1 input projection + persistent jj-split recurrence (W LDS-resident)
  k_gemm_gi<<<dim3(15, 128), 256, 0, stream>>>(x, Wih_c, bih_c, U);
  k_stage1<<<dim3(256), 256, 0, stream>>>(Wp, bhh_c, U, hx_all, hex, flagsA);

  // batched mu / lv / sampling
  k_gemm_mu<<<dim3(16, 128), 256, 0, stream>>>(x, hx_all, Wmu, bmu, U);
  k_lv<<<dim3(4096), 256, 0, stream>>>(x, hx_all, Wlv, blv, lv_all);
  k_sample<<<dim3(16384), 256, 0, stream>>>(x, U, lv_all, texts_b, out,
      nk[0][0], nk[0][1], nk[1][0], nk[1][1],
      nk[2][0], nk[2][1], nk[3][0], nk[3][1]);

  // stage-2 persistent recurrence (per-wave staging, barrier-free chunks)
  k_stage2<<<dim3(NBLK2), 512, 0, stream>>>(texts_b, Whb, Wib, bih_r, bhh_r, lens,
                                            h2b0, h2b1, lastb, flags);

  // batchnorm
  k_bn_stats<<<dim3(4), 256, 0, stream>>>(lastb, mv);
  k_bn_apply<<<dim3(512), 256, 0, stream>>>(lastb, mv, gam, bet, out);
}